// Round 9
// baseline (1792.510 us; speedup 1.0000x reference)
//
#include <hip/hip_runtime.h>
#include <math.h>

#define B_ 4
#define N_ 1024
#define C_ 1024
#define H_ 16
#define HD_ 64

// ---------------------------------------------------------------------------
// ERROR MODEL (validated r4/r6/r7: absmax 16 vs threshold 97):
//   S = (1-g)*spv/sp + g*sqv/sq ~ 4e-5 from cancellation; budget dS ~1.3e-7
//   => weight rel err <= 4e-8 for BOTH softmaxes -> f64 logits+exp
//   (fast_exp64, 3e-10). V_m exact via f64 wsum collapse. q,k <1e-7 ->
//   slab-f64 GEMM. DAMPED paths (PV numerators, v, proj): plain f32.
// PERF MODEL:
//   r5/r8 lesson: live VGPRs must stay <= ~90 or the allocator spills
//   (WRITE_SIZE balloons to GBs). r7 structure (VGPR 84) is the keeper.
//   r7 counters: VALU 62%, occ 33% (12 waves/CU) -> latency-hiding bound.
//   r9: QBLK 32 / 8 waves / 512 thr -> 2 blocks/CU = 16 waves/CU, K-stage
//   amortized over 2x rows; per-lane structure identical to r7.
//   GEMMs: double-buffered slabs, 1 barrier/slab.
// ---------------------------------------------------------------------------

// fast f64 exp for |a| <= ~16: range-reduce + deg-8 Taylor. rel err ~3e-10.
__device__ __forceinline__ double fast_exp64(double a) {
    const double LOG2E = 1.4426950408889634074;
    const double LN2HI = 6.93147180369123816490e-01;
    const double LN2LO = 1.90821492927058770002e-10;
    const double MAGIC = 6755399441055744.0;   // 1.5 * 2^52
    double t     = a * LOG2E;
    double shift = t + MAGIC;
    int    n     = (int)__double_as_longlong(shift);
    double nd    = shift - MAGIC;
    double f     = __fma_rn(nd, -LN2HI, a);
    f            = __fma_rn(nd, -LN2LO, f);
    double p = 2.4801587301587301587e-05;
    p = __fma_rn(p, f, 1.9841269841269841270e-04);
    p = __fma_rn(p, f, 1.3888888888888888889e-03);
    p = __fma_rn(p, f, 8.3333333333333333333e-03);
    p = __fma_rn(p, f, 4.1666666666666666667e-02);
    p = __fma_rn(p, f, 1.6666666666666666667e-01);
    p = __fma_rn(p, f, 5.0e-01);
    p = __fma_rn(p, f, 1.0);
    p = __fma_rn(p, f, 1.0);
    return p * __longlong_as_double(((long long)(1023 + n)) << 52);
}

// ---------------------------------------------------------------------------
// Slab-compensated GEMM for q,k (O=2048). Tile 128x64, f32 slabs -> f64.
// r9: double-buffered LDS slabs, reg prefetch, 1 barrier/slab.
// ---------------------------------------------------------------------------
__global__ __launch_bounds__(256)
void gemm_qk_kernel(const float* __restrict__ A,
                    const float* __restrict__ W0,   // W_qk rows 0..2047
                    float* __restrict__ outq,
                    float* __restrict__ outk,
                    int M, int K)
{
    __shared__ float As[2][16][132];
    __shared__ float Ws[2][16][68];

    const int t  = threadIdx.x;
    const int m0 = blockIdx.y * 128;
    const int o0 = blockIdx.x * 64;
    const int ty = t >> 4;
    const int tx = t & 15;

    // staging indices
    const int ar0 = t >> 2;            // A rows t>>2, +64
    const int ac4 = t & 3;
    const int wc  = t >> 2;            // W channel (first 256 vecs only)
    const int wc4 = t & 3;

    double acc[8][4];
    #pragma unroll
    for (int i = 0; i < 8; ++i)
        #pragma unroll
        for (int j = 0; j < 4; ++j) acc[i][j] = 0.0;

    // prologue: stage slab 0
    {
        const float4 a0 = *reinterpret_cast<const float4*>(&A[(size_t)(m0 + ar0) * K + ac4 * 4]);
        const float4 a1 = *reinterpret_cast<const float4*>(&A[(size_t)(m0 + ar0 + 64) * K + ac4 * 4]);
        const float4 w0 = *reinterpret_cast<const float4*>(&W0[(size_t)(o0 + wc) * K + wc4 * 4]);
        #pragma unroll
        for (int e = 0; e < 4; ++e) {
            As[0][ac4 * 4 + e][ar0]      = (&a0.x)[e];
            As[0][ac4 * 4 + e][ar0 + 64] = (&a1.x)[e];
            Ws[0][wc4 * 4 + e][wc]       = (&w0.x)[e];
        }
    }
    __syncthreads();

    const int NS = K / 16;   // 64 slabs
    for (int s = 0; s < NS; ++s) {
        const int cur = s & 1;
        float4 pa0, pa1, pw0;
        if (s < NS - 1) {
            const int k0 = (s + 1) * 16;
            pa0 = *reinterpret_cast<const float4*>(&A[(size_t)(m0 + ar0) * K + k0 + ac4 * 4]);
            pa1 = *reinterpret_cast<const float4*>(&A[(size_t)(m0 + ar0 + 64) * K + k0 + ac4 * 4]);
            pw0 = *reinterpret_cast<const float4*>(&W0[(size_t)(o0 + wc) * K + k0 + wc4 * 4]);
        }

        float sacc[8][4];
        #pragma unroll
        for (int i = 0; i < 8; ++i)
            #pragma unroll
            for (int j = 0; j < 4; ++j) sacc[i][j] = 0.f;

        #pragma unroll
        for (int kk = 0; kk < 16; ++kk) {
            float a[8], bb[4];
            *reinterpret_cast<float4*>(&a[0])  = *reinterpret_cast<const float4*>(&As[cur][kk][ty * 8]);
            *reinterpret_cast<float4*>(&a[4])  = *reinterpret_cast<const float4*>(&As[cur][kk][ty * 8 + 4]);
            *reinterpret_cast<float4*>(&bb[0]) = *reinterpret_cast<const float4*>(&Ws[cur][kk][tx * 4]);
            #pragma unroll
            for (int i = 0; i < 8; ++i)
                #pragma unroll
                for (int j = 0; j < 4; ++j)
                    sacc[i][j] += a[i] * bb[j];
        }
        #pragma unroll
        for (int i = 0; i < 8; ++i)
            #pragma unroll
            for (int j = 0; j < 4; ++j) acc[i][j] += (double)sacc[i][j];

        if (s < NS - 1) {
            const int nxt = cur ^ 1;
            #pragma unroll
            for (int e = 0; e < 4; ++e) {
                As[nxt][ac4 * 4 + e][ar0]      = (&pa0.x)[e];
                As[nxt][ac4 * 4 + e][ar0 + 64] = (&pa1.x)[e];
                Ws[nxt][wc4 * 4 + e][wc]       = (&pw0.x)[e];
            }
        }
        __syncthreads();
    }

    int oo = o0 + tx * 4;
    float* dst = (oo < 1024) ? outq : outk;
    oo &= 1023;
    const int hh = oo >> 6, d0 = oo & 63;
    #pragma unroll
    for (int i = 0; i < 8; ++i) {
        int m = m0 + ty * 8 + i;
        int bb_ = m >> 10, n = m & 1023;
        float4 r0 = make_float4((float)acc[i][0], (float)acc[i][1],
                                (float)acc[i][2], (float)acc[i][3]);
        *reinterpret_cast<float4*>(&dst[((((size_t)bb_ * H_) + hh) * N_ + n) * HD_ + d0]) = r0;
    }
}

// ---------------------------------------------------------------------------
// Plain f32 GEMM, tile 128x128 (damped paths: v and proj), dbuf slabs.
// ---------------------------------------------------------------------------
template<int MODE>
__global__ __launch_bounds__(256)
void gemm128_kernel(const float* __restrict__ A,
                    const float* __restrict__ W0,
                    const float* __restrict__ bias,
                    float* __restrict__ out0,
                    int M, int O, int K)
{
    __shared__ float As[2][16][132];
    __shared__ float Ws[2][16][132];

    const int t  = threadIdx.x;
    const int m0 = blockIdx.y * 128;
    const int o0 = blockIdx.x * 128;
    const int ty = t >> 4;
    const int tx = t & 15;

    const int ar0 = t >> 2;
    const int ac4 = t & 3;

    float acc[8][8];
    #pragma unroll
    for (int i = 0; i < 8; ++i)
        #pragma unroll
        for (int j = 0; j < 8; ++j) acc[i][j] = 0.f;

    // prologue: stage slab 0
    {
        const float4 a0 = *reinterpret_cast<const float4*>(&A[(size_t)(m0 + ar0) * K + ac4 * 4]);
        const float4 a1 = *reinterpret_cast<const float4*>(&A[(size_t)(m0 + ar0 + 64) * K + ac4 * 4]);
        const float4 w0 = *reinterpret_cast<const float4*>(&W0[(size_t)(o0 + ar0) * K + ac4 * 4]);
        const float4 w1 = *reinterpret_cast<const float4*>(&W0[(size_t)(o0 + ar0 + 64) * K + ac4 * 4]);
        #pragma unroll
        for (int e = 0; e < 4; ++e) {
            As[0][ac4 * 4 + e][ar0]      = (&a0.x)[e];
            As[0][ac4 * 4 + e][ar0 + 64] = (&a1.x)[e];
            Ws[0][ac4 * 4 + e][ar0]      = (&w0.x)[e];
            Ws[0][ac4 * 4 + e][ar0 + 64] = (&w1.x)[e];
        }
    }
    __syncthreads();

    const int NS = K / 16;
    for (int s = 0; s < NS; ++s) {
        const int cur = s & 1;
        float4 pa0, pa1, pw0, pw1;
        if (s < NS - 1) {
            const int k0 = (s + 1) * 16;
            pa0 = *reinterpret_cast<const float4*>(&A[(size_t)(m0 + ar0) * K + k0 + ac4 * 4]);
            pa1 = *reinterpret_cast<const float4*>(&A[(size_t)(m0 + ar0 + 64) * K + k0 + ac4 * 4]);
            pw0 = *reinterpret_cast<const float4*>(&W0[(size_t)(o0 + ar0) * K + k0 + ac4 * 4]);
            pw1 = *reinterpret_cast<const float4*>(&W0[(size_t)(o0 + ar0 + 64) * K + k0 + ac4 * 4]);
        }

        #pragma unroll
        for (int kk = 0; kk < 16; ++kk) {
            float a[8], bb[8];
            *reinterpret_cast<float4*>(&a[0])  = *reinterpret_cast<const float4*>(&As[cur][kk][ty * 8]);
            *reinterpret_cast<float4*>(&a[4])  = *reinterpret_cast<const float4*>(&As[cur][kk][ty * 8 + 4]);
            *reinterpret_cast<float4*>(&bb[0]) = *reinterpret_cast<const float4*>(&Ws[cur][kk][tx * 8]);
            *reinterpret_cast<float4*>(&bb[4]) = *reinterpret_cast<const float4*>(&Ws[cur][kk][tx * 8 + 4]);
            #pragma unroll
            for (int i = 0; i < 8; ++i)
                #pragma unroll
                for (int j = 0; j < 8; ++j)
                    acc[i][j] += a[i] * bb[j];
        }

        if (s < NS - 1) {
            const int nxt = cur ^ 1;
            #pragma unroll
            for (int e = 0; e < 4; ++e) {
                As[nxt][ac4 * 4 + e][ar0]      = (&pa0.x)[e];
                As[nxt][ac4 * 4 + e][ar0 + 64] = (&pa1.x)[e];
                Ws[nxt][ac4 * 4 + e][ar0]      = (&pw0.x)[e];
                Ws[nxt][ac4 * 4 + e][ar0 + 64] = (&pw1.x)[e];
            }
        }
        __syncthreads();
    }

    if (MODE == 1) {
        float bs[8];
        *reinterpret_cast<float4*>(&bs[0]) = *reinterpret_cast<const float4*>(&bias[o0 + tx * 8]);
        *reinterpret_cast<float4*>(&bs[4]) = *reinterpret_cast<const float4*>(&bias[o0 + tx * 8 + 4]);
        #pragma unroll
        for (int i = 0; i < 8; ++i) {
            int m = m0 + ty * 8 + i;
            float* p = &out0[(size_t)m * O + o0 + tx * 8];
            float4 r0 = make_float4(acc[i][0] + bs[0], acc[i][1] + bs[1], acc[i][2] + bs[2], acc[i][3] + bs[3]);
            float4 r1 = make_float4(acc[i][4] + bs[4], acc[i][5] + bs[5], acc[i][6] + bs[6], acc[i][7] + bs[7]);
            *reinterpret_cast<float4*>(p)     = r0;
            *reinterpret_cast<float4*>(p + 4) = r1;
        }
    } else {
        int oo = o0 + tx * 8;
        const int hh = oo >> 6, d0 = oo & 63;
        #pragma unroll
        for (int i = 0; i < 8; ++i) {
            int m = m0 + ty * 8 + i;
            int bb_ = m >> 10, n = m & 1023;
            float* p = &out0[((((size_t)bb_ * H_) + hh) * N_ + n) * HD_ + d0];
            *reinterpret_cast<float4*>(p)     = make_float4(acc[i][0], acc[i][1], acc[i][2], acc[i][3]);
            *reinterpret_cast<float4*>(p + 4) = make_float4(acc[i][4], acc[i][5], acc[i][6], acc[i][7]);
        }
    }
}

// ---------------------------------------------------------------------------
__global__ void wsum_kernel(const float* __restrict__ W_v, double* __restrict__ wsh)
{
    const int k = blockIdx.x * 256 + threadIdx.x;
    const int h = blockIdx.y;
    double s = 0.0;
    #pragma unroll 8
    for (int d = 0; d < 64; ++d) s += (double)W_v[(size_t)(h * 64 + d) * C_ + k];
    wsh[h * C_ + k] = s;
}

__global__ __launch_bounds__(256)
void vall_kernel(const float* __restrict__ x, const double* __restrict__ wsh,
                 double* __restrict__ Vall)
{
    __shared__ double ws_s[1024];
    const int h = blockIdx.y, b = blockIdx.z;
    const int m = blockIdx.x * 256 + threadIdx.x;
    for (int i = threadIdx.x; i < 1024; i += 256) ws_s[i] = wsh[h * C_ + i];
    __syncthreads();
    const float* xr = x + ((size_t)b * N_ + m) * C_;
    double acc = 0.0;
    #pragma unroll 8
    for (int kk = 0; kk < 1024; ++kk) acc += (double)xr[kk] * ws_s[kk];
    Vall[((size_t)b * H_ + h) * N_ + m] = acc;
}

// ---------------------------------------------------------------------------
// Fused attention r9: EXACT r7 per-lane structure (VGPR ~84, no spill),
// scaled to QBLK=32 / 8 waves / 512 threads:
//  - wave w owns rows {w, w+8, w+16, w+24}
//  - K dbuf staged once per block serves 32 query rows (2x amortization)
//  - 2 blocks/CU = 16 waves/CU (was 12) -> better latency hiding
// ---------------------------------------------------------------------------
__global__ __launch_bounds__(512)
void attn_kernel(const float* __restrict__ q,
                 const float* __restrict__ k,
                 const float* __restrict__ v,
                 const double* __restrict__ Vall,   // [B][H][N]
                 const float* __restrict__ coord,   // [B][N][3]
                 const float* __restrict__ W_pos,   // [H][4]
                 const float* __restrict__ gating,  // [H]
                 float* __restrict__ attn_out)      // [B][N][C]
{
    __shared__ float4 Qs4[32][16];                 // 8KB
    __shared__ float4 Kt4[2][64][16];              // 32KB double-buffered K
    __shared__ __align__(16) float pt[32][64];     // 8KB (wave-private rows)
    __shared__ __align__(16) float qt[32][64];     // 8KB
    __shared__ float qc[32][3];

    const int t  = threadIdx.x;
    const int w  = t >> 6;     // wave 0..7, owns rows {w, w+8, w+16, w+24}
    const int l  = t & 63;
    const int n0 = blockIdx.x * 32;
    const int h  = blockIdx.y;
    const int b  = blockIdx.z;
    const size_t bhN = ((size_t)b * H_ + h) * N_;

    // staging indices (2 vectors/tile/thread at 512 threads)
    const int sr0 = t >> 4;          // 0..31, rows sr0 and sr0+32
    const int sc  = t & 15;

    Qs4[t >> 4][t & 15] = reinterpret_cast<const float4*>(q + (bhN + n0) * HD_)[t & 511];
    if (t < 96) qc[t / 3][t % 3] = coord[((size_t)b * N_ + n0 + t / 3) * 3 + (t % 3)];
    const double w4hd = (double)W_pos[h * 4 + 3];
    const double ghd  = 1.0 / (1.0 + exp(-(double)gating[h]));

    double sp[4], sq[4], spv[4], sqv[4];
    float accp[4], accq[4];
    #pragma unroll
    for (int i = 0; i < 4; ++i) {
        sp[i] = 0.0; sq[i] = 0.0; spv[i] = 0.0; sqv[i] = 0.0;
        accp[i] = 0.f; accq[i] = 0.f;
    }

    // ---- prologue: stage tile 0 + its Vm/coord
    {
        const float4* kb4 = reinterpret_cast<const float4*>(k + bhN * HD_);
        Kt4[0][sr0     ][sc ^ ( sr0       & 15)] = kb4[t];
        Kt4[0][sr0 + 32][sc ^ ((sr0 + 32) & 15)] = kb4[t + 512];
    }
    double Vm  = Vall[bhN + l];
    double cmx = (double)coord[((size_t)b * N_ + l) * 3 + 0];
    double cmy = (double)coord[((size_t)b * N_ + l) * 3 + 1];
    double cmz = (double)coord[((size_t)b * N_ + l) * 3 + 2];
    __syncthreads();

    for (int t16 = 0; t16 < 16; ++t16) {
        const int cur = t16 & 1;
        const int m0  = t16 * 64;

        // ---- (1) issue next tile's loads
        float4 st0, st1;
        double VmN = 0.0, cmxN = 0.0, cmyN = 0.0, cmzN = 0.0;
        if (t16 < 15) {
            const float4* kb4 = reinterpret_cast<const float4*>(k + (bhN + m0 + 64) * HD_);
            st0 = kb4[t];
            st1 = kb4[t + 512];
            VmN  = Vall[bhN + m0 + 64 + l];
            cmxN = (double)coord[((size_t)b * N_ + m0 + 64 + l) * 3 + 0];
            cmyN = (double)coord[((size_t)b * N_ + m0 + 64 + l) * 3 + 1];
            cmzN = (double)coord[((size_t)b * N_ + m0 + 64 + l) * 3 + 2];
        }

        // ---- (2) QK^T from Kt4[cur]: rows w+8i, column m0+l
        float dotp[4][4];
        #pragma unroll
        for (int i = 0; i < 4; ++i)
            #pragma unroll
            for (int g = 0; g < 4; ++g) dotp[i][g] = 0.f;
        #pragma unroll
        for (int d4 = 0; d4 < 16; ++d4) {
            const float4 kt = Kt4[cur][l][d4 ^ (l & 15)];
            const int g = d4 >> 2;
            #pragma unroll
            for (int i = 0; i < 4; ++i) {
                const float4 q4 = Qs4[w + 8 * i][d4];
                float s = dotp[i][g];
                s = fmaf(kt.x, q4.x, s);
                s = fmaf(kt.y, q4.y, s);
                s = fmaf(kt.z, q4.z, s);
                s = fmaf(kt.w, q4.w, s);
                dotp[i][g] = s;
            }
        }

        // ---- (3) f64 weights + S-path updates (lane = m = m0+l)
        #pragma unroll
        for (int i = 0; i < 4; ++i) {
            const int r = w + 8 * i;
            const double lg = (((double)dotp[i][0] + (double)dotp[i][1]) +
                               ((double)dotp[i][2] + (double)dotp[i][3])) * 0.125;
            const double p64 = fast_exp64(lg);
            const double dx = (double)qc[r][0] - cmx;
            const double dy = (double)qc[r][1] - cmy;
            const double dz = (double)qc[r][2] - cmz;
            const double r2 = __fma_rn(dx, dx, __fma_rn(dy, dy, dz * dz));
            const double y0 = (double)rsqrtf((float)r2);
            const double y1 = y0 * __fma_rn(-0.5 * r2, y0 * y0, 1.5);
            const double dist = (r2 > 0.0) ? r2 * y1 : 0.0;
            const double q64 = fast_exp64(dist * w4hd);
            pt[r][l] = (float)p64;
            qt[r][l] = (float)q64;
            sp[i]  += p64;
            sq[i]  += q64;
            spv[i] += p64 * Vm;
            sqv[i] += q64 * Vm;
        }

        // ---- (4) PV: lane = output dim l, rows w+8i; V direct from global
        const float* vbase = v + (bhN + m0) * HD_ + l;
        #pragma unroll 4
        for (int ml4 = 0; ml4 < 16; ++ml4) {
            float vt0 = vbase[(ml4 * 4 + 0) * HD_];
            float vt1 = vbase[(ml4 * 4 + 1) * HD_];
            float vt2 = vbase[(ml4 * 4 + 2) * HD_];
            float vt3 = vbase[(ml4 * 4 + 3) * HD_];
            #pragma unroll
            for (int i = 0; i < 4; ++i) {
                const float4 pp = *reinterpret_cast<const float4*>(&pt[w + 8 * i][ml4 * 4]);
                const float4 pq = *reinterpret_cast<const float4*>(&qt[w + 8 * i][ml4 * 4]);
                float ap = accp[i], aq = accq[i];
                ap = fmaf(pp.x, vt0, ap); aq = fmaf(pq.x, vt0, aq);
                ap = fmaf(pp.y, vt1, ap); aq = fmaf(pq.y, vt1, aq);
                ap = fmaf(pp.z, vt2, ap); aq = fmaf(pq.z, vt2, aq);
                ap = fmaf(pp.w, vt3, ap); aq = fmaf(pq.w, vt3, aq);
                accp[i] = ap; accq[i] = aq;
            }
        }

        // ---- (5) write staged K into other buffer; roll Vm/coord
        if (t16 < 15) {
            const int nxt = cur ^ 1;
            Kt4[nxt][sr0     ][sc ^ ( sr0       & 15)] = st0;
            Kt4[nxt][sr0 + 32][sc ^ ((sr0 + 32) & 15)] = st1;
            Vm = VmN; cmx = cmxN; cmy = cmyN; cmz = cmzN;
        }
        // ---- (6) single barrier per tile
        __syncthreads();
    }

    // ---- epilogue: f64 reduce, combine, normalize, store (lane = dim l)
    #pragma unroll
    for (int i = 0; i < 4; ++i) {
        double vsp = sp[i], vsq = sq[i], vspv = spv[i], vsqv = sqv[i];
        #pragma unroll
        for (int mm = 32; mm >= 1; mm >>= 1) {
            vsp  += __shfl_xor(vsp,  mm);
            vsq  += __shfl_xor(vsq,  mm);
            vspv += __shfl_xor(vspv, mm);
            vsqv += __shfl_xor(vsqv, mm);
        }
        const double w1 = (1.0 - ghd) / vsp;
        const double w2 = ghd / vsq;
        const double S  = w1 * vspv + w2 * vsqv;
        const double a  = w1 * (double)accp[i] + w2 * (double)accq[i];
        attn_out[((size_t)b * N_ + n0 + (w + 8 * i)) * C_ + h * HD_ + l] = (float)(a / S);
    }
}

// ---------------------------------------------------------------------------
extern "C" void kernel_launch(void* const* d_in, const int* in_sizes, int n_in,
                              void* d_out, int out_size, void* d_ws, size_t ws_size,
                              hipStream_t stream)
{
    const float* x      = (const float*)d_in[0];
    const float* coord  = (const float*)d_in[1];
    const float* W_qk   = (const float*)d_in[2];
    const float* W_v    = (const float*)d_in[3];
    const float* W_proj = (const float*)d_in[4];
    const float* b_proj = (const float*)d_in[5];
    const float* W_pos  = (const float*)d_in[6];
    // d_in[7] = b_pos (cancels in softmax), d_in[9] = pos_emb (cancels) — unused
    const float* gating = (const float*)d_in[8];

    float* ws   = (float*)d_ws;
    const size_t per = (size_t)B_ * H_ * N_ * HD_;   // 4,194,304 floats
    float*  qb   = ws;
    float*  kb   = qb + per;
    float*  vb   = kb + per;
    float*  attn = vb + per;
    double* wsh  = (double*)(attn + per);
    double* Vall = wsh + (size_t)H_ * C_;
    float*  out  = (float*)d_out;

    wsum_kernel<<<dim3(4, 16), 256, 0, stream>>>(W_v, wsh);
    vall_kernel<<<dim3(4, 16, 4), 256, 0, stream>>>(x, wsh, Vall);

    gemm_qk_kernel<<<dim3(32, 32), 256, 0, stream>>>(x, W_qk, qb, kb, B_ * N_, C_);
    gemm128_kernel<0><<<dim3(8, 32), 256, 0, stream>>>(x, W_v, nullptr, vb, B_ * N_, C_, C_);

    attn_kernel<<<dim3(N_ / 32, H_, B_), 512, 0, stream>>>(
        qb, kb, vb, Vall, coord, W_pos, gating, attn);

    gemm128_kernel<1><<<dim3(8, 32), 256, 0, stream>>>(
        attn, W_proj, b_proj, out, B_ * N_, C_, C_);
}

// Round 10
// 1471.217 us; speedup vs baseline: 1.2184x; 1.2184x over previous
//
#include <hip/hip_runtime.h>
#include <math.h>

#define B_ 4
#define N_ 1024
#define C_ 1024
#define H_ 16
#define HD_ 64

// ---------------------------------------------------------------------------
// ERROR MODEL (validated r4/r6/r7: absmax 16 vs threshold 97):
//   S = (1-g)*spv/sp + g*sqv/sq ~ 4e-5 from cancellation; budget dS ~1.3e-7
//   => weight rel err <= 4e-8 for BOTH softmaxes -> f64 logits+exp
//   (fast_exp64, 3e-10). V_m exact via f64 wsum collapse. q,k <1e-7 ->
//   slab-f64 GEMM. DAMPED paths (PV numerators, v, proj): plain f32.
// PERF MODEL:
//   - live VGPRs must stay <= ~90 (r5/r8: spill -> GBs of scratch traffic)
//   - attn is LDS-PIPE-bound (~2000 LDS issue cyc/wave-tile vs ~2350 VALU
//     per SIMD but 4 SIMDs share one LDS pipe). Lever = fewer LDS insts.
//   - r9: QBLK=32/512thr dropped occupancy to 1 block/CU -> reverted.
//   r10 = r7 + Q reads moved off the LDS pipe (wave-uniform global/SMEM).
// ---------------------------------------------------------------------------

// fast f64 exp for |a| <= ~16: range-reduce + deg-8 Taylor. rel err ~3e-10.
__device__ __forceinline__ double fast_exp64(double a) {
    const double LOG2E = 1.4426950408889634074;
    const double LN2HI = 6.93147180369123816490e-01;
    const double LN2LO = 1.90821492927058770002e-10;
    const double MAGIC = 6755399441055744.0;   // 1.5 * 2^52
    double t     = a * LOG2E;
    double shift = t + MAGIC;
    int    n     = (int)__double_as_longlong(shift);
    double nd    = shift - MAGIC;
    double f     = __fma_rn(nd, -LN2HI, a);
    f            = __fma_rn(nd, -LN2LO, f);
    double p = 2.4801587301587301587e-05;
    p = __fma_rn(p, f, 1.9841269841269841270e-04);
    p = __fma_rn(p, f, 1.3888888888888888889e-03);
    p = __fma_rn(p, f, 8.3333333333333333333e-03);
    p = __fma_rn(p, f, 4.1666666666666666667e-02);
    p = __fma_rn(p, f, 1.6666666666666666667e-01);
    p = __fma_rn(p, f, 5.0e-01);
    p = __fma_rn(p, f, 1.0);
    p = __fma_rn(p, f, 1.0);
    return p * __longlong_as_double(((long long)(1023 + n)) << 52);
}

// ---------------------------------------------------------------------------
// Slab-compensated GEMM for q,k (O=2048). Tile 128x64, f32 slabs -> f64.
// (r7 version, known-good: 84..130 VGPR, no spill)
// ---------------------------------------------------------------------------
__global__ __launch_bounds__(256)
void gemm_qk_kernel(const float* __restrict__ A,
                    const float* __restrict__ W0,   // W_qk rows 0..2047
                    float* __restrict__ outq,
                    float* __restrict__ outk,
                    int M, int K)
{
    __shared__ float As[16][132];
    __shared__ float Ws[16][68];

    const int t  = threadIdx.x;
    const int m0 = blockIdx.y * 128;
    const int o0 = blockIdx.x * 64;
    const int ty = t >> 4;
    const int tx = t & 15;

    double acc[8][4];
    #pragma unroll
    for (int i = 0; i < 8; ++i)
        #pragma unroll
        for (int j = 0; j < 4; ++j) acc[i][j] = 0.0;

    for (int k0 = 0; k0 < K; k0 += 16) {
        #pragma unroll
        for (int i = 0; i < 2; ++i) {
            int vix = t + i * 256;
            int r   = vix >> 2;
            int c4  = vix & 3;
            const float4 a4 = *reinterpret_cast<const float4*>(&A[(size_t)(m0 + r) * K + k0 + c4 * 4]);
            As[c4 * 4 + 0][r] = a4.x;
            As[c4 * 4 + 1][r] = a4.y;
            As[c4 * 4 + 2][r] = a4.z;
            As[c4 * 4 + 3][r] = a4.w;
        }
        {
            int c  = t >> 2;
            int c4 = t & 3;
            const float4 w4 = *reinterpret_cast<const float4*>(&W0[(size_t)(o0 + c) * K + k0 + c4 * 4]);
            Ws[c4 * 4 + 0][c] = w4.x;
            Ws[c4 * 4 + 1][c] = w4.y;
            Ws[c4 * 4 + 2][c] = w4.z;
            Ws[c4 * 4 + 3][c] = w4.w;
        }
        __syncthreads();

        float sacc[8][4];
        #pragma unroll
        for (int i = 0; i < 8; ++i)
            #pragma unroll
            for (int j = 0; j < 4; ++j) sacc[i][j] = 0.f;

        #pragma unroll
        for (int kk = 0; kk < 16; ++kk) {
            float a[8], bb[4];
            *reinterpret_cast<float4*>(&a[0])  = *reinterpret_cast<const float4*>(&As[kk][ty * 8]);
            *reinterpret_cast<float4*>(&a[4])  = *reinterpret_cast<const float4*>(&As[kk][ty * 8 + 4]);
            *reinterpret_cast<float4*>(&bb[0]) = *reinterpret_cast<const float4*>(&Ws[kk][tx * 4]);
            #pragma unroll
            for (int i = 0; i < 8; ++i)
                #pragma unroll
                for (int j = 0; j < 4; ++j)
                    sacc[i][j] += a[i] * bb[j];
        }
        #pragma unroll
        for (int i = 0; i < 8; ++i)
            #pragma unroll
            for (int j = 0; j < 4; ++j) acc[i][j] += (double)sacc[i][j];
        __syncthreads();
    }

    int oo = o0 + tx * 4;
    float* dst = (oo < 1024) ? outq : outk;
    oo &= 1023;
    const int hh = oo >> 6, d0 = oo & 63;
    #pragma unroll
    for (int i = 0; i < 8; ++i) {
        int m = m0 + ty * 8 + i;
        int bb_ = m >> 10, n = m & 1023;
        float4 r0 = make_float4((float)acc[i][0], (float)acc[i][1],
                                (float)acc[i][2], (float)acc[i][3]);
        *reinterpret_cast<float4*>(&dst[((((size_t)bb_ * H_) + hh) * N_ + n) * HD_ + d0]) = r0;
    }
}

// ---------------------------------------------------------------------------
// Plain f32 GEMM, tile 128x128 (damped paths: v and proj). (r7 version)
// ---------------------------------------------------------------------------
template<int MODE>
__global__ __launch_bounds__(256)
void gemm128_kernel(const float* __restrict__ A,
                    const float* __restrict__ W0,
                    const float* __restrict__ bias,
                    float* __restrict__ out0,
                    int M, int O, int K)
{
    __shared__ float As[16][132];
    __shared__ float Ws[16][132];

    const int t  = threadIdx.x;
    const int m0 = blockIdx.y * 128;
    const int o0 = blockIdx.x * 128;
    const int ty = t >> 4;
    const int tx = t & 15;

    float acc[8][8];
    #pragma unroll
    for (int i = 0; i < 8; ++i)
        #pragma unroll
        for (int j = 0; j < 8; ++j) acc[i][j] = 0.f;

    for (int k0 = 0; k0 < K; k0 += 16) {
        #pragma unroll
        for (int i = 0; i < 2; ++i) {
            int vix = t + i * 256;
            int r   = vix >> 2;
            int c4  = vix & 3;
            const float4 a4 = *reinterpret_cast<const float4*>(&A[(size_t)(m0 + r) * K + k0 + c4 * 4]);
            As[c4 * 4 + 0][r] = a4.x;
            As[c4 * 4 + 1][r] = a4.y;
            As[c4 * 4 + 2][r] = a4.z;
            As[c4 * 4 + 3][r] = a4.w;
        }
        #pragma unroll
        for (int i = 0; i < 2; ++i) {
            int vix = t + i * 256;
            int c   = vix >> 2;
            int c4  = vix & 3;
            const float4 w4 = *reinterpret_cast<const float4*>(&W0[(size_t)(o0 + c) * K + k0 + c4 * 4]);
            Ws[c4 * 4 + 0][c] = w4.x;
            Ws[c4 * 4 + 1][c] = w4.y;
            Ws[c4 * 4 + 2][c] = w4.z;
            Ws[c4 * 4 + 3][c] = w4.w;
        }
        __syncthreads();

        #pragma unroll
        for (int kk = 0; kk < 16; ++kk) {
            float a[8], bb[8];
            *reinterpret_cast<float4*>(&a[0])  = *reinterpret_cast<const float4*>(&As[kk][ty * 8]);
            *reinterpret_cast<float4*>(&a[4])  = *reinterpret_cast<const float4*>(&As[kk][ty * 8 + 4]);
            *reinterpret_cast<float4*>(&bb[0]) = *reinterpret_cast<const float4*>(&Ws[kk][tx * 8]);
            *reinterpret_cast<float4*>(&bb[4]) = *reinterpret_cast<const float4*>(&Ws[kk][tx * 8 + 4]);
            #pragma unroll
            for (int i = 0; i < 8; ++i)
                #pragma unroll
                for (int j = 0; j < 8; ++j)
                    acc[i][j] += a[i] * bb[j];
        }
        __syncthreads();
    }

    if (MODE == 1) {
        float bs[8];
        *reinterpret_cast<float4*>(&bs[0]) = *reinterpret_cast<const float4*>(&bias[o0 + tx * 8]);
        *reinterpret_cast<float4*>(&bs[4]) = *reinterpret_cast<const float4*>(&bias[o0 + tx * 8 + 4]);
        #pragma unroll
        for (int i = 0; i < 8; ++i) {
            int m = m0 + ty * 8 + i;
            float* p = &out0[(size_t)m * O + o0 + tx * 8];
            float4 r0 = make_float4(acc[i][0] + bs[0], acc[i][1] + bs[1], acc[i][2] + bs[2], acc[i][3] + bs[3]);
            float4 r1 = make_float4(acc[i][4] + bs[4], acc[i][5] + bs[5], acc[i][6] + bs[6], acc[i][7] + bs[7]);
            *reinterpret_cast<float4*>(p)     = r0;
            *reinterpret_cast<float4*>(p + 4) = r1;
        }
    } else {
        int oo = o0 + tx * 8;
        const int hh = oo >> 6, d0 = oo & 63;
        #pragma unroll
        for (int i = 0; i < 8; ++i) {
            int m = m0 + ty * 8 + i;
            int bb_ = m >> 10, n = m & 1023;
            float* p = &out0[((((size_t)bb_ * H_) + hh) * N_ + n) * HD_ + d0];
            *reinterpret_cast<float4*>(p)     = make_float4(acc[i][0], acc[i][1], acc[i][2], acc[i][3]);
            *reinterpret_cast<float4*>(p + 4) = make_float4(acc[i][4], acc[i][5], acc[i][6], acc[i][7]);
        }
    }
}

// ---------------------------------------------------------------------------
__global__ void wsum_kernel(const float* __restrict__ W_v, double* __restrict__ wsh)
{
    const int k = blockIdx.x * 256 + threadIdx.x;
    const int h = blockIdx.y;
    double s = 0.0;
    #pragma unroll 8
    for (int d = 0; d < 64; ++d) s += (double)W_v[(size_t)(h * 64 + d) * C_ + k];
    wsh[h * C_ + k] = s;
}

__global__ __launch_bounds__(256)
void vall_kernel(const float* __restrict__ x, const double* __restrict__ wsh,
                 double* __restrict__ Vall)
{
    __shared__ double ws_s[1024];
    const int h = blockIdx.y, b = blockIdx.z;
    const int m = blockIdx.x * 256 + threadIdx.x;
    for (int i = threadIdx.x; i < 1024; i += 256) ws_s[i] = wsh[h * C_ + i];
    __syncthreads();
    const float* xr = x + ((size_t)b * N_ + m) * C_;
    double acc = 0.0;
    #pragma unroll 8
    for (int kk = 0; kk < 1024; ++kk) acc += (double)xr[kk] * ws_s[kk];
    Vall[((size_t)b * H_ + h) * N_ + m] = acc;
}

// ---------------------------------------------------------------------------
// Fused attention r10 = r7 + Q off the LDS pipe.
//  - Structure, mapping, LDS layout, barriers: byte-identical to r7 EXCEPT
//    Qs4 removed; QK reads Q via wave-uniform global pointers (readfirstlane
//    -> SGPR base -> SMEM/L1-broadcast; not on the LDS pipe).
//  - qc stays in LDS (cheap b32 broadcasts); PV keeps 8 scalar f32 accs.
//  - LDS 41472B -> 3 blocks/CU, expected VGPR ~84-96 (no spill).
// ---------------------------------------------------------------------------
__global__ __launch_bounds__(256)
void attn_kernel(const float* __restrict__ q,
                 const float* __restrict__ k,
                 const float* __restrict__ v,
                 const double* __restrict__ Vall,   // [B][H][N]
                 const float* __restrict__ coord,   // [B][N][3]
                 const float* __restrict__ W_pos,   // [H][4]
                 const float* __restrict__ gating,  // [H]
                 float* __restrict__ attn_out)      // [B][N][C]
{
    __shared__ float4 Kt4[2][64][16];              // 32KB double-buffered K
    __shared__ __align__(16) float pt[16][64];     // 4KB (wave-private rows)
    __shared__ __align__(16) float qt[16][64];     // 4KB
    __shared__ float qc[16][3];

    const int t  = threadIdx.x;
    const int wu = __builtin_amdgcn_readfirstlane(t >> 6);  // wave id (SGPR)
    const int l  = t & 63;
    const int n0 = blockIdx.x * 16;
    const int h  = blockIdx.y;
    const int b  = blockIdx.z;
    const size_t bhN = ((size_t)b * H_ + h) * N_;

    // staging indices (4 vectors/tile/thread)
    const int sr0 = t >> 4;
    const int sc  = t & 15;

    // wave-uniform Q row pointers (global; off the LDS pipe)
    const float4* qr0 = reinterpret_cast<const float4*>(q + (bhN + n0 + wu     ) * HD_);
    const float4* qr1 = reinterpret_cast<const float4*>(q + (bhN + n0 + wu + 4 ) * HD_);
    const float4* qr2 = reinterpret_cast<const float4*>(q + (bhN + n0 + wu + 8 ) * HD_);
    const float4* qr3 = reinterpret_cast<const float4*>(q + (bhN + n0 + wu + 12) * HD_);

    if (t < 48) qc[t / 3][t % 3] = coord[((size_t)b * N_ + n0 + t / 3) * 3 + (t % 3)];
    const double w4hd = (double)W_pos[h * 4 + 3];
    const double ghd  = 1.0 / (1.0 + exp(-(double)gating[h]));

    double sp[4], sq[4], spv[4], sqv[4];
    float accp[4], accq[4];
    #pragma unroll
    for (int i = 0; i < 4; ++i) {
        sp[i] = 0.0; sq[i] = 0.0; spv[i] = 0.0; sqv[i] = 0.0;
        accp[i] = 0.f; accq[i] = 0.f;
    }

    // ---- prologue: stage tile 0 + its Vm/coord
    {
        const float4* kb4 = reinterpret_cast<const float4*>(k + bhN * HD_);
        #pragma unroll
        for (int i = 0; i < 4; ++i)
            Kt4[0][sr0 + i * 16][sc ^ ((sr0 + i * 16) & 15)] = kb4[t + i * 256];
    }
    double Vm  = Vall[bhN + l];
    double cmx = (double)coord[((size_t)b * N_ + l) * 3 + 0];
    double cmy = (double)coord[((size_t)b * N_ + l) * 3 + 1];
    double cmz = (double)coord[((size_t)b * N_ + l) * 3 + 2];
    __syncthreads();

    for (int t16 = 0; t16 < 16; ++t16) {
        const int cur = t16 & 1;
        const int m0  = t16 * 64;

        // ---- (1) issue next tile's loads (in flight through compute)
        float4 st0, st1, st2, st3;
        double VmN = 0.0, cmxN = 0.0, cmyN = 0.0, cmzN = 0.0;
        if (t16 < 15) {
            const float4* kb4 = reinterpret_cast<const float4*>(k + (bhN + m0 + 64) * HD_);
            st0 = kb4[t];
            st1 = kb4[t + 256];
            st2 = kb4[t + 512];
            st3 = kb4[t + 768];
            VmN  = Vall[bhN + m0 + 64 + l];
            cmxN = (double)coord[((size_t)b * N_ + m0 + 64 + l) * 3 + 0];
            cmyN = (double)coord[((size_t)b * N_ + m0 + 64 + l) * 3 + 1];
            cmzN = (double)coord[((size_t)b * N_ + m0 + 64 + l) * 3 + 2];
        }

        // ---- (2) QK^T: K from Kt4[cur] (LDS), Q via uniform global reads
        float dotp[4][4];
        #pragma unroll
        for (int i = 0; i < 4; ++i)
            #pragma unroll
            for (int g = 0; g < 4; ++g) dotp[i][g] = 0.f;
        #pragma unroll
        for (int d4 = 0; d4 < 16; ++d4) {
            const float4 kt = Kt4[cur][l][d4 ^ (l & 15)];
            const int g = d4 >> 2;
            const float4 q0 = qr0[d4];
            const float4 q1 = qr1[d4];
            const float4 q2 = qr2[d4];
            const float4 q3 = qr3[d4];
            float s0 = dotp[0][g], s1 = dotp[1][g], s2 = dotp[2][g], s3 = dotp[3][g];
            s0 = fmaf(kt.x, q0.x, s0); s0 = fmaf(kt.y, q0.y, s0);
            s0 = fmaf(kt.z, q0.z, s0); s0 = fmaf(kt.w, q0.w, s0);
            s1 = fmaf(kt.x, q1.x, s1); s1 = fmaf(kt.y, q1.y, s1);
            s1 = fmaf(kt.z, q1.z, s1); s1 = fmaf(kt.w, q1.w, s1);
            s2 = fmaf(kt.x, q2.x, s2); s2 = fmaf(kt.y, q2.y, s2);
            s2 = fmaf(kt.z, q2.z, s2); s2 = fmaf(kt.w, q2.w, s2);
            s3 = fmaf(kt.x, q3.x, s3); s3 = fmaf(kt.y, q3.y, s3);
            s3 = fmaf(kt.z, q3.z, s3); s3 = fmaf(kt.w, q3.w, s3);
            dotp[0][g] = s0; dotp[1][g] = s1; dotp[2][g] = s2; dotp[3][g] = s3;
        }

        // ---- (3) f64 weights + S-path updates (lane = m = m0+l)
        #pragma unroll
        for (int i = 0; i < 4; ++i) {
            const int r = wu + 4 * i;
            const double lg = (((double)dotp[i][0] + (double)dotp[i][1]) +
                               ((double)dotp[i][2] + (double)dotp[i][3])) * 0.125;
            const double p64 = fast_exp64(lg);
            const double dx = (double)qc[r][0] - cmx;
            const double dy = (double)qc[r][1] - cmy;
            const double dz = (double)qc[r][2] - cmz;
            const double r2 = __fma_rn(dx, dx, __fma_rn(dy, dy, dz * dz));
            const double y0 = (double)rsqrtf((float)r2);
            const double y1 = y0 * __fma_rn(-0.5 * r2, y0 * y0, 1.5);
            const double dist = (r2 > 0.0) ? r2 * y1 : 0.0;
            const double q64 = fast_exp64(dist * w4hd);
            pt[r][l] = (float)p64;
            qt[r][l] = (float)q64;
            sp[i]  += p64;
            sq[i]  += q64;
            spv[i] += p64 * Vm;
            sqv[i] += q64 * Vm;
        }

        // ---- (4) PV: lane = output dim l, rows wu+4i; V direct from global
        const float* vbase = v + (bhN + m0) * HD_ + l;
        #pragma unroll 4
        for (int ml4 = 0; ml4 < 16; ++ml4) {
            float vt0 = vbase[(ml4 * 4 + 0) * HD_];
            float vt1 = vbase[(ml4 * 4 + 1) * HD_];
            float vt2 = vbase[(ml4 * 4 + 2) * HD_];
            float vt3 = vbase[(ml4 * 4 + 3) * HD_];
            #pragma unroll
            for (int i = 0; i < 4; ++i) {
                const float4 pp = *reinterpret_cast<const float4*>(&pt[wu + 4 * i][ml4 * 4]);
                const float4 pq = *reinterpret_cast<const float4*>(&qt[wu + 4 * i][ml4 * 4]);
                float ap = accp[i], aq = accq[i];
                ap = fmaf(pp.x, vt0, ap); aq = fmaf(pq.x, vt0, aq);
                ap = fmaf(pp.y, vt1, ap); aq = fmaf(pq.y, vt1, aq);
                ap = fmaf(pp.z, vt2, ap); aq = fmaf(pq.z, vt2, aq);
                ap = fmaf(pp.w, vt3, ap); aq = fmaf(pq.w, vt3, aq);
                accp[i] = ap; accq[i] = aq;
            }
        }

        // ---- (5) write staged K into other buffer; roll Vm/coord
        if (t16 < 15) {
            const int nxt = cur ^ 1;
            Kt4[nxt][sr0     ][sc ^ ( sr0       & 15)] = st0;
            Kt4[nxt][sr0 + 16][sc ^ ((sr0 + 16) & 15)] = st1;
            Kt4[nxt][sr0 + 32][sc ^ ((sr0 + 32) & 15)] = st2;
            Kt4[nxt][sr0 + 48][sc ^ ((sr0 + 48) & 15)] = st3;
            Vm = VmN; cmx = cmxN; cmy = cmyN; cmz = cmzN;
        }
        // ---- (6) single barrier per tile
        __syncthreads();
    }

    // ---- epilogue: f64 reduce, combine, normalize, store (lane = dim l)
    #pragma unroll
    for (int i = 0; i < 4; ++i) {
        double vsp = sp[i], vsq = sq[i], vspv = spv[i], vsqv = sqv[i];
        #pragma unroll
        for (int mm = 32; mm >= 1; mm >>= 1) {
            vsp  += __shfl_xor(vsp,  mm);
            vsq  += __shfl_xor(vsq,  mm);
            vspv += __shfl_xor(vspv, mm);
            vsqv += __shfl_xor(vsqv, mm);
        }
        const double w1 = (1.0 - ghd) / vsp;
        const double w2 = ghd / vsq;
        const double S  = w1 * vspv + w2 * vsqv;
        const double a  = w1 * (double)accp[i] + w2 * (double)accq[i];
        attn_out[((size_t)b * N_ + n0 + (wu + 4 * i)) * C_ + h * HD_ + l] = (float)(a / S);
    }
}

// ---------------------------------------------------------------------------
extern "C" void kernel_launch(void* const* d_in, const int* in_sizes, int n_in,
                              void* d_out, int out_size, void* d_ws, size_t ws_size,
                              hipStream_t stream)
{
    const float* x      = (const float*)d_in[0];
    const float* coord  = (const float*)d_in[1];
    const float* W_qk   = (const float*)d_in[2];
    const float* W_v    = (const float*)d_in[3];
    const float* W_proj = (const float*)d_in[4];
    const float* b_proj = (const float*)d_in[5];
    const float* W_pos  = (const float*)d_in[6];
    // d_in[7] = b_pos (cancels in softmax), d_in[9] = pos_emb (cancels) — unused
    const float* gating = (const float*)d_in[8];

    float* ws   = (float*)d_ws;
    const size_t per = (size_t)B_ * H_ * N_ * HD_;   // 4,194,304 floats
    float*  qb   = ws;
    float*  kb   = qb + per;
    float*  vb   = kb + per;
    float*  attn = vb + per;
    double* wsh  = (double*)(attn + per);
    double* Vall = wsh + (size_t)H_ * C_;
    float*  out  = (float*)d_out;

    wsum_kernel<<<dim3(4, 16), 256, 0, stream>>>(W_v, wsh);
    vall_kernel<<<dim3(4, 16, 4), 256, 0, stream>>>(x, wsh, Vall);

    gemm_qk_kernel<<<dim3(32, 32), 256, 0, stream>>>(x, W_qk, qb, kb, B_ * N_, C_);
    gemm128_kernel<0><<<dim3(8, 32), 256, 0, stream>>>(x, W_v, nullptr, vb, B_ * N_, C_, C_);

    attn_kernel<<<dim3(N_ / 16, H_, B_), 256, 0, stream>>>(
        qb, kb, vb, Vall, coord, W_pos, gating, attn);

    gemm128_kernel<1><<<dim3(8, 32), 256, 0, stream>>>(
        attn, W_proj, b_proj, out, B_ * N_, C_, C_);
}

// Round 11
// 1363.927 us; speedup vs baseline: 1.3142x; 1.0787x over previous
//
#include <hip/hip_runtime.h>
#include <math.h>

#define B_ 4
#define N_ 1024
#define C_ 1024
#define H_ 16
#define HD_ 64

typedef float f32x2 __attribute__((ext_vector_type(2)));

// packed 2xf32 fma -> v_pk_fma_f32 on gfx950 (157TF peak needs packed)
__device__ __forceinline__ f32x2 pk_fma(f32x2 a, f32x2 b, f32x2 c) {
#if __has_builtin(__builtin_elementwise_fma)
    return __builtin_elementwise_fma(a, b, c);
#else
    f32x2 r; r.x = fmaf(a.x, b.x, c.x); r.y = fmaf(a.y, b.y, c.y); return r;
#endif
}

// ---------------------------------------------------------------------------
// ERROR MODEL (validated r4/r6/r7/r10: absmax 16 vs threshold 97):
//   S = (1-g)*spv/sp + g*sqv/sq ~ 4e-5 from cancellation; budget dS ~1.3e-7
//   => weight rel err <= 4e-8 for BOTH softmaxes -> f64 logits+exp
//   (fast_exp64, 3e-10). V_m exact via f64 wsum collapse. q,k <1e-7 ->
//   slab-f64 GEMM (16-term f32 partials). DAMPED paths: v, PV, proj = f32.
// PERF MODEL:
//   - r7 attn structure (Q in LDS, K dbuf, 1 barrier/tile) = verified best.
//   - Kernel is VALU-ISSUE-bound (dur ~ VALU/0.65; r10: Q-off-LDS hurt).
//   - r11 lever: v_pk_fma_f32 packing. QK pairs dims (partial-split layout
//     preserved), PV pairs keys, GEMMs pair output columns. No structural
//     or numerical change elsewhere. VGPR budget: keep < ~100 (spill @~140).
// ---------------------------------------------------------------------------

// fast f64 exp for |a| <= ~16: range-reduce + deg-8 Taylor. rel err ~3e-10.
__device__ __forceinline__ double fast_exp64(double a) {
    const double LOG2E = 1.4426950408889634074;
    const double LN2HI = 6.93147180369123816490e-01;
    const double LN2LO = 1.90821492927058770002e-10;
    const double MAGIC = 6755399441055744.0;   // 1.5 * 2^52
    double t     = a * LOG2E;
    double shift = t + MAGIC;
    int    n     = (int)__double_as_longlong(shift);
    double nd    = shift - MAGIC;
    double f     = __fma_rn(nd, -LN2HI, a);
    f            = __fma_rn(nd, -LN2LO, f);
    double p = 2.4801587301587301587e-05;
    p = __fma_rn(p, f, 1.9841269841269841270e-04);
    p = __fma_rn(p, f, 1.3888888888888888889e-03);
    p = __fma_rn(p, f, 8.3333333333333333333e-03);
    p = __fma_rn(p, f, 4.1666666666666666667e-02);
    p = __fma_rn(p, f, 1.6666666666666666667e-01);
    p = __fma_rn(p, f, 5.0e-01);
    p = __fma_rn(p, f, 1.0);
    p = __fma_rn(p, f, 1.0);
    return p * __longlong_as_double(((long long)(1023 + n)) << 52);
}

// ---------------------------------------------------------------------------
// Slab-compensated GEMM for q,k (O=2048). Tile 128x64, f32 slabs -> f64.
// r11: packed inner loop (v_pk_fma_f32), 16-term partials preserved.
// ---------------------------------------------------------------------------
__global__ __launch_bounds__(256)
void gemm_qk_kernel(const float* __restrict__ A,
                    const float* __restrict__ W0,   // W_qk rows 0..2047
                    float* __restrict__ outq,
                    float* __restrict__ outk,
                    int M, int K)
{
    __shared__ float As[16][132];
    __shared__ float Ws[16][68];

    const int t  = threadIdx.x;
    const int m0 = blockIdx.y * 128;
    const int o0 = blockIdx.x * 64;
    const int ty = t >> 4;
    const int tx = t & 15;

    double acc[8][4];
    #pragma unroll
    for (int i = 0; i < 8; ++i)
        #pragma unroll
        for (int j = 0; j < 4; ++j) acc[i][j] = 0.0;

    for (int k0 = 0; k0 < K; k0 += 16) {
        #pragma unroll
        for (int i = 0; i < 2; ++i) {
            int vix = t + i * 256;
            int r   = vix >> 2;
            int c4  = vix & 3;
            const float4 a4 = *reinterpret_cast<const float4*>(&A[(size_t)(m0 + r) * K + k0 + c4 * 4]);
            As[c4 * 4 + 0][r] = a4.x;
            As[c4 * 4 + 1][r] = a4.y;
            As[c4 * 4 + 2][r] = a4.z;
            As[c4 * 4 + 3][r] = a4.w;
        }
        {
            int c  = t >> 2;
            int c4 = t & 3;
            const float4 w4 = *reinterpret_cast<const float4*>(&W0[(size_t)(o0 + c) * K + k0 + c4 * 4]);
            Ws[c4 * 4 + 0][c] = w4.x;
            Ws[c4 * 4 + 1][c] = w4.y;
            Ws[c4 * 4 + 2][c] = w4.z;
            Ws[c4 * 4 + 3][c] = w4.w;
        }
        __syncthreads();

        f32x2 sacc[8][2];
        #pragma unroll
        for (int i = 0; i < 8; ++i)
            #pragma unroll
            for (int j = 0; j < 2; ++j) sacc[i][j] = (f32x2){0.f, 0.f};

        #pragma unroll
        for (int kk = 0; kk < 16; ++kk) {
            float a[8];
            *reinterpret_cast<float4*>(&a[0]) = *reinterpret_cast<const float4*>(&As[kk][ty * 8]);
            *reinterpret_cast<float4*>(&a[4]) = *reinterpret_cast<const float4*>(&As[kk][ty * 8 + 4]);
            const float4 wv = *reinterpret_cast<const float4*>(&Ws[kk][tx * 4]);
            const f32x2 b0 = {wv.x, wv.y};
            const f32x2 b1 = {wv.z, wv.w};
            #pragma unroll
            for (int i = 0; i < 8; ++i) {
                const f32x2 av = {a[i], a[i]};
                sacc[i][0] = pk_fma(av, b0, sacc[i][0]);
                sacc[i][1] = pk_fma(av, b1, sacc[i][1]);
            }
        }
        #pragma unroll
        for (int i = 0; i < 8; ++i) {
            acc[i][0] += (double)sacc[i][0].x;
            acc[i][1] += (double)sacc[i][0].y;
            acc[i][2] += (double)sacc[i][1].x;
            acc[i][3] += (double)sacc[i][1].y;
        }
        __syncthreads();
    }

    int oo = o0 + tx * 4;
    float* dst = (oo < 1024) ? outq : outk;
    oo &= 1023;
    const int hh = oo >> 6, d0 = oo & 63;
    #pragma unroll
    for (int i = 0; i < 8; ++i) {
        int m = m0 + ty * 8 + i;
        int bb_ = m >> 10, n = m & 1023;
        float4 r0 = make_float4((float)acc[i][0], (float)acc[i][1],
                                (float)acc[i][2], (float)acc[i][3]);
        *reinterpret_cast<float4*>(&dst[((((size_t)bb_ * H_) + hh) * N_ + n) * HD_ + d0]) = r0;
    }
}

// ---------------------------------------------------------------------------
// Plain f32 GEMM, tile 128x128 (damped paths: v and proj), packed inner.
// ---------------------------------------------------------------------------
template<int MODE>
__global__ __launch_bounds__(256)
void gemm128_kernel(const float* __restrict__ A,
                    const float* __restrict__ W0,
                    const float* __restrict__ bias,
                    float* __restrict__ out0,
                    int M, int O, int K)
{
    __shared__ float As[16][132];
    __shared__ float Ws[16][132];

    const int t  = threadIdx.x;
    const int m0 = blockIdx.y * 128;
    const int o0 = blockIdx.x * 128;
    const int ty = t >> 4;
    const int tx = t & 15;

    f32x2 acc2[8][4];
    #pragma unroll
    for (int i = 0; i < 8; ++i)
        #pragma unroll
        for (int j = 0; j < 4; ++j) acc2[i][j] = (f32x2){0.f, 0.f};

    for (int k0 = 0; k0 < K; k0 += 16) {
        #pragma unroll
        for (int i = 0; i < 2; ++i) {
            int vix = t + i * 256;
            int r   = vix >> 2;
            int c4  = vix & 3;
            const float4 a4 = *reinterpret_cast<const float4*>(&A[(size_t)(m0 + r) * K + k0 + c4 * 4]);
            As[c4 * 4 + 0][r] = a4.x;
            As[c4 * 4 + 1][r] = a4.y;
            As[c4 * 4 + 2][r] = a4.z;
            As[c4 * 4 + 3][r] = a4.w;
        }
        #pragma unroll
        for (int i = 0; i < 2; ++i) {
            int vix = t + i * 256;
            int c   = vix >> 2;
            int c4  = vix & 3;
            const float4 w4 = *reinterpret_cast<const float4*>(&W0[(size_t)(o0 + c) * K + k0 + c4 * 4]);
            Ws[c4 * 4 + 0][c] = w4.x;
            Ws[c4 * 4 + 1][c] = w4.y;
            Ws[c4 * 4 + 2][c] = w4.z;
            Ws[c4 * 4 + 3][c] = w4.w;
        }
        __syncthreads();

        #pragma unroll
        for (int kk = 0; kk < 16; ++kk) {
            float a[8];
            *reinterpret_cast<float4*>(&a[0]) = *reinterpret_cast<const float4*>(&As[kk][ty * 8]);
            *reinterpret_cast<float4*>(&a[4]) = *reinterpret_cast<const float4*>(&As[kk][ty * 8 + 4]);
            const float4 w01 = *reinterpret_cast<const float4*>(&Ws[kk][tx * 8]);
            const float4 w23 = *reinterpret_cast<const float4*>(&Ws[kk][tx * 8 + 4]);
            const f32x2 b0 = {w01.x, w01.y};
            const f32x2 b1 = {w01.z, w01.w};
            const f32x2 b2 = {w23.x, w23.y};
            const f32x2 b3 = {w23.z, w23.w};
            #pragma unroll
            for (int i = 0; i < 8; ++i) {
                const f32x2 av = {a[i], a[i]};
                acc2[i][0] = pk_fma(av, b0, acc2[i][0]);
                acc2[i][1] = pk_fma(av, b1, acc2[i][1]);
                acc2[i][2] = pk_fma(av, b2, acc2[i][2]);
                acc2[i][3] = pk_fma(av, b3, acc2[i][3]);
            }
        }
        __syncthreads();
    }

    if (MODE == 1) {
        float bs[8];
        *reinterpret_cast<float4*>(&bs[0]) = *reinterpret_cast<const float4*>(&bias[o0 + tx * 8]);
        *reinterpret_cast<float4*>(&bs[4]) = *reinterpret_cast<const float4*>(&bias[o0 + tx * 8 + 4]);
        #pragma unroll
        for (int i = 0; i < 8; ++i) {
            int m = m0 + ty * 8 + i;
            float* p = &out0[(size_t)m * O + o0 + tx * 8];
            float4 r0 = make_float4(acc2[i][0].x + bs[0], acc2[i][0].y + bs[1],
                                    acc2[i][1].x + bs[2], acc2[i][1].y + bs[3]);
            float4 r1 = make_float4(acc2[i][2].x + bs[4], acc2[i][2].y + bs[5],
                                    acc2[i][3].x + bs[6], acc2[i][3].y + bs[7]);
            *reinterpret_cast<float4*>(p)     = r0;
            *reinterpret_cast<float4*>(p + 4) = r1;
        }
    } else {
        int oo = o0 + tx * 8;
        const int hh = oo >> 6, d0 = oo & 63;
        #pragma unroll
        for (int i = 0; i < 8; ++i) {
            int m = m0 + ty * 8 + i;
            int bb_ = m >> 10, n = m & 1023;
            float* p = &out0[((((size_t)bb_ * H_) + hh) * N_ + n) * HD_ + d0];
            *reinterpret_cast<float4*>(p)     = make_float4(acc2[i][0].x, acc2[i][0].y,
                                                            acc2[i][1].x, acc2[i][1].y);
            *reinterpret_cast<float4*>(p + 4) = make_float4(acc2[i][2].x, acc2[i][2].y,
                                                            acc2[i][3].x, acc2[i][3].y);
        }
    }
}

// ---------------------------------------------------------------------------
__global__ void wsum_kernel(const float* __restrict__ W_v, double* __restrict__ wsh)
{
    const int k = blockIdx.x * 256 + threadIdx.x;
    const int h = blockIdx.y;
    double s = 0.0;
    #pragma unroll 8
    for (int d = 0; d < 64; ++d) s += (double)W_v[(size_t)(h * 64 + d) * C_ + k];
    wsh[h * C_ + k] = s;
}

__global__ __launch_bounds__(256)
void vall_kernel(const float* __restrict__ x, const double* __restrict__ wsh,
                 double* __restrict__ Vall)
{
    __shared__ double ws_s[1024];
    const int h = blockIdx.y, b = blockIdx.z;
    const int m = blockIdx.x * 256 + threadIdx.x;
    for (int i = threadIdx.x; i < 1024; i += 256) ws_s[i] = wsh[h * C_ + i];
    __syncthreads();
    const float* xr = x + ((size_t)b * N_ + m) * C_;
    double acc = 0.0;
    #pragma unroll 8
    for (int kk = 0; kk < 1024; ++kk) acc += (double)xr[kk] * ws_s[kk];
    Vall[((size_t)b * H_ + h) * N_ + m] = acc;
}

// ---------------------------------------------------------------------------
// Fused attention r11 = r7 structure (verified best: Q in LDS, K dbuf,
// async stage, 1 barrier/tile) + packed f32 QK and PV:
//  - QK: dot2[i][g] f32x2, pairs (kt.xy,q.xy)/(kt.zw,q.zw). Each half = 16
//    terms -> SAME 4-partial f64 combine as r7 (precision preserved).
//  - PV: acc f32x2 pairs adjacent keys; pt/qt float4 .xy/.zw are adjacent
//    subregs; v scalars load directly into f32x2 halves. +8 VGPR.
// ---------------------------------------------------------------------------
__global__ __launch_bounds__(256)
void attn_kernel(const float* __restrict__ q,
                 const float* __restrict__ k,
                 const float* __restrict__ v,
                 const double* __restrict__ Vall,   // [B][H][N]
                 const float* __restrict__ coord,   // [B][N][3]
                 const float* __restrict__ W_pos,   // [H][4]
                 const float* __restrict__ gating,  // [H]
                 float* __restrict__ attn_out)      // [B][N][C]
{
    __shared__ float4 Qs4[16][16];                 // 4KB
    __shared__ float4 Kt4[2][64][16];              // 32KB double-buffered K
    __shared__ __align__(16) float pt[16][64];     // 4KB (wave-private rows)
    __shared__ __align__(16) float qt[16][64];     // 4KB
    __shared__ float qc[16][3];

    const int t  = threadIdx.x;
    const int w  = t >> 6;     // wave 0..3, owns rows {w, w+4, w+8, w+12}
    const int l  = t & 63;
    const int n0 = blockIdx.x * 16;
    const int h  = blockIdx.y;
    const int b  = blockIdx.z;
    const size_t bhN = ((size_t)b * H_ + h) * N_;

    // staging indices (4 vectors/tile/thread)
    const int sr0 = t >> 4;
    const int sc  = t & 15;

    Qs4[t >> 4][t & 15] = reinterpret_cast<const float4*>(q + (bhN + n0) * HD_)[t];
    if (t < 48) qc[t / 3][t % 3] = coord[((size_t)b * N_ + n0 + t / 3) * 3 + (t % 3)];
    const double w4hd = (double)W_pos[h * 4 + 3];
    const double ghd  = 1.0 / (1.0 + exp(-(double)gating[h]));

    double sp[4], sq[4], spv[4], sqv[4];
    f32x2 ap2[4], aq2[4];
    #pragma unroll
    for (int i = 0; i < 4; ++i) {
        sp[i] = 0.0; sq[i] = 0.0; spv[i] = 0.0; sqv[i] = 0.0;
        ap2[i] = (f32x2){0.f, 0.f};
        aq2[i] = (f32x2){0.f, 0.f};
    }

    // ---- prologue: stage tile 0 + its Vm/coord
    {
        const float4* kb4 = reinterpret_cast<const float4*>(k + bhN * HD_);
        #pragma unroll
        for (int i = 0; i < 4; ++i)
            Kt4[0][sr0 + i * 16][sc ^ ((sr0 + i * 16) & 15)] = kb4[t + i * 256];
    }
    double Vm  = Vall[bhN + l];
    double cmx = (double)coord[((size_t)b * N_ + l) * 3 + 0];
    double cmy = (double)coord[((size_t)b * N_ + l) * 3 + 1];
    double cmz = (double)coord[((size_t)b * N_ + l) * 3 + 2];
    __syncthreads();

    for (int t16 = 0; t16 < 16; ++t16) {
        const int cur = t16 & 1;
        const int m0  = t16 * 64;

        // ---- (1) issue next tile's loads (stay in flight through compute)
        float4 st0, st1, st2, st3;
        double VmN = 0.0, cmxN = 0.0, cmyN = 0.0, cmzN = 0.0;
        if (t16 < 15) {
            const float4* kb4 = reinterpret_cast<const float4*>(k + (bhN + m0 + 64) * HD_);
            st0 = kb4[t];
            st1 = kb4[t + 256];
            st2 = kb4[t + 512];
            st3 = kb4[t + 768];
            VmN  = Vall[bhN + m0 + 64 + l];
            cmxN = (double)coord[((size_t)b * N_ + m0 + 64 + l) * 3 + 0];
            cmyN = (double)coord[((size_t)b * N_ + m0 + 64 + l) * 3 + 1];
            cmzN = (double)coord[((size_t)b * N_ + m0 + 64 + l) * 3 + 2];
        }

        // ---- (2) QK^T from Kt4[cur], packed over dim pairs
        f32x2 dot2[4][2];
        #pragma unroll
        for (int i = 0; i < 4; ++i) {
            dot2[i][0] = (f32x2){0.f, 0.f};
            dot2[i][1] = (f32x2){0.f, 0.f};
        }
        #pragma unroll
        for (int d4 = 0; d4 < 16; ++d4) {
            const float4 kt = Kt4[cur][l][d4 ^ (l & 15)];
            const int g = d4 >> 3;
            const f32x2 kxy = {kt.x, kt.y};
            const f32x2 kzw = {kt.z, kt.w};
            #pragma unroll
            for (int i = 0; i < 4; ++i) {
                const float4 q4 = Qs4[w + 4 * i][d4];
                const f32x2 qxy = {q4.x, q4.y};
                const f32x2 qzw = {q4.z, q4.w};
                dot2[i][g] = pk_fma(kxy, qxy, dot2[i][g]);
                dot2[i][g] = pk_fma(kzw, qzw, dot2[i][g]);
            }
        }

        // ---- (3) f64 weights + S-path updates (lane = m = m0+l)
        #pragma unroll
        for (int i = 0; i < 4; ++i) {
            const int r = w + 4 * i;
            const double lg = (((double)dot2[i][0].x + (double)dot2[i][0].y) +
                               ((double)dot2[i][1].x + (double)dot2[i][1].y)) * 0.125;
            const double p64 = fast_exp64(lg);
            const double dx = (double)qc[r][0] - cmx;
            const double dy = (double)qc[r][1] - cmy;
            const double dz = (double)qc[r][2] - cmz;
            const double r2 = __fma_rn(dx, dx, __fma_rn(dy, dy, dz * dz));
            const double y0 = (double)rsqrtf((float)r2);
            const double y1 = y0 * __fma_rn(-0.5 * r2, y0 * y0, 1.5);
            const double dist = (r2 > 0.0) ? r2 * y1 : 0.0;
            const double q64 = fast_exp64(dist * w4hd);
            pt[r][l] = (float)p64;
            qt[r][l] = (float)q64;
            sp[i]  += p64;
            sq[i]  += q64;
            spv[i] += p64 * Vm;
            sqv[i] += q64 * Vm;
        }

        // ---- (4) PV packed over adjacent keys: lane = output dim l
        const float* vbase = v + (bhN + m0) * HD_ + l;
        #pragma unroll 4
        for (int ml4 = 0; ml4 < 16; ++ml4) {
            f32x2 vt01, vt23;
            vt01.x = vbase[(ml4 * 4 + 0) * HD_];
            vt01.y = vbase[(ml4 * 4 + 1) * HD_];
            vt23.x = vbase[(ml4 * 4 + 2) * HD_];
            vt23.y = vbase[(ml4 * 4 + 3) * HD_];
            #pragma unroll
            for (int i = 0; i < 4; ++i) {
                const float4 pp = *reinterpret_cast<const float4*>(&pt[w + 4 * i][ml4 * 4]);
                const float4 pq = *reinterpret_cast<const float4*>(&qt[w + 4 * i][ml4 * 4]);
                ap2[i] = pk_fma((f32x2){pp.x, pp.y}, vt01, ap2[i]);
                ap2[i] = pk_fma((f32x2){pp.z, pp.w}, vt23, ap2[i]);
                aq2[i] = pk_fma((f32x2){pq.x, pq.y}, vt01, aq2[i]);
                aq2[i] = pk_fma((f32x2){pq.z, pq.w}, vt23, aq2[i]);
            }
        }

        // ---- (5) write staged K into other buffer; roll Vm/coord
        if (t16 < 15) {
            const int nxt = cur ^ 1;
            Kt4[nxt][sr0     ][sc ^ ( sr0       & 15)] = st0;
            Kt4[nxt][sr0 + 16][sc ^ ((sr0 + 16) & 15)] = st1;
            Kt4[nxt][sr0 + 32][sc ^ ((sr0 + 32) & 15)] = st2;
            Kt4[nxt][sr0 + 48][sc ^ ((sr0 + 48) & 15)] = st3;
            Vm = VmN; cmx = cmxN; cmy = cmyN; cmz = cmzN;
        }
        // ---- (6) single barrier per tile
        __syncthreads();
    }

    // ---- epilogue: f64 reduce, combine, normalize, store (lane = dim l)
    #pragma unroll
    for (int i = 0; i < 4; ++i) {
        double vsp = sp[i], vsq = sq[i], vspv = spv[i], vsqv = sqv[i];
        #pragma unroll
        for (int mm = 32; mm >= 1; mm >>= 1) {
            vsp  += __shfl_xor(vsp,  mm);
            vsq  += __shfl_xor(vsq,  mm);
            vspv += __shfl_xor(vspv, mm);
            vsqv += __shfl_xor(vsqv, mm);
        }
        const double w1 = (1.0 - ghd) / vsp;
        const double w2 = ghd / vsq;
        const double S  = w1 * vspv + w2 * vsqv;
        const float accp = ap2[i].x + ap2[i].y;
        const float accq = aq2[i].x + aq2[i].y;
        const double a  = w1 * (double)accp + w2 * (double)accq;
        attn_out[((size_t)b * N_ + n0 + (w + 4 * i)) * C_ + h * HD_ + l] = (float)(a / S);
    }
}

// ---------------------------------------------------------------------------
extern "C" void kernel_launch(void* const* d_in, const int* in_sizes, int n_in,
                              void* d_out, int out_size, void* d_ws, size_t ws_size,
                              hipStream_t stream)
{
    const float* x      = (const float*)d_in[0];
    const float* coord  = (const float*)d_in[1];
    const float* W_qk   = (const float*)d_in[2];
    const float* W_v    = (const float*)d_in[3];
    const float* W_proj = (const float*)d_in[4];
    const float* b_proj = (const float*)d_in[5];
    const float* W_pos  = (const float*)d_in[6];
    // d_in[7] = b_pos (cancels in softmax), d_in[9] = pos_emb (cancels) — unused
    const float* gating = (const float*)d_in[8];

    float* ws   = (float*)d_ws;
    const size_t per = (size_t)B_ * H_ * N_ * HD_;   // 4,194,304 floats
    float*  qb   = ws;
    float*  kb   = qb + per;
    float*  vb   = kb + per;
    float*  attn = vb + per;
    double* wsh  = (double*)(attn + per);
    double* Vall = wsh + (size_t)H_ * C_;
    float*  out  = (float*)d_out;

    wsum_kernel<<<dim3(4, 16), 256, 0, stream>>>(W_v, wsh);
    vall_kernel<<<dim3(4, 16, 4), 256, 0, stream>>>(x, wsh, Vall);

    gemm_qk_kernel<<<dim3(32, 32), 256, 0, stream>>>(x, W_qk, qb, kb, B_ * N_, C_);
    gemm128_kernel<0><<<dim3(8, 32), 256, 0, stream>>>(x, W_v, nullptr, vb, B_ * N_, C_, C_);

    attn_kernel<<<dim3(N_ / 16, H_, B_), 256, 0, stream>>>(
        qb, kb, vb, Vall, coord, W_pos, gating, attn);

    gemm128_kernel<1><<<dim3(8, 32), 256, 0, stream>>>(
        attn, W_proj, b_proj, out, B_ * N_, C_, C_);
}

// Round 12
// 927.884 us; speedup vs baseline: 1.9318x; 1.4699x over previous
//
#include <hip/hip_runtime.h>
#include <math.h>

#define B_ 4
#define N_ 1024
#define C_ 1024
#define H_ 16
#define HD_ 64

typedef float f32x2 __attribute__((ext_vector_type(2)));
typedef float f32x4 __attribute__((ext_vector_type(4)));
typedef short bf16x8 __attribute__((ext_vector_type(8)));

// packed 2xf32 fma -> v_pk_fma_f32 on gfx950
__device__ __forceinline__ f32x2 pk_fma(f32x2 a, f32x2 b, f32x2 c) {
#if __has_builtin(__builtin_elementwise_fma)
    return __builtin_elementwise_fma(a, b, c);
#else
    f32x2 r; r.x = fmaf(a.x, b.x, c.x); r.y = fmaf(a.y, b.y, c.y); return r;
#endif
}

__device__ __forceinline__ unsigned short f2bf(float v) {   // RNE f32->bf16
    unsigned u = __float_as_uint(v);
    u += 0x7FFFu + ((u >> 16) & 1u);
    return (unsigned short)(u >> 16);
}

// ---------------------------------------------------------------------------
// ERROR MODEL (validated r4..r11, absmax 16 vs 97):
//   S path (exact): f64 Vall collapse + f64 logits/exp, rel err <= 4e-8.
//   q,k: slab-f64 GEMM. DAMPED numerator paths (budget ~4e-3 rel): PV may
//   use bf16 P and bf16 V (adds ~+11 absmax via 1/S amplification, safe).
// PERF MODEL: attn floor ~900us = per-CU LDS issue pipe (212 insts/wave-tile,
//   128 of them pt/qt PV broadcasts). r12: PV -> MFMA bf16 (matrix pipe),
//   pt/qt bf16 swizzled fragments (6 b128 reads), V^T bf16 staged tiles.
//   VGPR budget <= ~100 (spill cliff); 2 barriers/tile.
// ---------------------------------------------------------------------------

// fast f64 exp for |a| <= ~16: range-reduce + deg-8 Taylor. rel err ~3e-10.
__device__ __forceinline__ double fast_exp64(double a) {
    const double LOG2E = 1.4426950408889634074;
    const double LN2HI = 6.93147180369123816490e-01;
    const double LN2LO = 1.90821492927058770002e-10;
    const double MAGIC = 6755399441055744.0;   // 1.5 * 2^52
    double t     = a * LOG2E;
    double shift = t + MAGIC;
    int    n     = (int)__double_as_longlong(shift);
    double nd    = shift - MAGIC;
    double f     = __fma_rn(nd, -LN2HI, a);
    f            = __fma_rn(nd, -LN2LO, f);
    double p = 2.4801587301587301587e-05;
    p = __fma_rn(p, f, 1.9841269841269841270e-04);
    p = __fma_rn(p, f, 1.3888888888888888889e-03);
    p = __fma_rn(p, f, 8.3333333333333333333e-03);
    p = __fma_rn(p, f, 4.1666666666666666667e-02);
    p = __fma_rn(p, f, 1.6666666666666666667e-01);
    p = __fma_rn(p, f, 5.0e-01);
    p = __fma_rn(p, f, 1.0);
    p = __fma_rn(p, f, 1.0);
    return p * __longlong_as_double(((long long)(1023 + n)) << 52);
}

// ---------------------------------------------------------------------------
// Slab-compensated GEMM for q,k (O=2048). Tile 128x64, f32 slabs -> f64.
// ---------------------------------------------------------------------------
__global__ __launch_bounds__(256)
void gemm_qk_kernel(const float* __restrict__ A,
                    const float* __restrict__ W0,
                    float* __restrict__ outq,
                    float* __restrict__ outk,
                    int M, int K)
{
    __shared__ float As[16][132];
    __shared__ float Ws[16][68];

    const int t  = threadIdx.x;
    const int m0 = blockIdx.y * 128;
    const int o0 = blockIdx.x * 64;
    const int ty = t >> 4;
    const int tx = t & 15;

    double acc[8][4];
    #pragma unroll
    for (int i = 0; i < 8; ++i)
        #pragma unroll
        for (int j = 0; j < 4; ++j) acc[i][j] = 0.0;

    for (int k0 = 0; k0 < K; k0 += 16) {
        #pragma unroll
        for (int i = 0; i < 2; ++i) {
            int vix = t + i * 256;
            int r   = vix >> 2;
            int c4  = vix & 3;
            const float4 a4 = *reinterpret_cast<const float4*>(&A[(size_t)(m0 + r) * K + k0 + c4 * 4]);
            As[c4 * 4 + 0][r] = a4.x;
            As[c4 * 4 + 1][r] = a4.y;
            As[c4 * 4 + 2][r] = a4.z;
            As[c4 * 4 + 3][r] = a4.w;
        }
        {
            int c  = t >> 2;
            int c4 = t & 3;
            const float4 w4 = *reinterpret_cast<const float4*>(&W0[(size_t)(o0 + c) * K + k0 + c4 * 4]);
            Ws[c4 * 4 + 0][c] = w4.x;
            Ws[c4 * 4 + 1][c] = w4.y;
            Ws[c4 * 4 + 2][c] = w4.z;
            Ws[c4 * 4 + 3][c] = w4.w;
        }
        __syncthreads();

        f32x2 sacc[8][2];
        #pragma unroll
        for (int i = 0; i < 8; ++i)
            #pragma unroll
            for (int j = 0; j < 2; ++j) sacc[i][j] = (f32x2){0.f, 0.f};

        #pragma unroll
        for (int kk = 0; kk < 16; ++kk) {
            float a[8];
            *reinterpret_cast<float4*>(&a[0]) = *reinterpret_cast<const float4*>(&As[kk][ty * 8]);
            *reinterpret_cast<float4*>(&a[4]) = *reinterpret_cast<const float4*>(&As[kk][ty * 8 + 4]);
            const float4 wv = *reinterpret_cast<const float4*>(&Ws[kk][tx * 4]);
            const f32x2 b0 = {wv.x, wv.y};
            const f32x2 b1 = {wv.z, wv.w};
            #pragma unroll
            for (int i = 0; i < 8; ++i) {
                const f32x2 av = {a[i], a[i]};
                sacc[i][0] = pk_fma(av, b0, sacc[i][0]);
                sacc[i][1] = pk_fma(av, b1, sacc[i][1]);
            }
        }
        #pragma unroll
        for (int i = 0; i < 8; ++i) {
            acc[i][0] += (double)sacc[i][0].x;
            acc[i][1] += (double)sacc[i][0].y;
            acc[i][2] += (double)sacc[i][1].x;
            acc[i][3] += (double)sacc[i][1].y;
        }
        __syncthreads();
    }

    int oo = o0 + tx * 4;
    float* dst = (oo < 1024) ? outq : outk;
    oo &= 1023;
    const int hh = oo >> 6, d0 = oo & 63;
    #pragma unroll
    for (int i = 0; i < 8; ++i) {
        int m = m0 + ty * 8 + i;
        int bb_ = m >> 10, n = m & 1023;
        float4 r0 = make_float4((float)acc[i][0], (float)acc[i][1],
                                (float)acc[i][2], (float)acc[i][3]);
        *reinterpret_cast<float4*>(&dst[((((size_t)bb_ * H_) + hh) * N_ + n) * HD_ + d0]) = r0;
    }
}

// ---------------------------------------------------------------------------
// Plain f32 GEMM, tile 128x128, packed inner.
// MODE 0: v -> vtb bf16 TRANSPOSED [B][H][64][N] (PV MFMA B-operand source).
// MODE 1: row-major f32 + bias.
// ---------------------------------------------------------------------------
template<int MODE>
__global__ __launch_bounds__(256)
void gemm128_kernel(const float* __restrict__ A,
                    const float* __restrict__ W0,
                    const float* __restrict__ bias,
                    float* __restrict__ out0,
                    int M, int O, int K)
{
    __shared__ float As[16][132];
    __shared__ float Ws[16][132];

    const int t  = threadIdx.x;
    const int m0 = blockIdx.y * 128;
    const int o0 = blockIdx.x * 128;
    const int ty = t >> 4;
    const int tx = t & 15;

    f32x2 acc2[8][4];
    #pragma unroll
    for (int i = 0; i < 8; ++i)
        #pragma unroll
        for (int j = 0; j < 4; ++j) acc2[i][j] = (f32x2){0.f, 0.f};

    for (int k0 = 0; k0 < K; k0 += 16) {
        #pragma unroll
        for (int i = 0; i < 2; ++i) {
            int vix = t + i * 256;
            int r   = vix >> 2;
            int c4  = vix & 3;
            const float4 a4 = *reinterpret_cast<const float4*>(&A[(size_t)(m0 + r) * K + k0 + c4 * 4]);
            As[c4 * 4 + 0][r] = a4.x;
            As[c4 * 4 + 1][r] = a4.y;
            As[c4 * 4 + 2][r] = a4.z;
            As[c4 * 4 + 3][r] = a4.w;
        }
        #pragma unroll
        for (int i = 0; i < 2; ++i) {
            int vix = t + i * 256;
            int c   = vix >> 2;
            int c4  = vix & 3;
            const float4 w4 = *reinterpret_cast<const float4*>(&W0[(size_t)(o0 + c) * K + k0 + c4 * 4]);
            Ws[c4 * 4 + 0][c] = w4.x;
            Ws[c4 * 4 + 1][c] = w4.y;
            Ws[c4 * 4 + 2][c] = w4.z;
            Ws[c4 * 4 + 3][c] = w4.w;
        }
        __syncthreads();

        #pragma unroll
        for (int kk = 0; kk < 16; ++kk) {
            float a[8];
            *reinterpret_cast<float4*>(&a[0]) = *reinterpret_cast<const float4*>(&As[kk][ty * 8]);
            *reinterpret_cast<float4*>(&a[4]) = *reinterpret_cast<const float4*>(&As[kk][ty * 8 + 4]);
            const float4 w01 = *reinterpret_cast<const float4*>(&Ws[kk][tx * 8]);
            const float4 w23 = *reinterpret_cast<const float4*>(&Ws[kk][tx * 8 + 4]);
            const f32x2 b0 = {w01.x, w01.y};
            const f32x2 b1 = {w01.z, w01.w};
            const f32x2 b2 = {w23.x, w23.y};
            const f32x2 b3 = {w23.z, w23.w};
            #pragma unroll
            for (int i = 0; i < 8; ++i) {
                const f32x2 av = {a[i], a[i]};
                acc2[i][0] = pk_fma(av, b0, acc2[i][0]);
                acc2[i][1] = pk_fma(av, b1, acc2[i][1]);
                acc2[i][2] = pk_fma(av, b2, acc2[i][2]);
                acc2[i][3] = pk_fma(av, b3, acc2[i][3]);
            }
        }
        __syncthreads();
    }

    if (MODE == 1) {
        float bs[8];
        *reinterpret_cast<float4*>(&bs[0]) = *reinterpret_cast<const float4*>(&bias[o0 + tx * 8]);
        *reinterpret_cast<float4*>(&bs[4]) = *reinterpret_cast<const float4*>(&bias[o0 + tx * 8 + 4]);
        #pragma unroll
        for (int i = 0; i < 8; ++i) {
            int m = m0 + ty * 8 + i;
            float* p = &out0[(size_t)m * O + o0 + tx * 8];
            float4 r0 = make_float4(acc2[i][0].x + bs[0], acc2[i][0].y + bs[1],
                                    acc2[i][1].x + bs[2], acc2[i][1].y + bs[3]);
            float4 r1 = make_float4(acc2[i][2].x + bs[4], acc2[i][2].y + bs[5],
                                    acc2[i][3].x + bs[6], acc2[i][3].y + bs[7]);
            *reinterpret_cast<float4*>(p)     = r0;
            *reinterpret_cast<float4*>(p + 4) = r1;
        }
    } else {
        // v transposed bf16: vtb[((b*H+hh)*64 + d)*N + n], 8 rows packed/store
        unsigned short* vtb = reinterpret_cast<unsigned short*>(out0);
        const int oo = o0 + tx * 8;            // O=1024 here
        const int hh = oo >> 6, d0 = oo & 63;
        const int m_base = m0 + ty * 8;
        const int bb_ = m_base >> 10, nb = m_base & 1023;
        #pragma unroll
        for (int jd = 0; jd < 8; ++jd) {
            unsigned short pk[8];
            #pragma unroll
            for (int i = 0; i < 8; ++i) {
                const float v = (jd & 1) ? acc2[i][jd >> 1].y : acc2[i][jd >> 1].x;
                pk[i] = f2bf(v);
            }
            *reinterpret_cast<bf16x8*>(
                &vtb[(((size_t)bb_ * H_ + hh) * 64 + d0 + jd) * N_ + nb]) =
                *reinterpret_cast<bf16x8*>(pk);
        }
    }
}

// ---------------------------------------------------------------------------
__global__ void wsum_kernel(const float* __restrict__ W_v, double* __restrict__ wsh)
{
    const int k = blockIdx.x * 256 + threadIdx.x;
    const int h = blockIdx.y;
    double s = 0.0;
    #pragma unroll 8
    for (int d = 0; d < 64; ++d) s += (double)W_v[(size_t)(h * 64 + d) * C_ + k];
    wsh[h * C_ + k] = s;
}

__global__ __launch_bounds__(256)
void vall_kernel(const float* __restrict__ x, const double* __restrict__ wsh,
                 double* __restrict__ Vall)
{
    __shared__ double ws_s[1024];
    const int h = blockIdx.y, b = blockIdx.z;
    const int m = blockIdx.x * 256 + threadIdx.x;
    for (int i = threadIdx.x; i < 1024; i += 256) ws_s[i] = wsh[h * C_ + i];
    __syncthreads();
    const float* xr = x + ((size_t)b * N_ + m) * C_;
    double acc = 0.0;
    #pragma unroll 8
    for (int kk = 0; kk < 1024; ++kk) acc += (double)xr[kk] * ws_s[kk];
    Vall[((size_t)b * H_ + h) * N_ + m] = acc;
}

// ---------------------------------------------------------------------------
// Fused attention r12: r11 QK/weights, PV via bf16 MFMA.
//  Per tile: (1) prefetch next K (f32) + next V^T (bf16) + Vm/coord;
//  (2) QK packed f32 from Kt4; (3) f64 weights -> ptB/qtB bf16 (swizzled);
//  barrier A; (4) 4x mfma_f32_16x16x32_bf16 (wave w owns dims 16w..16w+15);
//  (5) write staged K/Vt; barrier B.
//  C layout (m89): col=lane&15, row=4*(lane>>4)+reg. A: row=l&15,
//  k=8*(l>>4)+j. B: col=l&15, k=8*(l>>4)+j.
// ---------------------------------------------------------------------------
__global__ __launch_bounds__(256)
void attn_kernel(const float* __restrict__ q,
                 const float* __restrict__ k,
                 const unsigned short* __restrict__ vtb, // [B][H][64][N] bf16
                 const double* __restrict__ Vall,        // [B][H][N]
                 const float* __restrict__ coord,        // [B][N][3]
                 const float* __restrict__ W_pos,        // [H][4]
                 const float* __restrict__ gating,       // [H]
                 float* __restrict__ attn_out)           // [B][N][C]
{
    __shared__ float4 Qs4[16][16];                         // 4KB
    __shared__ float4 Kt4[64][16];                         // 16KB (single buf)
    __shared__ __align__(16) unsigned short ptB[16 * 64];  // 2KB bf16 swz
    __shared__ __align__(16) unsigned short qtB[16 * 64];  // 2KB
    __shared__ __align__(16) unsigned short VtB[2][64 * 64]; // 16KB dbuf
    __shared__ float qc[16][3];
    __shared__ double w1L[16], w2L[16], SL[16];

    const int t  = threadIdx.x;
    const int w  = t >> 6;     // wave 0..3
    const int l  = t & 63;
    const int n0 = blockIdx.x * 16;
    const int h  = blockIdx.y;
    const int b  = blockIdx.z;
    const size_t bhN = ((size_t)b * H_ + h) * N_;

    // K staging indices (4 float4/tile/thread)
    const int sr0 = t >> 4;
    const int sc  = t & 15;
    // Vt staging indices (2 bf16x8/tile/thread): dim vd, keys vkc..vkc+15
    const int vd  = t >> 2;
    const int vkc = (t & 3) * 16;
    const unsigned short* vrow = vtb + (((size_t)b * H_ + h) * 64 + vd) * N_;
    const int vswz = (vd & 7) << 4;

    Qs4[t >> 4][t & 15] = reinterpret_cast<const float4*>(q + (bhN + n0) * HD_)[t];
    if (t < 48) qc[t / 3][t % 3] = coord[((size_t)b * N_ + n0 + t / 3) * 3 + (t % 3)];
    const double w4hd = (double)W_pos[h * 4 + 3];
    const double ghd  = 1.0 / (1.0 + exp(-(double)gating[h]));

    double sp[4], sq[4], spv[4], sqv[4];
    f32x4 accP = {0.f, 0.f, 0.f, 0.f};
    f32x4 accQ = {0.f, 0.f, 0.f, 0.f};
    #pragma unroll
    for (int i = 0; i < 4; ++i) { sp[i] = 0.0; sq[i] = 0.0; spv[i] = 0.0; sqv[i] = 0.0; }

    // ---- prologue: stage K tile 0, Vt tile 0, Vm/coord
    {
        const float4* kb4 = reinterpret_cast<const float4*>(k + bhN * HD_);
        #pragma unroll
        for (int i = 0; i < 4; ++i)
            Kt4[sr0 + i * 16][sc ^ ((sr0 + i * 16) & 15)] = kb4[t + i * 256];
        const bf16x8 v0 = *reinterpret_cast<const bf16x8*>(vrow + vkc);
        const bf16x8 v1 = *reinterpret_cast<const bf16x8*>(vrow + vkc + 8);
        char* vb = reinterpret_cast<char*>(&VtB[0][0]);
        *reinterpret_cast<bf16x8*>(vb + ((vd * 128 + vkc * 2)      ^ vswz)) = v0;
        *reinterpret_cast<bf16x8*>(vb + ((vd * 128 + vkc * 2 + 16) ^ vswz)) = v1;
    }
    double Vm  = Vall[bhN + l];
    double cmx = (double)coord[((size_t)b * N_ + l) * 3 + 0];
    double cmy = (double)coord[((size_t)b * N_ + l) * 3 + 1];
    double cmz = (double)coord[((size_t)b * N_ + l) * 3 + 2];
    __syncthreads();

    for (int t16 = 0; t16 < 16; ++t16) {
        const int m0   = t16 * 64;
        const int vcur = t16 & 1;

        // ---- (1) prefetch next tile
        float4 st0, st1, st2, st3;
        bf16x8 sv0, sv1;
        double VmN = 0.0, cmxN = 0.0, cmyN = 0.0, cmzN = 0.0;
        if (t16 < 15) {
            const float4* kb4 = reinterpret_cast<const float4*>(k + (bhN + m0 + 64) * HD_);
            st0 = kb4[t];
            st1 = kb4[t + 256];
            st2 = kb4[t + 512];
            st3 = kb4[t + 768];
            sv0 = *reinterpret_cast<const bf16x8*>(vrow + m0 + 64 + vkc);
            sv1 = *reinterpret_cast<const bf16x8*>(vrow + m0 + 64 + vkc + 8);
            VmN  = Vall[bhN + m0 + 64 + l];
            cmxN = (double)coord[((size_t)b * N_ + m0 + 64 + l) * 3 + 0];
            cmyN = (double)coord[((size_t)b * N_ + m0 + 64 + l) * 3 + 1];
            cmzN = (double)coord[((size_t)b * N_ + m0 + 64 + l) * 3 + 2];
        }

        // ---- (2) QK^T packed f32 (rows w+4i, column m0+l)
        f32x2 dot2[4][2];
        #pragma unroll
        for (int i = 0; i < 4; ++i) {
            dot2[i][0] = (f32x2){0.f, 0.f};
            dot2[i][1] = (f32x2){0.f, 0.f};
        }
        #pragma unroll
        for (int d4 = 0; d4 < 16; ++d4) {
            const float4 kt = Kt4[l][d4 ^ (l & 15)];
            const int g = d4 >> 3;
            const f32x2 kxy = {kt.x, kt.y};
            const f32x2 kzw = {kt.z, kt.w};
            #pragma unroll
            for (int i = 0; i < 4; ++i) {
                const float4 q4 = Qs4[w + 4 * i][d4];
                dot2[i][g] = pk_fma(kxy, (f32x2){q4.x, q4.y}, dot2[i][g]);
                dot2[i][g] = pk_fma(kzw, (f32x2){q4.z, q4.w}, dot2[i][g]);
            }
        }

        // ---- (3) f64 weights + S-path; write bf16 weights (swizzled)
        #pragma unroll
        for (int i = 0; i < 4; ++i) {
            const int r = w + 4 * i;
            const double lg = (((double)dot2[i][0].x + (double)dot2[i][0].y) +
                               ((double)dot2[i][1].x + (double)dot2[i][1].y)) * 0.125;
            const double p64 = fast_exp64(lg);
            const double dx = (double)qc[r][0] - cmx;
            const double dy = (double)qc[r][1] - cmy;
            const double dz = (double)qc[r][2] - cmz;
            const double r2 = __fma_rn(dx, dx, __fma_rn(dy, dy, dz * dz));
            const double y0 = (double)rsqrtf((float)r2);
            const double y1 = y0 * __fma_rn(-0.5 * r2, y0 * y0, 1.5);
            const double dist = (r2 > 0.0) ? r2 * y1 : 0.0;
            const double q64 = fast_exp64(dist * w4hd);
            const int off = (r * 128 + l * 2) ^ ((r & 7) << 4);
            *reinterpret_cast<unsigned short*>(reinterpret_cast<char*>(ptB) + off) = f2bf((float)p64);
            *reinterpret_cast<unsigned short*>(reinterpret_cast<char*>(qtB) + off) = f2bf((float)q64);
            sp[i]  += p64;
            sq[i]  += q64;
            spv[i] += p64 * Vm;
            sqv[i] += q64 * Vm;
        }
        __syncthreads();   // barrier A: ptB/qtB/VtB[vcur] ready for MFMA

        // ---- (4) PV via MFMA: wave w -> dims 16w..16w+15, all 16 rows
        {
            const int r_   = l & 15;
            const int kb_  = l >> 4;
            const int aoff = r_ * 128 + kb_ * 16;
            const int aswz = (r_ & 7) << 4;
            const int dimw = w * 16 + r_;
            const int boff = dimw * 128 + kb_ * 16;
            const int bswz = (dimw & 7) << 4;
            const char* pbase = reinterpret_cast<const char*>(ptB);
            const char* qbase = reinterpret_cast<const char*>(qtB);
            const char* vbase = reinterpret_cast<const char*>(&VtB[vcur][0]);
            #pragma unroll
            for (int kh = 0; kh < 2; ++kh) {
                const bf16x8 afp = *reinterpret_cast<const bf16x8*>(pbase + ((aoff + kh * 64) ^ aswz));
                const bf16x8 afq = *reinterpret_cast<const bf16x8*>(qbase + ((aoff + kh * 64) ^ aswz));
                const bf16x8 bf_ = *reinterpret_cast<const bf16x8*>(vbase + ((boff + kh * 64) ^ bswz));
                accP = __builtin_amdgcn_mfma_f32_16x16x32_bf16(afp, bf_, accP, 0, 0, 0);
                accQ = __builtin_amdgcn_mfma_f32_16x16x32_bf16(afq, bf_, accQ, 0, 0, 0);
            }
        }

        // ---- (5) write staged K/Vt; roll Vm/coord
        if (t16 < 15) {
            Kt4[sr0     ][sc ^ ( sr0       & 15)] = st0;
            Kt4[sr0 + 16][sc ^ ((sr0 + 16) & 15)] = st1;
            Kt4[sr0 + 32][sc ^ ((sr0 + 32) & 15)] = st2;
            Kt4[sr0 + 48][sc ^ ((sr0 + 48) & 15)] = st3;
            char* vb = reinterpret_cast<char*>(&VtB[vcur ^ 1][0]);
            *reinterpret_cast<bf16x8*>(vb + ((vd * 128 + vkc * 2)      ^ vswz)) = sv0;
            *reinterpret_cast<bf16x8*>(vb + ((vd * 128 + vkc * 2 + 16) ^ vswz)) = sv1;
            Vm = VmN; cmx = cmxN; cmy = cmyN; cmz = cmzN;
        }
        __syncthreads();   // barrier B
    }

    // ---- epilogue: per-row S via wave reduce -> LDS share -> store
    #pragma unroll
    for (int i = 0; i < 4; ++i) {
        double vsp = sp[i], vsq = sq[i], vspv = spv[i], vsqv = sqv[i];
        #pragma unroll
        for (int mm = 32; mm >= 1; mm >>= 1) {
            vsp  += __shfl_xor(vsp,  mm);
            vsq  += __shfl_xor(vsq,  mm);
            vspv += __shfl_xor(vspv, mm);
            vsqv += __shfl_xor(vsqv, mm);
        }
        const double w1 = (1.0 - ghd) / vsp;
        const double w2 = ghd / vsq;
        if (l == 0) {
            w1L[w + 4 * i] = w1;
            w2L[w + 4 * i] = w2;
            SL[w + 4 * i]  = w1 * vspv + w2 * vsqv;
        }
    }
    __syncthreads();
    const int col = h * HD_ + w * 16 + (l & 15);
    #pragma unroll
    for (int j = 0; j < 4; ++j) {
        const int m = 4 * (l >> 4) + j;
        const double a = w1L[m] * (double)accP[j] + w2L[m] * (double)accQ[j];
        attn_out[((size_t)b * N_ + n0 + m) * C_ + col] = (float)(a / SL[m]);
    }
}

// ---------------------------------------------------------------------------
extern "C" void kernel_launch(void* const* d_in, const int* in_sizes, int n_in,
                              void* d_out, int out_size, void* d_ws, size_t ws_size,
                              hipStream_t stream)
{
    const float* x      = (const float*)d_in[0];
    const float* coord  = (const float*)d_in[1];
    const float* W_qk   = (const float*)d_in[2];
    const float* W_v    = (const float*)d_in[3];
    const float* W_proj = (const float*)d_in[4];
    const float* b_proj = (const float*)d_in[5];
    const float* W_pos  = (const float*)d_in[6];
    // d_in[7] = b_pos (cancels in softmax), d_in[9] = pos_emb (cancels) — unused
    const float* gating = (const float*)d_in[8];

    float* ws   = (float*)d_ws;
    const size_t per = (size_t)B_ * H_ * N_ * HD_;   // 4,194,304 elements
    float*          qb   = ws;
    float*          kb   = qb + per;
    float*          attn = kb + per;
    unsigned short* vtb  = (unsigned short*)(attn + per);   // bf16, per shorts
    double*         wsh  = (double*)(vtb + per);
    double*         Vall = wsh + (size_t)H_ * C_;
    float*          out  = (float*)d_out;

    wsum_kernel<<<dim3(4, 16), 256, 0, stream>>>(W_v, wsh);
    vall_kernel<<<dim3(4, 16, 4), 256, 0, stream>>>(x, wsh, Vall);

    gemm_qk_kernel<<<dim3(32, 32), 256, 0, stream>>>(x, W_qk, qb, kb, B_ * N_, C_);
    gemm128_kernel<0><<<dim3(8, 32), 256, 0, stream>>>(x, W_v, nullptr, (float*)vtb, B_ * N_, C_, C_);

    attn_kernel<<<dim3(N_ / 16, H_, B_), 256, 0, stream>>>(
        qb, kb, vtb, Vall, coord, W_pos, gating, attn);

    gemm128_kernel<1><<<dim3(8, 32), 256, 0, stream>>>(
        attn, W_proj, b_proj, out, B_ * N_, C_, C_);
}

// Round 13
// 739.972 us; speedup vs baseline: 2.4224x; 1.2539x over previous
//
#include <hip/hip_runtime.h>
#include <math.h>

#define B_ 4
#define N_ 1024
#define C_ 1024
#define H_ 16
#define HD_ 64

typedef float f32x2 __attribute__((ext_vector_type(2)));
typedef float f32x4 __attribute__((ext_vector_type(4)));
typedef short bf16x8 __attribute__((ext_vector_type(8)));

__device__ __forceinline__ f32x2 pk_fma(f32x2 a, f32x2 b, f32x2 c) {
#if __has_builtin(__builtin_elementwise_fma)
    return __builtin_elementwise_fma(a, b, c);
#else
    f32x2 r; r.x = fmaf(a.x, b.x, c.x); r.y = fmaf(a.y, b.y, c.y); return r;
#endif
}

__device__ __forceinline__ unsigned short f2bf(float v) {   // RNE f32->bf16
    unsigned u = __float_as_uint(v);
    u += 0x7FFFu + ((u >> 16) & 1u);
    return (unsigned short)(u >> 16);
}

// ---------------------------------------------------------------------------
// ERROR MODEL (validated r4..r12, absmax 16 vs 97):
//   EXACT S path: f64 Vall collapse (wsum/vall) + f64 logits/exp; q,k from
//   slab-f64 GEMM. DAMPED paths (budget ~4e-3 rel / ~97 abs out): PV bf16
//   (validated r12, absmax unchanged), v-GEMM bf16 MFMA (v only feeds bf16
//   PV anyway), proj-GEMM bf16 MFMA (delta_out ~ sqrt(1024)*rms*2e-3*0.02
//   ~ a few abs), attn intermediate bf16.
// PERF MODEL: r12 attn 439us (f64 weight phase = numerics floor). r13 moves
//   the two damped GEMMs (230us combined, f32-vector-bound) onto the matrix
//   pipe using the r12-validated 16x16x32 bf16 fragment layouts.
// ---------------------------------------------------------------------------

// fast f64 exp for |a| <= ~16: range-reduce + deg-8 Taylor. rel err ~3e-10.
__device__ __forceinline__ double fast_exp64(double a) {
    const double LOG2E = 1.4426950408889634074;
    const double LN2HI = 6.93147180369123816490e-01;
    const double LN2LO = 1.90821492927058770002e-10;
    const double MAGIC = 6755399441055744.0;   // 1.5 * 2^52
    double t     = a * LOG2E;
    double shift = t + MAGIC;
    int    n     = (int)__double_as_longlong(shift);
    double nd    = shift - MAGIC;
    double f     = __fma_rn(nd, -LN2HI, a);
    f            = __fma_rn(nd, -LN2LO, f);
    double p = 2.4801587301587301587e-05;
    p = __fma_rn(p, f, 1.9841269841269841270e-04);
    p = __fma_rn(p, f, 1.3888888888888888889e-03);
    p = __fma_rn(p, f, 8.3333333333333333333e-03);
    p = __fma_rn(p, f, 4.1666666666666666667e-02);
    p = __fma_rn(p, f, 1.6666666666666666667e-01);
    p = __fma_rn(p, f, 5.0e-01);
    p = __fma_rn(p, f, 1.0);
    p = __fma_rn(p, f, 1.0);
    return p * __longlong_as_double(((long long)(1023 + n)) << 52);
}

// ---------------------------------------------------------------------------
// f32 -> bf16 bulk convert (n multiple of 2048)
// ---------------------------------------------------------------------------
__global__ __launch_bounds__(256)
void cvt_bf16_kernel(const float* __restrict__ src, unsigned short* __restrict__ dst, int n)
{
    const int i = (blockIdx.x * 256 + threadIdx.x) * 8;
    if (i >= n) return;
    const float4 a = *reinterpret_cast<const float4*>(&src[i]);
    const float4 b = *reinterpret_cast<const float4*>(&src[i + 4]);
    unsigned short pk[8];
    pk[0] = f2bf(a.x); pk[1] = f2bf(a.y); pk[2] = f2bf(a.z); pk[3] = f2bf(a.w);
    pk[4] = f2bf(b.x); pk[5] = f2bf(b.y); pk[6] = f2bf(b.z); pk[7] = f2bf(b.w);
    *reinterpret_cast<bf16x8*>(&dst[i]) = *reinterpret_cast<bf16x8*>(pk);
}

// ---------------------------------------------------------------------------
// bf16 MFMA GEMM: C[m][o] = sum_k A[m][k]*Bw[o][k] (+bias), K=1024.
// Tile 128x64, BK=32, 4 waves; wave w owns rows [32w,32w+32).
// Frag layouts validated on-HW in r12: A row=l&15,k=8*(l>>4)+j; B col=l&15;
// C col=l&15,row=4*(l>>4)+reg. LDS rows padded to 40 ushorts (80B) ->
// frag reads 2-way bank alias only (free).
// OUT_BF16=1: out bf16 [m*O+o] (v^T path). OUT_BF16=0: f32 + bias (proj).
// ---------------------------------------------------------------------------
template<int OUT_BF16>
__global__ __launch_bounds__(256)
void mfma_gemm_kernel(const unsigned short* __restrict__ A,    // [M][K] bf16
                      const unsigned short* __restrict__ Bw,   // [O][K] bf16 (+z off)
                      const float* __restrict__ bias,          // [O] or null
                      float* __restrict__ outF,
                      unsigned short* __restrict__ outB,
                      int M, int O, int K)
{
    __shared__ unsigned short As[128][40];
    __shared__ unsigned short Bs[64][40];

    const int t  = threadIdx.x;
    const int w  = t >> 6;
    const int l  = t & 63;
    const int o0 = blockIdx.x * 64;
    const int m0 = blockIdx.y * 128;
    const size_t zoff = (size_t)blockIdx.z * 1048576;   // v: per-batch slab
    Bw += zoff;

    f32x4 acc[2][4];
    #pragma unroll
    for (int r = 0; r < 2; ++r)
        #pragma unroll
        for (int c = 0; c < 4; ++c) acc[r][c] = (f32x4){0.f, 0.f, 0.f, 0.f};

    const int ar = t >> 1, aseg = t & 1;     // A staging: row, 32B segment
    const int br = t >> 2, bseg = t & 3;     // B staging: row, 16B segment
    const int fr = l & 15, kg = l >> 4;      // fragment row/col + k-group

    for (int k0 = 0; k0 < K; k0 += 32) {
        const bf16x8 a0 = *reinterpret_cast<const bf16x8*>(&A[(size_t)(m0 + ar) * K + k0 + aseg * 16]);
        const bf16x8 a1 = *reinterpret_cast<const bf16x8*>(&A[(size_t)(m0 + ar) * K + k0 + aseg * 16 + 8]);
        const bf16x8 b0 = *reinterpret_cast<const bf16x8*>(&Bw[(size_t)(o0 + br) * K + k0 + bseg * 8]);
        __syncthreads();   // previous iteration's frag reads done
        *reinterpret_cast<bf16x8*>(&As[ar][aseg * 16])     = a0;
        *reinterpret_cast<bf16x8*>(&As[ar][aseg * 16 + 8]) = a1;
        *reinterpret_cast<bf16x8*>(&Bs[br][bseg * 8])      = b0;
        __syncthreads();   // tile staged

        bf16x8 bfr[4];
        #pragma unroll
        for (int c = 0; c < 4; ++c)
            bfr[c] = *reinterpret_cast<const bf16x8*>(&Bs[c * 16 + fr][kg * 8]);
        #pragma unroll
        for (int r = 0; r < 2; ++r) {
            const bf16x8 af = *reinterpret_cast<const bf16x8*>(&As[w * 32 + r * 16 + fr][kg * 8]);
            #pragma unroll
            for (int c = 0; c < 4; ++c)
                acc[r][c] = __builtin_amdgcn_mfma_f32_16x16x32_bf16(af, bfr[c], acc[r][c], 0, 0, 0);
        }
    }

    // epilogue: C col=l&15, row=4*(l>>4)+j
    #pragma unroll
    for (int c = 0; c < 4; ++c) {
        const int col = o0 + c * 16 + fr;
        const float bv = (OUT_BF16 == 0) ? bias[col] : 0.f;
        #pragma unroll
        for (int r = 0; r < 2; ++r) {
            #pragma unroll
            for (int j = 0; j < 4; ++j) {
                const int row = m0 + w * 32 + r * 16 + kg * 4 + j;
                const float v = acc[r][c][j] + bv;
                if (OUT_BF16)
                    outB[zoff + (size_t)row * O + col] = f2bf(v);
                else
                    outF[(size_t)row * O + col] = v;
            }
        }
    }
}

// ---------------------------------------------------------------------------
// Slab-compensated GEMM for q,k (O=2048, exact path). Unchanged from r11.
// ---------------------------------------------------------------------------
__global__ __launch_bounds__(256)
void gemm_qk_kernel(const float* __restrict__ A,
                    const float* __restrict__ W0,
                    float* __restrict__ outq,
                    float* __restrict__ outk,
                    int M, int K)
{
    __shared__ float As[16][132];
    __shared__ float Ws[16][68];

    const int t  = threadIdx.x;
    const int m0 = blockIdx.y * 128;
    const int o0 = blockIdx.x * 64;
    const int ty = t >> 4;
    const int tx = t & 15;

    double acc[8][4];
    #pragma unroll
    for (int i = 0; i < 8; ++i)
        #pragma unroll
        for (int j = 0; j < 4; ++j) acc[i][j] = 0.0;

    for (int k0 = 0; k0 < K; k0 += 16) {
        #pragma unroll
        for (int i = 0; i < 2; ++i) {
            int vix = t + i * 256;
            int r   = vix >> 2;
            int c4  = vix & 3;
            const float4 a4 = *reinterpret_cast<const float4*>(&A[(size_t)(m0 + r) * K + k0 + c4 * 4]);
            As[c4 * 4 + 0][r] = a4.x;
            As[c4 * 4 + 1][r] = a4.y;
            As[c4 * 4 + 2][r] = a4.z;
            As[c4 * 4 + 3][r] = a4.w;
        }
        {
            int c  = t >> 2;
            int c4 = t & 3;
            const float4 w4 = *reinterpret_cast<const float4*>(&W0[(size_t)(o0 + c) * K + k0 + c4 * 4]);
            Ws[c4 * 4 + 0][c] = w4.x;
            Ws[c4 * 4 + 1][c] = w4.y;
            Ws[c4 * 4 + 2][c] = w4.z;
            Ws[c4 * 4 + 3][c] = w4.w;
        }
        __syncthreads();

        f32x2 sacc[8][2];
        #pragma unroll
        for (int i = 0; i < 8; ++i)
            #pragma unroll
            for (int j = 0; j < 2; ++j) sacc[i][j] = (f32x2){0.f, 0.f};

        #pragma unroll
        for (int kk = 0; kk < 16; ++kk) {
            float a[8];
            *reinterpret_cast<float4*>(&a[0]) = *reinterpret_cast<const float4*>(&As[kk][ty * 8]);
            *reinterpret_cast<float4*>(&a[4]) = *reinterpret_cast<const float4*>(&As[kk][ty * 8 + 4]);
            const float4 wv = *reinterpret_cast<const float4*>(&Ws[kk][tx * 4]);
            const f32x2 b0 = {wv.x, wv.y};
            const f32x2 b1 = {wv.z, wv.w};
            #pragma unroll
            for (int i = 0; i < 8; ++i) {
                const f32x2 av = {a[i], a[i]};
                sacc[i][0] = pk_fma(av, b0, sacc[i][0]);
                sacc[i][1] = pk_fma(av, b1, sacc[i][1]);
            }
        }
        #pragma unroll
        for (int i = 0; i < 8; ++i) {
            acc[i][0] += (double)sacc[i][0].x;
            acc[i][1] += (double)sacc[i][0].y;
            acc[i][2] += (double)sacc[i][1].x;
            acc[i][3] += (double)sacc[i][1].y;
        }
        __syncthreads();
    }

    int oo = o0 + tx * 4;
    float* dst = (oo < 1024) ? outq : outk;
    oo &= 1023;
    const int hh = oo >> 6, d0 = oo & 63;
    #pragma unroll
    for (int i = 0; i < 8; ++i) {
        int m = m0 + ty * 8 + i;
        int bb_ = m >> 10, n = m & 1023;
        float4 r0 = make_float4((float)acc[i][0], (float)acc[i][1],
                                (float)acc[i][2], (float)acc[i][3]);
        *reinterpret_cast<float4*>(&dst[((((size_t)bb_ * H_) + hh) * N_ + n) * HD_ + d0]) = r0;
    }
}

// ---------------------------------------------------------------------------
__global__ void wsum_kernel(const float* __restrict__ W_v, double* __restrict__ wsh)
{
    const int k = blockIdx.x * 256 + threadIdx.x;
    const int h = blockIdx.y;
    double s = 0.0;
    #pragma unroll 8
    for (int d = 0; d < 64; ++d) s += (double)W_v[(size_t)(h * 64 + d) * C_ + k];
    wsh[h * C_ + k] = s;
}

__global__ __launch_bounds__(256)
void vall_kernel(const float* __restrict__ x, const double* __restrict__ wsh,
                 double* __restrict__ Vall)
{
    __shared__ double ws_s[1024];
    const int h = blockIdx.y, b = blockIdx.z;
    const int m = blockIdx.x * 256 + threadIdx.x;
    for (int i = threadIdx.x; i < 1024; i += 256) ws_s[i] = wsh[h * C_ + i];
    __syncthreads();
    const float* xr = x + ((size_t)b * N_ + m) * C_;
    double acc = 0.0;
    #pragma unroll 8
    for (int kk = 0; kk < 1024; ++kk) acc += (double)xr[kk] * ws_s[kk];
    Vall[((size_t)b * H_ + h) * N_ + m] = acc;
}

// ---------------------------------------------------------------------------
// Fused attention (r12 structure, validated): QK packed f32, f64 weights,
// PV via bf16 MFMA. Only change: attn output written as bf16 (feeds the
// bf16 MFMA proj GEMM).
// ---------------------------------------------------------------------------
__global__ __launch_bounds__(256)
void attn_kernel(const float* __restrict__ q,
                 const float* __restrict__ k,
                 const unsigned short* __restrict__ vtb, // [B][1024 d][N] bf16
                 const double* __restrict__ Vall,        // [B][H][N]
                 const float* __restrict__ coord,        // [B][N][3]
                 const float* __restrict__ W_pos,        // [H][4]
                 const float* __restrict__ gating,       // [H]
                 unsigned short* __restrict__ attnB)     // [B][N][C] bf16
{
    __shared__ float4 Qs4[16][16];
    __shared__ float4 Kt4[64][16];
    __shared__ __align__(16) unsigned short ptB[16 * 64];
    __shared__ __align__(16) unsigned short qtB[16 * 64];
    __shared__ __align__(16) unsigned short VtB[2][64 * 64];
    __shared__ float qc[16][3];
    __shared__ double w1L[16], w2L[16], SL[16];

    const int t  = threadIdx.x;
    const int w  = t >> 6;
    const int l  = t & 63;
    const int n0 = blockIdx.x * 16;
    const int h  = blockIdx.y;
    const int b  = blockIdx.z;
    const size_t bhN = ((size_t)b * H_ + h) * N_;

    const int sr0 = t >> 4;
    const int sc  = t & 15;
    const int vd  = t >> 2;
    const int vkc = (t & 3) * 16;
    const unsigned short* vrow = vtb + (((size_t)b * H_ + h) * 64 + vd) * N_;
    const int vswz = (vd & 7) << 4;

    Qs4[t >> 4][t & 15] = reinterpret_cast<const float4*>(q + (bhN + n0) * HD_)[t];
    if (t < 48) qc[t / 3][t % 3] = coord[((size_t)b * N_ + n0 + t / 3) * 3 + (t % 3)];
    const double w4hd = (double)W_pos[h * 4 + 3];
    const double ghd  = 1.0 / (1.0 + exp(-(double)gating[h]));

    double sp[4], sq[4], spv[4], sqv[4];
    f32x4 accP = {0.f, 0.f, 0.f, 0.f};
    f32x4 accQ = {0.f, 0.f, 0.f, 0.f};
    #pragma unroll
    for (int i = 0; i < 4; ++i) { sp[i] = 0.0; sq[i] = 0.0; spv[i] = 0.0; sqv[i] = 0.0; }

    {
        const float4* kb4 = reinterpret_cast<const float4*>(k + bhN * HD_);
        #pragma unroll
        for (int i = 0; i < 4; ++i)
            Kt4[sr0 + i * 16][sc ^ ((sr0 + i * 16) & 15)] = kb4[t + i * 256];
        const bf16x8 v0 = *reinterpret_cast<const bf16x8*>(vrow + vkc);
        const bf16x8 v1 = *reinterpret_cast<const bf16x8*>(vrow + vkc + 8);
        char* vb = reinterpret_cast<char*>(&VtB[0][0]);
        *reinterpret_cast<bf16x8*>(vb + ((vd * 128 + vkc * 2)      ^ vswz)) = v0;
        *reinterpret_cast<bf16x8*>(vb + ((vd * 128 + vkc * 2 + 16) ^ vswz)) = v1;
    }
    double Vm  = Vall[bhN + l];
    double cmx = (double)coord[((size_t)b * N_ + l) * 3 + 0];
    double cmy = (double)coord[((size_t)b * N_ + l) * 3 + 1];
    double cmz = (double)coord[((size_t)b * N_ + l) * 3 + 2];
    __syncthreads();

    for (int t16 = 0; t16 < 16; ++t16) {
        const int m0   = t16 * 64;
        const int vcur = t16 & 1;

        float4 st0, st1, st2, st3;
        bf16x8 sv0, sv1;
        double VmN = 0.0, cmxN = 0.0, cmyN = 0.0, cmzN = 0.0;
        if (t16 < 15) {
            const float4* kb4 = reinterpret_cast<const float4*>(k + (bhN + m0 + 64) * HD_);
            st0 = kb4[t];
            st1 = kb4[t + 256];
            st2 = kb4[t + 512];
            st3 = kb4[t + 768];
            sv0 = *reinterpret_cast<const bf16x8*>(vrow + m0 + 64 + vkc);
            sv1 = *reinterpret_cast<const bf16x8*>(vrow + m0 + 64 + vkc + 8);
            VmN  = Vall[bhN + m0 + 64 + l];
            cmxN = (double)coord[((size_t)b * N_ + m0 + 64 + l) * 3 + 0];
            cmyN = (double)coord[((size_t)b * N_ + m0 + 64 + l) * 3 + 1];
            cmzN = (double)coord[((size_t)b * N_ + m0 + 64 + l) * 3 + 2];
        }

        f32x2 dot2[4][2];
        #pragma unroll
        for (int i = 0; i < 4; ++i) {
            dot2[i][0] = (f32x2){0.f, 0.f};
            dot2[i][1] = (f32x2){0.f, 0.f};
        }
        #pragma unroll
        for (int d4 = 0; d4 < 16; ++d4) {
            const float4 kt = Kt4[l][d4 ^ (l & 15)];
            const int g = d4 >> 3;
            const f32x2 kxy = {kt.x, kt.y};
            const f32x2 kzw = {kt.z, kt.w};
            #pragma unroll
            for (int i = 0; i < 4; ++i) {
                const float4 q4 = Qs4[w + 4 * i][d4];
                dot2[i][g] = pk_fma(kxy, (f32x2){q4.x, q4.y}, dot2[i][g]);
                dot2[i][g] = pk_fma(kzw, (f32x2){q4.z, q4.w}, dot2[i][g]);
            }
        }

        #pragma unroll
        for (int i = 0; i < 4; ++i) {
            const int r = w + 4 * i;
            const double lg = (((double)dot2[i][0].x + (double)dot2[i][0].y) +
                               ((double)dot2[i][1].x + (double)dot2[i][1].y)) * 0.125;
            const double p64 = fast_exp64(lg);
            const double dx = (double)qc[r][0] - cmx;
            const double dy = (double)qc[r][1] - cmy;
            const double dz = (double)qc[r][2] - cmz;
            const double r2 = __fma_rn(dx, dx, __fma_rn(dy, dy, dz * dz));
            const double y0 = (double)rsqrtf((float)r2);
            const double y1 = y0 * __fma_rn(-0.5 * r2, y0 * y0, 1.5);
            const double dist = (r2 > 0.0) ? r2 * y1 : 0.0;
            const double q64 = fast_exp64(dist * w4hd);
            const int off = (r * 128 + l * 2) ^ ((r & 7) << 4);
            *reinterpret_cast<unsigned short*>(reinterpret_cast<char*>(ptB) + off) = f2bf((float)p64);
            *reinterpret_cast<unsigned short*>(reinterpret_cast<char*>(qtB) + off) = f2bf((float)q64);
            sp[i]  += p64;
            sq[i]  += q64;
            spv[i] += p64 * Vm;
            sqv[i] += q64 * Vm;
        }
        __syncthreads();   // barrier A

        {
            const int r_   = l & 15;
            const int kb_  = l >> 4;
            const int aoff = r_ * 128 + kb_ * 16;
            const int aswz = (r_ & 7) << 4;
            const int dimw = w * 16 + r_;
            const int boff = dimw * 128 + kb_ * 16;
            const int bswz = (dimw & 7) << 4;
            const char* pbase = reinterpret_cast<const char*>(ptB);
            const char* qbase = reinterpret_cast<const char*>(qtB);
            const char* vbase = reinterpret_cast<const char*>(&VtB[vcur][0]);
            #pragma unroll
            for (int kh = 0; kh < 2; ++kh) {
                const bf16x8 afp = *reinterpret_cast<const bf16x8*>(pbase + ((aoff + kh * 64) ^ aswz));
                const bf16x8 afq = *reinterpret_cast<const bf16x8*>(qbase + ((aoff + kh * 64) ^ aswz));
                const bf16x8 bf_ = *reinterpret_cast<const bf16x8*>(vbase + ((boff + kh * 64) ^ bswz));
                accP = __builtin_amdgcn_mfma_f32_16x16x32_bf16(afp, bf_, accP, 0, 0, 0);
                accQ = __builtin_amdgcn_mfma_f32_16x16x32_bf16(afq, bf_, accQ, 0, 0, 0);
            }
        }

        if (t16 < 15) {
            Kt4[sr0     ][sc ^ ( sr0       & 15)] = st0;
            Kt4[sr0 + 16][sc ^ ((sr0 + 16) & 15)] = st1;
            Kt4[sr0 + 32][sc ^ ((sr0 + 32) & 15)] = st2;
            Kt4[sr0 + 48][sc ^ ((sr0 + 48) & 15)] = st3;
            char* vb = reinterpret_cast<char*>(&VtB[vcur ^ 1][0]);
            *reinterpret_cast<bf16x8*>(vb + ((vd * 128 + vkc * 2)      ^ vswz)) = sv0;
            *reinterpret_cast<bf16x8*>(vb + ((vd * 128 + vkc * 2 + 16) ^ vswz)) = sv1;
            Vm = VmN; cmx = cmxN; cmy = cmyN; cmz = cmzN;
        }
        __syncthreads();   // barrier B
    }

    // ---- epilogue: per-row S -> LDS share -> bf16 store
    #pragma unroll
    for (int i = 0; i < 4; ++i) {
        double vsp = sp[i], vsq = sq[i], vspv = spv[i], vsqv = sqv[i];
        #pragma unroll
        for (int mm = 32; mm >= 1; mm >>= 1) {
            vsp  += __shfl_xor(vsp,  mm);
            vsq  += __shfl_xor(vsq,  mm);
            vspv += __shfl_xor(vspv, mm);
            vsqv += __shfl_xor(vsqv, mm);
        }
        const double w1 = (1.0 - ghd) / vsp;
        const double w2 = ghd / vsq;
        if (l == 0) {
            w1L[w + 4 * i] = w1;
            w2L[w + 4 * i] = w2;
            SL[w + 4 * i]  = w1 * vspv + w2 * vsqv;
        }
    }
    __syncthreads();
    const int col = h * HD_ + w * 16 + (l & 15);
    #pragma unroll
    for (int j = 0; j < 4; ++j) {
        const int m = 4 * (l >> 4) + j;
        const double a = w1L[m] * (double)accP[j] + w2L[m] * (double)accQ[j];
        attnB[((size_t)b * N_ + n0 + m) * C_ + col] = f2bf((float)(a / SL[m]));
    }
}

// ---------------------------------------------------------------------------
extern "C" void kernel_launch(void* const* d_in, const int* in_sizes, int n_in,
                              void* d_out, int out_size, void* d_ws, size_t ws_size,
                              hipStream_t stream)
{
    const float* x      = (const float*)d_in[0];
    const float* coord  = (const float*)d_in[1];
    const float* W_qk   = (const float*)d_in[2];
    const float* W_v    = (const float*)d_in[3];
    const float* W_proj = (const float*)d_in[4];
    const float* b_proj = (const float*)d_in[5];
    const float* W_pos  = (const float*)d_in[6];
    // d_in[7] = b_pos (cancels in softmax), d_in[9] = pos_emb (cancels) — unused
    const float* gating = (const float*)d_in[8];

    float* ws   = (float*)d_ws;
    const size_t per = (size_t)B_ * H_ * N_ * HD_;   // 4,194,304 elements
    float*          qb    = ws;                          // 16MB
    float*          kb    = qb + per;                    // 16MB
    unsigned short* attnB = (unsigned short*)(kb + per); // 8MB bf16
    unsigned short* vtb   = attnB + per;                 // 8MB bf16
    unsigned short* xB    = vtb + per;                   // 8MB bf16
    unsigned short* WvB   = xB + per;                    // 2MB bf16
    unsigned short* WpB   = WvB + (size_t)C_ * C_;       // 2MB bf16
    double*         wsh   = (double*)(WpB + (size_t)C_ * C_);
    double*         Vall  = wsh + (size_t)H_ * C_;
    float*          out   = (float*)d_out;

    // bf16 conversions for the damped-path MFMA GEMMs
    cvt_bf16_kernel<<<2048, 256, 0, stream>>>(x, xB, (int)per);
    cvt_bf16_kernel<<<512, 256, 0, stream>>>(W_v, WvB, C_ * C_);
    cvt_bf16_kernel<<<512, 256, 0, stream>>>(W_proj, WpB, C_ * C_);

    // exact S-path precomputation
    wsum_kernel<<<dim3(4, 16), 256, 0, stream>>>(W_v, wsh);
    vall_kernel<<<dim3(4, 16, 4), 256, 0, stream>>>(x, wsh, Vall);

    // q,k: slab-f64 GEMM (exact path)
    gemm_qk_kernel<<<dim3(32, 32), 256, 0, stream>>>(x, W_qk, qb, kb, B_ * N_, C_);

    // v^T bf16 via MFMA: C[d][n] = sum_k Wv[d][k]*x[b][n][k]
    mfma_gemm_kernel<1><<<dim3(16, 8, 4), 256, 0, stream>>>(
        WvB, xB, nullptr, nullptr, vtb, C_, N_, C_);

    // fused attention (bf16 out)
    attn_kernel<<<dim3(N_ / 16, H_, B_), 256, 0, stream>>>(
        qb, kb, vtb, Vall, coord, W_pos, gating, attnB);

    // proj via MFMA: out[m][o] = sum_k attnB[m][k]*Wp[o][k] + b[o]
    mfma_gemm_kernel<0><<<dim3(16, 32, 1), 256, 0, stream>>>(
        attnB, WpB, b_proj, out, nullptr, B_ * N_, C_, C_);
}

// Round 14
// 735.380 us; speedup vs baseline: 2.4375x; 1.0062x over previous
//
#include <hip/hip_runtime.h>
#include <math.h>

#define B_ 4
#define N_ 1024
#define C_ 1024
#define H_ 16
#define HD_ 64

typedef float f32x2 __attribute__((ext_vector_type(2)));
typedef float f32x4 __attribute__((ext_vector_type(4)));
typedef short bf16x8 __attribute__((ext_vector_type(8)));

__device__ __forceinline__ f32x2 pk_fma(f32x2 a, f32x2 b, f32x2 c) {
#if __has_builtin(__builtin_elementwise_fma)
    return __builtin_elementwise_fma(a, b, c);
#else
    f32x2 r; r.x = fmaf(a.x, b.x, c.x); r.y = fmaf(a.y, b.y, c.y); return r;
#endif
}

__device__ __forceinline__ unsigned short f2bf(float v) {   // RNE f32->bf16
    unsigned u = __float_as_uint(v);
    u += 0x7FFFu + ((u >> 16) & 1u);
    return (unsigned short)(u >> 16);
}

__device__ __forceinline__ float fast_exp2f(float x) {
#if __has_builtin(__builtin_amdgcn_exp2f)
    return __builtin_amdgcn_exp2f(x);   // v_exp_f32, ~1 ulp
#else
    return exp2f(x);
#endif
}

// ---------------------------------------------------------------------------
// ERROR MODEL (validated r4..r13; r13 absmax 32 vs 97):
//   Weight error ε enters S as ε·std(V)/√N_eff (per softmax):
//   - PATCH softmax: diffuse (N_eff~870) ×(1-g) -> ε budget ~9e-7
//     => f32 HW exp2 admissible (ε≈3.6e-7, f64-combined logit).  [r14 NEW]
//   - POS softmax: concentrated (N_eff~5) ×g -> ε ≤ ~8e-8 => f64 chain
//     (f64 dist + fast_exp64) mandatory (r3 measured f32 fail).
//   EXACT S path: f64 Vall collapse; q,k slab-f32/f64-fold GEMM (fold @32K,
//   √2 on a subdominant term). DAMPED paths bf16 MFMA (validated r12/r13).
// PERF: attn f64 weight phase ~55% -> patch-f32-exp cuts ~16 f64 ops/row;
//   gemm_qk fold halved.
// ---------------------------------------------------------------------------

// fast f64 exp for |a| <= ~16: range-reduce + deg-8 Taylor. rel err ~3e-10.
__device__ __forceinline__ double fast_exp64(double a) {
    const double LOG2E = 1.4426950408889634074;
    const double LN2HI = 6.93147180369123816490e-01;
    const double LN2LO = 1.90821492927058770002e-10;
    const double MAGIC = 6755399441055744.0;   // 1.5 * 2^52
    double t     = a * LOG2E;
    double shift = t + MAGIC;
    int    n     = (int)__double_as_longlong(shift);
    double nd    = shift - MAGIC;
    double f     = __fma_rn(nd, -LN2HI, a);
    f            = __fma_rn(nd, -LN2LO, f);
    double p = 2.4801587301587301587e-05;
    p = __fma_rn(p, f, 1.9841269841269841270e-04);
    p = __fma_rn(p, f, 1.3888888888888888889e-03);
    p = __fma_rn(p, f, 8.3333333333333333333e-03);
    p = __fma_rn(p, f, 4.1666666666666666667e-02);
    p = __fma_rn(p, f, 1.6666666666666666667e-01);
    p = __fma_rn(p, f, 5.0e-01);
    p = __fma_rn(p, f, 1.0);
    p = __fma_rn(p, f, 1.0);
    return p * __longlong_as_double(((long long)(1023 + n)) << 52);
}

// ---------------------------------------------------------------------------
// f32 -> bf16 bulk convert
// ---------------------------------------------------------------------------
__global__ __launch_bounds__(256)
void cvt_bf16_kernel(const float* __restrict__ src, unsigned short* __restrict__ dst, int n)
{
    const int i = (blockIdx.x * 256 + threadIdx.x) * 8;
    if (i >= n) return;
    const float4 a = *reinterpret_cast<const float4*>(&src[i]);
    const float4 b = *reinterpret_cast<const float4*>(&src[i + 4]);
    unsigned short pk[8];
    pk[0] = f2bf(a.x); pk[1] = f2bf(a.y); pk[2] = f2bf(a.z); pk[3] = f2bf(a.w);
    pk[4] = f2bf(b.x); pk[5] = f2bf(b.y); pk[6] = f2bf(b.z); pk[7] = f2bf(b.w);
    *reinterpret_cast<bf16x8*>(&dst[i]) = *reinterpret_cast<bf16x8*>(pk);
}

// ---------------------------------------------------------------------------
// bf16 MFMA GEMM (damped paths). Validated r13.
// ---------------------------------------------------------------------------
template<int OUT_BF16>
__global__ __launch_bounds__(256)
void mfma_gemm_kernel(const unsigned short* __restrict__ A,
                      const unsigned short* __restrict__ Bw,
                      const float* __restrict__ bias,
                      float* __restrict__ outF,
                      unsigned short* __restrict__ outB,
                      int M, int O, int K)
{
    __shared__ unsigned short As[128][40];
    __shared__ unsigned short Bs[64][40];

    const int t  = threadIdx.x;
    const int w  = t >> 6;
    const int l  = t & 63;
    const int o0 = blockIdx.x * 64;
    const int m0 = blockIdx.y * 128;
    const size_t zoff = (size_t)blockIdx.z * 1048576;
    Bw += zoff;

    f32x4 acc[2][4];
    #pragma unroll
    for (int r = 0; r < 2; ++r)
        #pragma unroll
        for (int c = 0; c < 4; ++c) acc[r][c] = (f32x4){0.f, 0.f, 0.f, 0.f};

    const int ar = t >> 1, aseg = t & 1;
    const int br = t >> 2, bseg = t & 3;
    const int fr = l & 15, kg = l >> 4;

    for (int k0 = 0; k0 < K; k0 += 32) {
        const bf16x8 a0 = *reinterpret_cast<const bf16x8*>(&A[(size_t)(m0 + ar) * K + k0 + aseg * 16]);
        const bf16x8 a1 = *reinterpret_cast<const bf16x8*>(&A[(size_t)(m0 + ar) * K + k0 + aseg * 16 + 8]);
        const bf16x8 b0 = *reinterpret_cast<const bf16x8*>(&Bw[(size_t)(o0 + br) * K + k0 + bseg * 8]);
        __syncthreads();
        *reinterpret_cast<bf16x8*>(&As[ar][aseg * 16])     = a0;
        *reinterpret_cast<bf16x8*>(&As[ar][aseg * 16 + 8]) = a1;
        *reinterpret_cast<bf16x8*>(&Bs[br][bseg * 8])      = b0;
        __syncthreads();

        bf16x8 bfr[4];
        #pragma unroll
        for (int c = 0; c < 4; ++c)
            bfr[c] = *reinterpret_cast<const bf16x8*>(&Bs[c * 16 + fr][kg * 8]);
        #pragma unroll
        for (int r = 0; r < 2; ++r) {
            const bf16x8 af = *reinterpret_cast<const bf16x8*>(&As[w * 32 + r * 16 + fr][kg * 8]);
            #pragma unroll
            for (int c = 0; c < 4; ++c)
                acc[r][c] = __builtin_amdgcn_mfma_f32_16x16x32_bf16(af, bfr[c], acc[r][c], 0, 0, 0);
        }
    }

    #pragma unroll
    for (int c = 0; c < 4; ++c) {
        const int col = o0 + c * 16 + fr;
        const float bv = (OUT_BF16 == 0) ? bias[col] : 0.f;
        #pragma unroll
        for (int r = 0; r < 2; ++r) {
            #pragma unroll
            for (int j = 0; j < 4; ++j) {
                const int row = m0 + w * 32 + r * 16 + kg * 4 + j;
                const float v = acc[r][c][j] + bv;
                if (OUT_BF16)
                    outB[zoff + (size_t)row * O + col] = f2bf(v);
                else
                    outF[(size_t)row * O + col] = v;
            }
        }
    }
}

// ---------------------------------------------------------------------------
// Slab-compensated GEMM for q,k (O=2048, exact path).
// r14: f64 fold every 32 K (was 16) -- halves fold overhead.
// ---------------------------------------------------------------------------
__global__ __launch_bounds__(256)
void gemm_qk_kernel(const float* __restrict__ A,
                    const float* __restrict__ W0,
                    float* __restrict__ outq,
                    float* __restrict__ outk,
                    int M, int K)
{
    __shared__ float As[16][132];
    __shared__ float Ws[16][68];

    const int t  = threadIdx.x;
    const int m0 = blockIdx.y * 128;
    const int o0 = blockIdx.x * 64;
    const int ty = t >> 4;
    const int tx = t & 15;

    double acc[8][4];
    #pragma unroll
    for (int i = 0; i < 8; ++i)
        #pragma unroll
        for (int j = 0; j < 4; ++j) acc[i][j] = 0.0;

    f32x2 sacc[8][2];
    #pragma unroll
    for (int i = 0; i < 8; ++i)
        #pragma unroll
        for (int j = 0; j < 2; ++j) sacc[i][j] = (f32x2){0.f, 0.f};

    for (int k0 = 0; k0 < K; k0 += 16) {
        #pragma unroll
        for (int i = 0; i < 2; ++i) {
            int vix = t + i * 256;
            int r   = vix >> 2;
            int c4  = vix & 3;
            const float4 a4 = *reinterpret_cast<const float4*>(&A[(size_t)(m0 + r) * K + k0 + c4 * 4]);
            As[c4 * 4 + 0][r] = a4.x;
            As[c4 * 4 + 1][r] = a4.y;
            As[c4 * 4 + 2][r] = a4.z;
            As[c4 * 4 + 3][r] = a4.w;
        }
        {
            int c  = t >> 2;
            int c4 = t & 3;
            const float4 w4 = *reinterpret_cast<const float4*>(&W0[(size_t)(o0 + c) * K + k0 + c4 * 4]);
            Ws[c4 * 4 + 0][c] = w4.x;
            Ws[c4 * 4 + 1][c] = w4.y;
            Ws[c4 * 4 + 2][c] = w4.z;
            Ws[c4 * 4 + 3][c] = w4.w;
        }
        __syncthreads();

        #pragma unroll
        for (int kk = 0; kk < 16; ++kk) {
            float a[8];
            *reinterpret_cast<float4*>(&a[0]) = *reinterpret_cast<const float4*>(&As[kk][ty * 8]);
            *reinterpret_cast<float4*>(&a[4]) = *reinterpret_cast<const float4*>(&As[kk][ty * 8 + 4]);
            const float4 wv = *reinterpret_cast<const float4*>(&Ws[kk][tx * 4]);
            const f32x2 b0 = {wv.x, wv.y};
            const f32x2 b1 = {wv.z, wv.w};
            #pragma unroll
            for (int i = 0; i < 8; ++i) {
                const f32x2 av = {a[i], a[i]};
                sacc[i][0] = pk_fma(av, b0, sacc[i][0]);
                sacc[i][1] = pk_fma(av, b1, sacc[i][1]);
            }
        }
        // fold every 32 K (second of each slab pair); partials stay ~0.1
        if (k0 & 16) {
            #pragma unroll
            for (int i = 0; i < 8; ++i) {
                acc[i][0] += (double)sacc[i][0].x;
                acc[i][1] += (double)sacc[i][0].y;
                acc[i][2] += (double)sacc[i][1].x;
                acc[i][3] += (double)sacc[i][1].y;
                sacc[i][0] = (f32x2){0.f, 0.f};
                sacc[i][1] = (f32x2){0.f, 0.f};
            }
        }
        __syncthreads();
    }

    int oo = o0 + tx * 4;
    float* dst = (oo < 1024) ? outq : outk;
    oo &= 1023;
    const int hh = oo >> 6, d0 = oo & 63;
    #pragma unroll
    for (int i = 0; i < 8; ++i) {
        int m = m0 + ty * 8 + i;
        int bb_ = m >> 10, n = m & 1023;
        float4 r0 = make_float4((float)acc[i][0], (float)acc[i][1],
                                (float)acc[i][2], (float)acc[i][3]);
        *reinterpret_cast<float4*>(&dst[((((size_t)bb_ * H_) + hh) * N_ + n) * HD_ + d0]) = r0;
    }
}

// ---------------------------------------------------------------------------
__global__ void wsum_kernel(const float* __restrict__ W_v, double* __restrict__ wsh)
{
    const int k = blockIdx.x * 256 + threadIdx.x;
    const int h = blockIdx.y;
    double s = 0.0;
    #pragma unroll 8
    for (int d = 0; d < 64; ++d) s += (double)W_v[(size_t)(h * 64 + d) * C_ + k];
    wsh[h * C_ + k] = s;
}

__global__ __launch_bounds__(256)
void vall_kernel(const float* __restrict__ x, const double* __restrict__ wsh,
                 double* __restrict__ Vall)
{
    __shared__ double ws_s[1024];
    const int h = blockIdx.y, b = blockIdx.z;
    const int m = blockIdx.x * 256 + threadIdx.x;
    for (int i = threadIdx.x; i < 1024; i += 256) ws_s[i] = wsh[h * C_ + i];
    __syncthreads();
    const float* xr = x + ((size_t)b * N_ + m) * C_;
    double acc = 0.0;
    #pragma unroll 8
    for (int kk = 0; kk < 1024; ++kk) acc += (double)xr[kk] * ws_s[kk];
    Vall[((size_t)b * H_ + h) * N_ + m] = acc;
}

// ---------------------------------------------------------------------------
// Fused attention (r12/r13 structure): QK packed f32, weights (patch f32
// HW-exp2 / pos f64), PV via bf16 MFMA, bf16 out.
// ---------------------------------------------------------------------------
__global__ __launch_bounds__(256)
void attn_kernel(const float* __restrict__ q,
                 const float* __restrict__ k,
                 const unsigned short* __restrict__ vtb,
                 const double* __restrict__ Vall,
                 const float* __restrict__ coord,
                 const float* __restrict__ W_pos,
                 const float* __restrict__ gating,
                 unsigned short* __restrict__ attnB)
{
    __shared__ float4 Qs4[16][16];
    __shared__ float4 Kt4[64][16];
    __shared__ __align__(16) unsigned short ptB[16 * 64];
    __shared__ __align__(16) unsigned short qtB[16 * 64];
    __shared__ __align__(16) unsigned short VtB[2][64 * 64];
    __shared__ float qc[16][3];
    __shared__ double w1L[16], w2L[16], SL[16];

    const int t  = threadIdx.x;
    const int w  = t >> 6;
    const int l  = t & 63;
    const int n0 = blockIdx.x * 16;
    const int h  = blockIdx.y;
    const int b  = blockIdx.z;
    const size_t bhN = ((size_t)b * H_ + h) * N_;

    const int sr0 = t >> 4;
    const int sc  = t & 15;
    const int vd  = t >> 2;
    const int vkc = (t & 3) * 16;
    const unsigned short* vrow = vtb + (((size_t)b * H_ + h) * 64 + vd) * N_;
    const int vswz = (vd & 7) << 4;

    Qs4[t >> 4][t & 15] = reinterpret_cast<const float4*>(q + (bhN + n0) * HD_)[t];
    if (t < 48) qc[t / 3][t % 3] = coord[((size_t)b * N_ + n0 + t / 3) * 3 + (t % 3)];
    const double w4hd = (double)W_pos[h * 4 + 3];
    const double ghd  = 1.0 / (1.0 + exp(-(double)gating[h]));

    double sp[4], sq[4], spv[4], sqv[4];
    f32x4 accP = {0.f, 0.f, 0.f, 0.f};
    f32x4 accQ = {0.f, 0.f, 0.f, 0.f};
    #pragma unroll
    for (int i = 0; i < 4; ++i) { sp[i] = 0.0; sq[i] = 0.0; spv[i] = 0.0; sqv[i] = 0.0; }

    {
        const float4* kb4 = reinterpret_cast<const float4*>(k + bhN * HD_);
        #pragma unroll
        for (int i = 0; i < 4; ++i)
            Kt4[sr0 + i * 16][sc ^ ((sr0 + i * 16) & 15)] = kb4[t + i * 256];
        const bf16x8 v0 = *reinterpret_cast<const bf16x8*>(vrow + vkc);
        const bf16x8 v1 = *reinterpret_cast<const bf16x8*>(vrow + vkc + 8);
        char* vb = reinterpret_cast<char*>(&VtB[0][0]);
        *reinterpret_cast<bf16x8*>(vb + ((vd * 128 + vkc * 2)      ^ vswz)) = v0;
        *reinterpret_cast<bf16x8*>(vb + ((vd * 128 + vkc * 2 + 16) ^ vswz)) = v1;
    }
    double Vm  = Vall[bhN + l];
    double cmx = (double)coord[((size_t)b * N_ + l) * 3 + 0];
    double cmy = (double)coord[((size_t)b * N_ + l) * 3 + 1];
    double cmz = (double)coord[((size_t)b * N_ + l) * 3 + 2];
    __syncthreads();

    for (int t16 = 0; t16 < 16; ++t16) {
        const int m0   = t16 * 64;
        const int vcur = t16 & 1;

        float4 st0, st1, st2, st3;
        bf16x8 sv0, sv1;
        double VmN = 0.0, cmxN = 0.0, cmyN = 0.0, cmzN = 0.0;
        if (t16 < 15) {
            const float4* kb4 = reinterpret_cast<const float4*>(k + (bhN + m0 + 64) * HD_);
            st0 = kb4[t];
            st1 = kb4[t + 256];
            st2 = kb4[t + 512];
            st3 = kb4[t + 768];
            sv0 = *reinterpret_cast<const bf16x8*>(vrow + m0 + 64 + vkc);
            sv1 = *reinterpret_cast<const bf16x8*>(vrow + m0 + 64 + vkc + 8);
            VmN  = Vall[bhN + m0 + 64 + l];
            cmxN = (double)coord[((size_t)b * N_ + m0 + 64 + l) * 3 + 0];
            cmyN = (double)coord[((size_t)b * N_ + m0 + 64 + l) * 3 + 1];
            cmzN = (double)coord[((size_t)b * N_ + m0 + 64 + l) * 3 + 2];
        }

        f32x2 dot2[4][2];
        #pragma unroll
        for (int i = 0; i < 4; ++i) {
            dot2[i][0] = (f32x2){0.f, 0.f};
            dot2[i][1] = (f32x2){0.f, 0.f};
        }
        #pragma unroll
        for (int d4 = 0; d4 < 16; ++d4) {
            const float4 kt = Kt4[l][d4 ^ (l & 15)];
            const int g = d4 >> 3;
            const f32x2 kxy = {kt.x, kt.y};
            const f32x2 kzw = {kt.z, kt.w};
            #pragma unroll
            for (int i = 0; i < 4; ++i) {
                const float4 q4 = Qs4[w + 4 * i][d4];
                dot2[i][g] = pk_fma(kxy, (f32x2){q4.x, q4.y}, dot2[i][g]);
                dot2[i][g] = pk_fma(kzw, (f32x2){q4.z, q4.w}, dot2[i][g]);
            }
        }

        #pragma unroll
        for (int i = 0; i < 4; ++i) {
            const int r = w + 4 * i;
            // patch: f64-combined logit, f32 HW exp2 (diffuse softmax,
            // budget 9e-7 >> 3.6e-7) [r14]
            const double lgs = (((double)dot2[i][0].x + (double)dot2[i][0].y) +
                                ((double)dot2[i][1].x + (double)dot2[i][1].y));
            const float pf = fast_exp2f((float)(lgs * 0.18033688011112042));  // 0.125*log2(e)
            // pos: f64 chain (concentrated softmax, budget ~8e-8)
            const double dx = (double)qc[r][0] - cmx;
            const double dy = (double)qc[r][1] - cmy;
            const double dz = (double)qc[r][2] - cmz;
            const double r2 = __fma_rn(dx, dx, __fma_rn(dy, dy, dz * dz));
            const double y0 = (double)rsqrtf((float)r2);
            const double y1 = y0 * __fma_rn(-0.5 * r2, y0 * y0, 1.5);
            const double dist = (r2 > 0.0) ? r2 * y1 : 0.0;
            const double q64 = fast_exp64(dist * w4hd);
            const int off = (r * 128 + l * 2) ^ ((r & 7) << 4);
            *reinterpret_cast<unsigned short*>(reinterpret_cast<char*>(ptB) + off) = f2bf(pf);
            *reinterpret_cast<unsigned short*>(reinterpret_cast<char*>(qtB) + off) = f2bf((float)q64);
            sp[i]  += (double)pf;
            sq[i]  += q64;
            spv[i] += (double)pf * Vm;
            sqv[i] += q64 * Vm;
        }
        __syncthreads();   // barrier A

        {
            const int r_   = l & 15;
            const int kb_  = l >> 4;
            const int aoff = r_ * 128 + kb_ * 16;
            const int aswz = (r_ & 7) << 4;
            const int dimw = w * 16 + r_;
            const int boff = dimw * 128 + kb_ * 16;
            const int bswz = (dimw & 7) << 4;
            const char* pbase = reinterpret_cast<const char*>(ptB);
            const char* qbase = reinterpret_cast<const char*>(qtB);
            const char* vbase = reinterpret_cast<const char*>(&VtB[vcur][0]);
            #pragma unroll
            for (int kh = 0; kh < 2; ++kh) {
                const bf16x8 afp = *reinterpret_cast<const bf16x8*>(pbase + ((aoff + kh * 64) ^ aswz));
                const bf16x8 afq = *reinterpret_cast<const bf16x8*>(qbase + ((aoff + kh * 64) ^ aswz));
                const bf16x8 bf_ = *reinterpret_cast<const bf16x8*>(vbase + ((boff + kh * 64) ^ bswz));
                accP = __builtin_amdgcn_mfma_f32_16x16x32_bf16(afp, bf_, accP, 0, 0, 0);
                accQ = __builtin_amdgcn_mfma_f32_16x16x32_bf16(afq, bf_, accQ, 0, 0, 0);
            }
        }

        if (t16 < 15) {
            Kt4[sr0     ][sc ^ ( sr0       & 15)] = st0;
            Kt4[sr0 + 16][sc ^ ((sr0 + 16) & 15)] = st1;
            Kt4[sr0 + 32][sc ^ ((sr0 + 32) & 15)] = st2;
            Kt4[sr0 + 48][sc ^ ((sr0 + 48) & 15)] = st3;
            char* vb = reinterpret_cast<char*>(&VtB[vcur ^ 1][0]);
            *reinterpret_cast<bf16x8*>(vb + ((vd * 128 + vkc * 2)      ^ vswz)) = sv0;
            *reinterpret_cast<bf16x8*>(vb + ((vd * 128 + vkc * 2 + 16) ^ vswz)) = sv1;
            Vm = VmN; cmx = cmxN; cmy = cmyN; cmz = cmzN;
        }
        __syncthreads();   // barrier B
    }

    // ---- epilogue: per-row S -> LDS share -> bf16 store
    #pragma unroll
    for (int i = 0; i < 4; ++i) {
        double vsp = sp[i], vsq = sq[i], vspv = spv[i], vsqv = sqv[i];
        #pragma unroll
        for (int mm = 32; mm >= 1; mm >>= 1) {
            vsp  += __shfl_xor(vsp,  mm);
            vsq  += __shfl_xor(vsq,  mm);
            vspv += __shfl_xor(vspv, mm);
            vsqv += __shfl_xor(vsqv, mm);
        }
        const double w1 = (1.0 - ghd) / vsp;
        const double w2 = ghd / vsq;
        if (l == 0) {
            w1L[w + 4 * i] = w1;
            w2L[w + 4 * i] = w2;
            SL[w + 4 * i]  = w1 * vspv + w2 * vsqv;
        }
    }
    __syncthreads();
    const int col = h * HD_ + w * 16 + (l & 15);
    #pragma unroll
    for (int j = 0; j < 4; ++j) {
        const int m = 4 * (l >> 4) + j;
        const double a = w1L[m] * (double)accP[j] + w2L[m] * (double)accQ[j];
        attnB[((size_t)b * N_ + n0 + m) * C_ + col] = f2bf((float)(a / SL[m]));
    }
}

// ---------------------------------------------------------------------------
extern "C" void kernel_launch(void* const* d_in, const int* in_sizes, int n_in,
                              void* d_out, int out_size, void* d_ws, size_t ws_size,
                              hipStream_t stream)
{
    const float* x      = (const float*)d_in[0];
    const float* coord  = (const float*)d_in[1];
    const float* W_qk   = (const float*)d_in[2];
    const float* W_v    = (const float*)d_in[3];
    const float* W_proj = (const float*)d_in[4];
    const float* b_proj = (const float*)d_in[5];
    const float* W_pos  = (const float*)d_in[6];
    // d_in[7] = b_pos (cancels in softmax), d_in[9] = pos_emb (cancels) — unused
    const float* gating = (const float*)d_in[8];

    float* ws   = (float*)d_ws;
    const size_t per = (size_t)B_ * H_ * N_ * HD_;   // 4,194,304 elements
    float*          qb    = ws;
    float*          kb    = qb + per;
    unsigned short* attnB = (unsigned short*)(kb + per);
    unsigned short* vtb   = attnB + per;
    unsigned short* xB    = vtb + per;
    unsigned short* WvB   = xB + per;
    unsigned short* WpB   = WvB + (size_t)C_ * C_;
    double*         wsh   = (double*)(WpB + (size_t)C_ * C_);
    double*         Vall  = wsh + (size_t)H_ * C_;
    float*          out   = (float*)d_out;

    cvt_bf16_kernel<<<2048, 256, 0, stream>>>(x, xB, (int)per);
    cvt_bf16_kernel<<<512, 256, 0, stream>>>(W_v, WvB, C_ * C_);
    cvt_bf16_kernel<<<512, 256, 0, stream>>>(W_proj, WpB, C_ * C_);

    wsum_kernel<<<dim3(4, 16), 256, 0, stream>>>(W_v, wsh);
    vall_kernel<<<dim3(4, 16, 4), 256, 0, stream>>>(x, wsh, Vall);

    gemm_qk_kernel<<<dim3(32, 32), 256, 0, stream>>>(x, W_qk, qb, kb, B_ * N_, C_);

    mfma_gemm_kernel<1><<<dim3(16, 8, 4), 256, 0, stream>>>(
        WvB, xB, nullptr, nullptr, vtb, C_, N_, C_);

    attn_kernel<<<dim3(N_ / 16, H_, B_), 256, 0, stream>>>(
        qb, kb, vtb, Vall, coord, W_pos, gating, attnB);

    mfma_gemm_kernel<0><<<dim3(16, 32, 1), 256, 0, stream>>>(
        attnB, WpB, b_proj, out, nullptr, B_ * N_, C_, C_);
}

// Round 15
// 558.777 us; speedup vs baseline: 3.2079x; 1.3161x over previous
//
#include <hip/hip_runtime.h>
#include <math.h>

#define B_ 4
#define N_ 1024
#define C_ 1024
#define H_ 16
#define HD_ 64

typedef float f32x2 __attribute__((ext_vector_type(2)));
typedef float f32x4 __attribute__((ext_vector_type(4)));
typedef short bf16x8 __attribute__((ext_vector_type(8)));

__device__ __forceinline__ unsigned short f2bf(float v) {   // RNE f32->bf16
    unsigned u = __float_as_uint(v);
    u += 0x7FFFu + ((u >> 16) & 1u);
    return (unsigned short)(u >> 16);
}

__device__ __forceinline__ float bf2f(unsigned short h) {
    return __uint_as_float(((unsigned)h) << 16);
}

__device__ __forceinline__ float fast_exp2f(float x) {
#if __has_builtin(__builtin_amdgcn_exp2f)
    return __builtin_amdgcn_exp2f(x);   // v_exp_f32, ~1 ulp
#else
    return exp2f(x);
#endif
}

// ---------------------------------------------------------------------------
// ERROR MODEL (validated r4..r14; r13/r14 absmax 32 vs 97; r14 showed the
// eps->absmax model is >=2-3x conservative):
//   - PATCH softmax (diffuse, x(1-g)): eps budget ~9e-7. f32 HW exp2 OK
//     (3.6e-7, measured +0). q,k via SPLIT-bf16 MFMA (4 products, residual
//     -> delta_logit ~5e-7) admissible.                      [r15 NEW]
//   - POS softmax (concentrated, xg): f64 dist+exp chain mandatory.
//   - EXACT S path: f64 Vall collapse (wsum/vall from raw f32 inputs).
//   - DAMPED paths: PV bf16 MFMA, v-GEMM bf16 MFMA, proj bf16 MFMA.
// PERF: r12 PV-MFMA 900->439; r13 v/proj-MFMA -190; r15 qk-MFMA(split) is
//   the last VALU GEMM (190us -> ~80us).
// ---------------------------------------------------------------------------

// fast f64 exp for |a| <= ~16: range-reduce + deg-8 Taylor. rel err ~3e-10.
__device__ __forceinline__ double fast_exp64(double a) {
    const double LOG2E = 1.4426950408889634074;
    const double LN2HI = 6.93147180369123816490e-01;
    const double LN2LO = 1.90821492927058770002e-10;
    const double MAGIC = 6755399441055744.0;   // 1.5 * 2^52
    double t     = a * LOG2E;
    double shift = t + MAGIC;
    int    n     = (int)__double_as_longlong(shift);
    double nd    = shift - MAGIC;
    double f     = __fma_rn(nd, -LN2HI, a);
    f            = __fma_rn(nd, -LN2LO, f);
    double p = 2.4801587301587301587e-05;
    p = __fma_rn(p, f, 1.9841269841269841270e-04);
    p = __fma_rn(p, f, 1.3888888888888888889e-03);
    p = __fma_rn(p, f, 8.3333333333333333333e-03);
    p = __fma_rn(p, f, 4.1666666666666666667e-02);
    p = __fma_rn(p, f, 1.6666666666666666667e-01);
    p = __fma_rn(p, f, 5.0e-01);
    p = __fma_rn(p, f, 1.0);
    p = __fma_rn(p, f, 1.0);
    return p * __longlong_as_double(((long long)(1023 + n)) << 52);
}

// ---------------------------------------------------------------------------
// f32 -> bf16 bulk convert
// ---------------------------------------------------------------------------
__global__ __launch_bounds__(256)
void cvt_bf16_kernel(const float* __restrict__ src, unsigned short* __restrict__ dst, int n)
{
    const int i = (blockIdx.x * 256 + threadIdx.x) * 8;
    if (i >= n) return;
    const float4 a = *reinterpret_cast<const float4*>(&src[i]);
    const float4 b = *reinterpret_cast<const float4*>(&src[i + 4]);
    unsigned short pk[8];
    pk[0] = f2bf(a.x); pk[1] = f2bf(a.y); pk[2] = f2bf(a.z); pk[3] = f2bf(a.w);
    pk[4] = f2bf(b.x); pk[5] = f2bf(b.y); pk[6] = f2bf(b.z); pk[7] = f2bf(b.w);
    *reinterpret_cast<bf16x8*>(&dst[i]) = *reinterpret_cast<bf16x8*>(pk);
}

// ---------------------------------------------------------------------------
// f32 -> (hi, lo) bf16 split: hi = bf16(v), lo = bf16(v - hi). v-hi exact
// (Sterbenz). Residual |v - hi - lo| <~ 2^-18 |v|.
// ---------------------------------------------------------------------------
__global__ __launch_bounds__(256)
void cvt_split_kernel(const float* __restrict__ src,
                      unsigned short* __restrict__ hi,
                      unsigned short* __restrict__ lo, int n)
{
    const int i = (blockIdx.x * 256 + threadIdx.x) * 8;
    if (i >= n) return;
    unsigned short ph[8], pl[8];
    #pragma unroll
    for (int j = 0; j < 8; ++j) {
        const float v = src[i + j];
        const unsigned short h = f2bf(v);
        ph[j] = h;
        pl[j] = f2bf(v - bf2f(h));
    }
    *reinterpret_cast<bf16x8*>(&hi[i]) = *reinterpret_cast<bf16x8*>(ph);
    *reinterpret_cast<bf16x8*>(&lo[i]) = *reinterpret_cast<bf16x8*>(pl);
}

// ---------------------------------------------------------------------------
// Split-bf16 MFMA GEMM for q,k (exact-ish path, ~f32 accuracy):
// q|k[m][o] = sum_k x[m][k]*Wqk[o][k], via (xh+xl)(Wh+Wl) = 4 MFMA products.
// Tile 128x64, BK=32, 4 waves. Frag layouts = r12/r13-validated.
// Scatter-stores f32 into q/k [B][H][N][64].
// ---------------------------------------------------------------------------
__global__ __launch_bounds__(256)
void qk_split_kernel(const unsigned short* __restrict__ Ahi,  // [M][K]
                     const unsigned short* __restrict__ Alo,
                     const unsigned short* __restrict__ Bhi,  // [O][K]
                     const unsigned short* __restrict__ Blo,
                     float* __restrict__ outq,
                     float* __restrict__ outk,
                     int M, int O, int K)
{
    __shared__ unsigned short Ash[128][40];
    __shared__ unsigned short Asl[128][40];
    __shared__ unsigned short Bsh[64][40];
    __shared__ unsigned short Bsl[64][40];

    const int t  = threadIdx.x;
    const int w  = t >> 6;
    const int l  = t & 63;
    const int o0 = blockIdx.x * 64;
    const int m0 = blockIdx.y * 128;

    f32x4 acc[2][4];
    #pragma unroll
    for (int r = 0; r < 2; ++r)
        #pragma unroll
        for (int c = 0; c < 4; ++c) acc[r][c] = (f32x4){0.f, 0.f, 0.f, 0.f};

    const int ar = t >> 1, aseg = t & 1;
    const int br = t >> 2, bseg = t & 3;
    const int fr = l & 15, kg = l >> 4;

    for (int k0 = 0; k0 < K; k0 += 32) {
        const size_t abase = (size_t)(m0 + ar) * K + k0 + aseg * 16;
        const size_t bbase = (size_t)(o0 + br) * K + k0 + bseg * 8;
        const bf16x8 ah0 = *reinterpret_cast<const bf16x8*>(&Ahi[abase]);
        const bf16x8 ah1 = *reinterpret_cast<const bf16x8*>(&Ahi[abase + 8]);
        const bf16x8 al0 = *reinterpret_cast<const bf16x8*>(&Alo[abase]);
        const bf16x8 al1 = *reinterpret_cast<const bf16x8*>(&Alo[abase + 8]);
        const bf16x8 bh0 = *reinterpret_cast<const bf16x8*>(&Bhi[bbase]);
        const bf16x8 bl0 = *reinterpret_cast<const bf16x8*>(&Blo[bbase]);
        __syncthreads();
        *reinterpret_cast<bf16x8*>(&Ash[ar][aseg * 16])     = ah0;
        *reinterpret_cast<bf16x8*>(&Ash[ar][aseg * 16 + 8]) = ah1;
        *reinterpret_cast<bf16x8*>(&Asl[ar][aseg * 16])     = al0;
        *reinterpret_cast<bf16x8*>(&Asl[ar][aseg * 16 + 8]) = al1;
        *reinterpret_cast<bf16x8*>(&Bsh[br][bseg * 8])      = bh0;
        *reinterpret_cast<bf16x8*>(&Bsl[br][bseg * 8])      = bl0;
        __syncthreads();

        bf16x8 bfh[4], bfl[4];
        #pragma unroll
        for (int c = 0; c < 4; ++c) {
            bfh[c] = *reinterpret_cast<const bf16x8*>(&Bsh[c * 16 + fr][kg * 8]);
            bfl[c] = *reinterpret_cast<const bf16x8*>(&Bsl[c * 16 + fr][kg * 8]);
        }
        #pragma unroll
        for (int r = 0; r < 2; ++r) {
            const bf16x8 afh = *reinterpret_cast<const bf16x8*>(&Ash[w * 32 + r * 16 + fr][kg * 8]);
            const bf16x8 afl = *reinterpret_cast<const bf16x8*>(&Asl[w * 32 + r * 16 + fr][kg * 8]);
            #pragma unroll
            for (int c = 0; c < 4; ++c) {
                f32x4 a = acc[r][c];
                a = __builtin_amdgcn_mfma_f32_16x16x32_bf16(afh, bfh[c], a, 0, 0, 0);
                a = __builtin_amdgcn_mfma_f32_16x16x32_bf16(afh, bfl[c], a, 0, 0, 0);
                a = __builtin_amdgcn_mfma_f32_16x16x32_bf16(afl, bfh[c], a, 0, 0, 0);
                a = __builtin_amdgcn_mfma_f32_16x16x32_bf16(afl, bfl[c], a, 0, 0, 0);
                acc[r][c] = a;
            }
        }
    }

    // scatter f32: row -> (b,n), col -> (q|k, head, dim)
    #pragma unroll
    for (int c = 0; c < 4; ++c) {
        int oo = o0 + c * 16 + fr;
        float* dst = (oo < 1024) ? outq : outk;
        oo &= 1023;
        const int hh = oo >> 6, d0 = oo & 63;
        #pragma unroll
        for (int r = 0; r < 2; ++r) {
            #pragma unroll
            for (int j = 0; j < 4; ++j) {
                const int m = m0 + w * 32 + r * 16 + kg * 4 + j;
                const int bb_ = m >> 10, n = m & 1023;
                dst[((((size_t)bb_ * H_) + hh) * N_ + n) * HD_ + d0] = acc[r][c][j];
            }
        }
    }
}

// ---------------------------------------------------------------------------
// bf16 MFMA GEMM (damped paths). Validated r13.
// ---------------------------------------------------------------------------
template<int OUT_BF16>
__global__ __launch_bounds__(256)
void mfma_gemm_kernel(const unsigned short* __restrict__ A,
                      const unsigned short* __restrict__ Bw,
                      const float* __restrict__ bias,
                      float* __restrict__ outF,
                      unsigned short* __restrict__ outB,
                      int M, int O, int K)
{
    __shared__ unsigned short As[128][40];
    __shared__ unsigned short Bs[64][40];

    const int t  = threadIdx.x;
    const int w  = t >> 6;
    const int l  = t & 63;
    const int o0 = blockIdx.x * 64;
    const int m0 = blockIdx.y * 128;
    const size_t zoff = (size_t)blockIdx.z * 1048576;
    Bw += zoff;

    f32x4 acc[2][4];
    #pragma unroll
    for (int r = 0; r < 2; ++r)
        #pragma unroll
        for (int c = 0; c < 4; ++c) acc[r][c] = (f32x4){0.f, 0.f, 0.f, 0.f};

    const int ar = t >> 1, aseg = t & 1;
    const int br = t >> 2, bseg = t & 3;
    const int fr = l & 15, kg = l >> 4;

    for (int k0 = 0; k0 < K; k0 += 32) {
        const bf16x8 a0 = *reinterpret_cast<const bf16x8*>(&A[(size_t)(m0 + ar) * K + k0 + aseg * 16]);
        const bf16x8 a1 = *reinterpret_cast<const bf16x8*>(&A[(size_t)(m0 + ar) * K + k0 + aseg * 16 + 8]);
        const bf16x8 b0 = *reinterpret_cast<const bf16x8*>(&Bw[(size_t)(o0 + br) * K + k0 + bseg * 8]);
        __syncthreads();
        *reinterpret_cast<bf16x8*>(&As[ar][aseg * 16])     = a0;
        *reinterpret_cast<bf16x8*>(&As[ar][aseg * 16 + 8]) = a1;
        *reinterpret_cast<bf16x8*>(&Bs[br][bseg * 8])      = b0;
        __syncthreads();

        bf16x8 bfr[4];
        #pragma unroll
        for (int c = 0; c < 4; ++c)
            bfr[c] = *reinterpret_cast<const bf16x8*>(&Bs[c * 16 + fr][kg * 8]);
        #pragma unroll
        for (int r = 0; r < 2; ++r) {
            const bf16x8 af = *reinterpret_cast<const bf16x8*>(&As[w * 32 + r * 16 + fr][kg * 8]);
            #pragma unroll
            for (int c = 0; c < 4; ++c)
                acc[r][c] = __builtin_amdgcn_mfma_f32_16x16x32_bf16(af, bfr[c], acc[r][c], 0, 0, 0);
        }
    }

    #pragma unroll
    for (int c = 0; c < 4; ++c) {
        const int col = o0 + c * 16 + fr;
        const float bv = (OUT_BF16 == 0) ? bias[col] : 0.f;
        #pragma unroll
        for (int r = 0; r < 2; ++r) {
            #pragma unroll
            for (int j = 0; j < 4; ++j) {
                const int row = m0 + w * 32 + r * 16 + kg * 4 + j;
                const float v = acc[r][c][j] + bv;
                if (OUT_BF16)
                    outB[zoff + (size_t)row * O + col] = f2bf(v);
                else
                    outF[(size_t)row * O + col] = v;
            }
        }
    }
}

// ---------------------------------------------------------------------------
__global__ void wsum_kernel(const float* __restrict__ W_v, double* __restrict__ wsh)
{
    const int k = blockIdx.x * 256 + threadIdx.x;
    const int h = blockIdx.y;
    double s = 0.0;
    #pragma unroll 8
    for (int d = 0; d < 64; ++d) s += (double)W_v[(size_t)(h * 64 + d) * C_ + k];
    wsh[h * C_ + k] = s;
}

__global__ __launch_bounds__(256)
void vall_kernel(const float* __restrict__ x, const double* __restrict__ wsh,
                 double* __restrict__ Vall)
{
    __shared__ double ws_s[1024];
    const int h = blockIdx.y, b = blockIdx.z;
    const int m = blockIdx.x * 256 + threadIdx.x;
    for (int i = threadIdx.x; i < 1024; i += 256) ws_s[i] = wsh[h * C_ + i];
    __syncthreads();
    const float* xr = x + ((size_t)b * N_ + m) * C_;
    double acc = 0.0;
    #pragma unroll 8
    for (int kk = 0; kk < 1024; ++kk) acc += (double)xr[kk] * ws_s[kk];
    Vall[((size_t)b * H_ + h) * N_ + m] = acc;
}

// ---------------------------------------------------------------------------
// Fused attention (r14, validated): QK packed f32, patch f32-exp2 / pos f64,
// PV bf16 MFMA, bf16 out.
// ---------------------------------------------------------------------------
typedef float f32x2_ __attribute__((ext_vector_type(2)));
__device__ __forceinline__ f32x2 pk_fma(f32x2 a, f32x2 b, f32x2 c) {
#if __has_builtin(__builtin_elementwise_fma)
    return __builtin_elementwise_fma(a, b, c);
#else
    f32x2 r; r.x = fmaf(a.x, b.x, c.x); r.y = fmaf(a.y, b.y, c.y); return r;
#endif
}

__global__ __launch_bounds__(256)
void attn_kernel(const float* __restrict__ q,
                 const float* __restrict__ k,
                 const unsigned short* __restrict__ vtb,
                 const double* __restrict__ Vall,
                 const float* __restrict__ coord,
                 const float* __restrict__ W_pos,
                 const float* __restrict__ gating,
                 unsigned short* __restrict__ attnB)
{
    __shared__ float4 Qs4[16][16];
    __shared__ float4 Kt4[64][16];
    __shared__ __align__(16) unsigned short ptB[16 * 64];
    __shared__ __align__(16) unsigned short qtB[16 * 64];
    __shared__ __align__(16) unsigned short VtB[2][64 * 64];
    __shared__ float qc[16][3];
    __shared__ double w1L[16], w2L[16], SL[16];

    const int t  = threadIdx.x;
    const int w  = t >> 6;
    const int l  = t & 63;
    const int n0 = blockIdx.x * 16;
    const int h  = blockIdx.y;
    const int b  = blockIdx.z;
    const size_t bhN = ((size_t)b * H_ + h) * N_;

    const int sr0 = t >> 4;
    const int sc  = t & 15;
    const int vd  = t >> 2;
    const int vkc = (t & 3) * 16;
    const unsigned short* vrow = vtb + (((size_t)b * H_ + h) * 64 + vd) * N_;
    const int vswz = (vd & 7) << 4;

    Qs4[t >> 4][t & 15] = reinterpret_cast<const float4*>(q + (bhN + n0) * HD_)[t];
    if (t < 48) qc[t / 3][t % 3] = coord[((size_t)b * N_ + n0 + t / 3) * 3 + (t % 3)];
    const double w4hd = (double)W_pos[h * 4 + 3];
    const double ghd  = 1.0 / (1.0 + exp(-(double)gating[h]));

    double sp[4], sq[4], spv[4], sqv[4];
    f32x4 accP = {0.f, 0.f, 0.f, 0.f};
    f32x4 accQ = {0.f, 0.f, 0.f, 0.f};
    #pragma unroll
    for (int i = 0; i < 4; ++i) { sp[i] = 0.0; sq[i] = 0.0; spv[i] = 0.0; sqv[i] = 0.0; }

    {
        const float4* kb4 = reinterpret_cast<const float4*>(k + bhN * HD_);
        #pragma unroll
        for (int i = 0; i < 4; ++i)
            Kt4[sr0 + i * 16][sc ^ ((sr0 + i * 16) & 15)] = kb4[t + i * 256];
        const bf16x8 v0 = *reinterpret_cast<const bf16x8*>(vrow + vkc);
        const bf16x8 v1 = *reinterpret_cast<const bf16x8*>(vrow + vkc + 8);
        char* vb = reinterpret_cast<char*>(&VtB[0][0]);
        *reinterpret_cast<bf16x8*>(vb + ((vd * 128 + vkc * 2)      ^ vswz)) = v0;
        *reinterpret_cast<bf16x8*>(vb + ((vd * 128 + vkc * 2 + 16) ^ vswz)) = v1;
    }
    double Vm  = Vall[bhN + l];
    double cmx = (double)coord[((size_t)b * N_ + l) * 3 + 0];
    double cmy = (double)coord[((size_t)b * N_ + l) * 3 + 1];
    double cmz = (double)coord[((size_t)b * N_ + l) * 3 + 2];
    __syncthreads();

    for (int t16 = 0; t16 < 16; ++t16) {
        const int m0   = t16 * 64;
        const int vcur = t16 & 1;

        float4 st0, st1, st2, st3;
        bf16x8 sv0, sv1;
        double VmN = 0.0, cmxN = 0.0, cmyN = 0.0, cmzN = 0.0;
        if (t16 < 15) {
            const float4* kb4 = reinterpret_cast<const float4*>(k + (bhN + m0 + 64) * HD_);
            st0 = kb4[t];
            st1 = kb4[t + 256];
            st2 = kb4[t + 512];
            st3 = kb4[t + 768];
            sv0 = *reinterpret_cast<const bf16x8*>(vrow + m0 + 64 + vkc);
            sv1 = *reinterpret_cast<const bf16x8*>(vrow + m0 + 64 + vkc + 8);
            VmN  = Vall[bhN + m0 + 64 + l];
            cmxN = (double)coord[((size_t)b * N_ + m0 + 64 + l) * 3 + 0];
            cmyN = (double)coord[((size_t)b * N_ + m0 + 64 + l) * 3 + 1];
            cmzN = (double)coord[((size_t)b * N_ + m0 + 64 + l) * 3 + 2];
        }

        f32x2 dot2[4][2];
        #pragma unroll
        for (int i = 0; i < 4; ++i) {
            dot2[i][0] = (f32x2){0.f, 0.f};
            dot2[i][1] = (f32x2){0.f, 0.f};
        }
        #pragma unroll
        for (int d4 = 0; d4 < 16; ++d4) {
            const float4 kt = Kt4[l][d4 ^ (l & 15)];
            const int g = d4 >> 3;
            const f32x2 kxy = {kt.x, kt.y};
            const f32x2 kzw = {kt.z, kt.w};
            #pragma unroll
            for (int i = 0; i < 4; ++i) {
                const float4 q4 = Qs4[w + 4 * i][d4];
                dot2[i][g] = pk_fma(kxy, (f32x2){q4.x, q4.y}, dot2[i][g]);
                dot2[i][g] = pk_fma(kzw, (f32x2){q4.z, q4.w}, dot2[i][g]);
            }
        }

        #pragma unroll
        for (int i = 0; i < 4; ++i) {
            const int r = w + 4 * i;
            const double lgs = (((double)dot2[i][0].x + (double)dot2[i][0].y) +
                                ((double)dot2[i][1].x + (double)dot2[i][1].y));
            const float pf = fast_exp2f((float)(lgs * 0.18033688011112042));  // 0.125*log2(e)
            const double dx = (double)qc[r][0] - cmx;
            const double dy = (double)qc[r][1] - cmy;
            const double dz = (double)qc[r][2] - cmz;
            const double r2 = __fma_rn(dx, dx, __fma_rn(dy, dy, dz * dz));
            const double y0 = (double)rsqrtf((float)r2);
            const double y1 = y0 * __fma_rn(-0.5 * r2, y0 * y0, 1.5);
            const double dist = (r2 > 0.0) ? r2 * y1 : 0.0;
            const double q64 = fast_exp64(dist * w4hd);
            const int off = (r * 128 + l * 2) ^ ((r & 7) << 4);
            *reinterpret_cast<unsigned short*>(reinterpret_cast<char*>(ptB) + off) = f2bf(pf);
            *reinterpret_cast<unsigned short*>(reinterpret_cast<char*>(qtB) + off) = f2bf((float)q64);
            sp[i]  += (double)pf;
            sq[i]  += q64;
            spv[i] += (double)pf * Vm;
            sqv[i] += q64 * Vm;
        }
        __syncthreads();   // barrier A

        {
            const int r_   = l & 15;
            const int kb_  = l >> 4;
            const int aoff = r_ * 128 + kb_ * 16;
            const int aswz = (r_ & 7) << 4;
            const int dimw = w * 16 + r_;
            const int boff = dimw * 128 + kb_ * 16;
            const int bswz = (dimw & 7) << 4;
            const char* pbase = reinterpret_cast<const char*>(ptB);
            const char* qbase = reinterpret_cast<const char*>(qtB);
            const char* vbase = reinterpret_cast<const char*>(&VtB[vcur][0]);
            #pragma unroll
            for (int kh = 0; kh < 2; ++kh) {
                const bf16x8 afp = *reinterpret_cast<const bf16x8*>(pbase + ((aoff + kh * 64) ^ aswz));
                const bf16x8 afq = *reinterpret_cast<const bf16x8*>(qbase + ((aoff + kh * 64) ^ aswz));
                const bf16x8 bf_ = *reinterpret_cast<const bf16x8*>(vbase + ((boff + kh * 64) ^ bswz));
                accP = __builtin_amdgcn_mfma_f32_16x16x32_bf16(afp, bf_, accP, 0, 0, 0);
                accQ = __builtin_amdgcn_mfma_f32_16x16x32_bf16(afq, bf_, accQ, 0, 0, 0);
            }
        }

        if (t16 < 15) {
            Kt4[sr0     ][sc ^ ( sr0       & 15)] = st0;
            Kt4[sr0 + 16][sc ^ ((sr0 + 16) & 15)] = st1;
            Kt4[sr0 + 32][sc ^ ((sr0 + 32) & 15)] = st2;
            Kt4[sr0 + 48][sc ^ ((sr0 + 48) & 15)] = st3;
            char* vb = reinterpret_cast<char*>(&VtB[vcur ^ 1][0]);
            *reinterpret_cast<bf16x8*>(vb + ((vd * 128 + vkc * 2)      ^ vswz)) = sv0;
            *reinterpret_cast<bf16x8*>(vb + ((vd * 128 + vkc * 2 + 16) ^ vswz)) = sv1;
            Vm = VmN; cmx = cmxN; cmy = cmyN; cmz = cmzN;
        }
        __syncthreads();   // barrier B
    }

    #pragma unroll
    for (int i = 0; i < 4; ++i) {
        double vsp = sp[i], vsq = sq[i], vspv = spv[i], vsqv = sqv[i];
        #pragma unroll
        for (int mm = 32; mm >= 1; mm >>= 1) {
            vsp  += __shfl_xor(vsp,  mm);
            vsq  += __shfl_xor(vsq,  mm);
            vspv += __shfl_xor(vspv, mm);
            vsqv += __shfl_xor(vsqv, mm);
        }
        const double w1 = (1.0 - ghd) / vsp;
        const double w2 = ghd / vsq;
        if (l == 0) {
            w1L[w + 4 * i] = w1;
            w2L[w + 4 * i] = w2;
            SL[w + 4 * i]  = w1 * vspv + w2 * vsqv;
        }
    }
    __syncthreads();
    const int col = h * HD_ + w * 16 + (l & 15);
    #pragma unroll
    for (int j = 0; j < 4; ++j) {
        const int m = 4 * (l >> 4) + j;
        const double a = w1L[m] * (double)accP[j] + w2L[m] * (double)accQ[j];
        attnB[((size_t)b * N_ + n0 + m) * C_ + col] = f2bf((float)(a / SL[m]));
    }
}

// ---------------------------------------------------------------------------
extern "C" void kernel_launch(void* const* d_in, const int* in_sizes, int n_in,
                              void* d_out, int out_size, void* d_ws, size_t ws_size,
                              hipStream_t stream)
{
    const float* x      = (const float*)d_in[0];
    const float* coord  = (const float*)d_in[1];
    const float* W_qk   = (const float*)d_in[2];
    const float* W_v    = (const float*)d_in[3];
    const float* W_proj = (const float*)d_in[4];
    const float* b_proj = (const float*)d_in[5];
    const float* W_pos  = (const float*)d_in[6];
    // d_in[7] = b_pos (cancels in softmax), d_in[9] = pos_emb (cancels) — unused
    const float* gating = (const float*)d_in[8];

    float* ws   = (float*)d_ws;
    const size_t per = (size_t)B_ * H_ * N_ * HD_;   // 4,194,304 elements
    float*          qb    = ws;                          // 16MB
    float*          kb    = qb + per;                    // 16MB
    unsigned short* attnB = (unsigned short*)(kb + per); // 8MB; hosts Wqk splits pre-attn
    unsigned short* WqkHi = attnB;                       // 2M shorts (4MB)
    unsigned short* WqkLo = attnB + 2 * (size_t)C_ * C_; // 2M shorts (4MB)
    unsigned short* vtb   = attnB + per;                 // 8MB
    unsigned short* xhi   = vtb + per;                   // 8MB (also v-GEMM's A)
    unsigned short* xlo   = xhi + per;                   // 8MB
    unsigned short* WvB   = xlo + per;                   // 2MB
    unsigned short* WpB   = WvB + (size_t)C_ * C_;       // 2MB
    double*         wsh   = (double*)(WpB + (size_t)C_ * C_);
    double*         Vall  = wsh + (size_t)H_ * C_;
    float*          out   = (float*)d_out;

    // splits + bf16 conversions
    cvt_split_kernel<<<2048, 256, 0, stream>>>(x, xhi, xlo, (int)per);
    cvt_split_kernel<<<1024, 256, 0, stream>>>(W_qk, WqkHi, WqkLo, 2 * C_ * C_);
    cvt_bf16_kernel<<<512, 256, 0, stream>>>(W_v, WvB, C_ * C_);
    cvt_bf16_kernel<<<512, 256, 0, stream>>>(W_proj, WpB, C_ * C_);

    // exact S-path precomputation (from raw f32 inputs)
    wsum_kernel<<<dim3(4, 16), 256, 0, stream>>>(W_v, wsh);
    vall_kernel<<<dim3(4, 16, 4), 256, 0, stream>>>(x, wsh, Vall);

    // q,k via split-bf16 MFMA (4 products, ~f32 accuracy)
    qk_split_kernel<<<dim3(32, 32), 256, 0, stream>>>(
        xhi, xlo, WqkHi, WqkLo, qb, kb, B_ * N_, 2 * C_, C_);

    // v^T bf16 via MFMA
    mfma_gemm_kernel<1><<<dim3(16, 8, 4), 256, 0, stream>>>(
        WvB, xhi, nullptr, nullptr, vtb, C_, N_, C_);

    // fused attention (overwrites the Wqk-split region with attnB — qk done)
    attn_kernel<<<dim3(N_ / 16, H_, B_), 256, 0, stream>>>(
        qb, kb, vtb, Vall, coord, W_pos, gating, attnB);

    // proj via MFMA
    mfma_gemm_kernel<0><<<dim3(16, 32, 1), 256, 0, stream>>>(
        attnB, WpB, b_proj, out, nullptr, B_ * N_, C_, C_);
}

// Round 16
// 544.702 us; speedup vs baseline: 3.2908x; 1.0258x over previous
//
#include <hip/hip_runtime.h>
#include <math.h>

#define B_ 4
#define N_ 1024
#define C_ 1024
#define H_ 16
#define HD_ 64

typedef float f32x2 __attribute__((ext_vector_type(2)));
typedef float f32x4 __attribute__((ext_vector_type(4)));
typedef short bf16x8 __attribute__((ext_vector_type(8)));

__device__ __forceinline__ unsigned short f2bf(float v) {   // RNE f32->bf16
    unsigned u = __float_as_uint(v);
    u += 0x7FFFu + ((u >> 16) & 1u);
    return (unsigned short)(u >> 16);
}

__device__ __forceinline__ float bf2f(unsigned short h) {
    return __uint_as_float(((unsigned)h) << 16);
}

__device__ __forceinline__ float fast_exp2f(float x) {
#if __has_builtin(__builtin_amdgcn_exp2f)
    return __builtin_amdgcn_exp2f(x);   // v_exp_f32, ~1 ulp
#else
    return exp2f(x);
#endif
}

__device__ __forceinline__ float rdfl(float v) {   // force wave-uniform -> SGPR
    return __uint_as_float(__builtin_amdgcn_readfirstlane(__float_as_uint(v)));
}

// ---------------------------------------------------------------------------
// ERROR MODEL — FROZEN as of r15 (absmax 96 vs threshold 97.28, deterministic):
//   - PATCH softmax: f32 HW exp2 + split-bf16 MFMA q,k (4 products).
//   - POS softmax: f64 dist+exp chain (mandatory).
//   - EXACT S path: f64 Vall collapse.
//   - DAMPED paths: PV/v/proj bf16 MFMA.
//   NO further numerics relaxation permitted. r16 changes are bit-identical.
// PERF MODEL: attn 416us, occ 22%, VALU 51% -> residency-bound; LDS 41984
//   caps at 3 blocks/CU. r16: qc->SGPR + epilogue arrays alias into ptB ->
//   LDS exactly 40960 -> 4 blocks/CU.
// ---------------------------------------------------------------------------

// fast f64 exp for |a| <= ~16: range-reduce + deg-8 Taylor. rel err ~3e-10.
__device__ __forceinline__ double fast_exp64(double a) {
    const double LOG2E = 1.4426950408889634074;
    const double LN2HI = 6.93147180369123816490e-01;
    const double LN2LO = 1.90821492927058770002e-10;
    const double MAGIC = 6755399441055744.0;   // 1.5 * 2^52
    double t     = a * LOG2E;
    double shift = t + MAGIC;
    int    n     = (int)__double_as_longlong(shift);
    double nd    = shift - MAGIC;
    double f     = __fma_rn(nd, -LN2HI, a);
    f            = __fma_rn(nd, -LN2LO, f);
    double p = 2.4801587301587301587e-05;
    p = __fma_rn(p, f, 1.9841269841269841270e-04);
    p = __fma_rn(p, f, 1.3888888888888888889e-03);
    p = __fma_rn(p, f, 8.3333333333333333333e-03);
    p = __fma_rn(p, f, 4.1666666666666666667e-02);
    p = __fma_rn(p, f, 1.6666666666666666667e-01);
    p = __fma_rn(p, f, 5.0e-01);
    p = __fma_rn(p, f, 1.0);
    p = __fma_rn(p, f, 1.0);
    return p * __longlong_as_double(((long long)(1023 + n)) << 52);
}

// ---------------------------------------------------------------------------
// f32 -> bf16 bulk convert
// ---------------------------------------------------------------------------
__global__ __launch_bounds__(256)
void cvt_bf16_kernel(const float* __restrict__ src, unsigned short* __restrict__ dst, int n)
{
    const int i = (blockIdx.x * 256 + threadIdx.x) * 8;
    if (i >= n) return;
    const float4 a = *reinterpret_cast<const float4*>(&src[i]);
    const float4 b = *reinterpret_cast<const float4*>(&src[i + 4]);
    unsigned short pk[8];
    pk[0] = f2bf(a.x); pk[1] = f2bf(a.y); pk[2] = f2bf(a.z); pk[3] = f2bf(a.w);
    pk[4] = f2bf(b.x); pk[5] = f2bf(b.y); pk[6] = f2bf(b.z); pk[7] = f2bf(b.w);
    *reinterpret_cast<bf16x8*>(&dst[i]) = *reinterpret_cast<bf16x8*>(pk);
}

// ---------------------------------------------------------------------------
// f32 -> (hi, lo) bf16 split: hi = bf16(v), lo = bf16(v - hi).
// ---------------------------------------------------------------------------
__global__ __launch_bounds__(256)
void cvt_split_kernel(const float* __restrict__ src,
                      unsigned short* __restrict__ hi,
                      unsigned short* __restrict__ lo, int n)
{
    const int i = (blockIdx.x * 256 + threadIdx.x) * 8;
    if (i >= n) return;
    unsigned short ph[8], pl[8];
    #pragma unroll
    for (int j = 0; j < 8; ++j) {
        const float v = src[i + j];
        const unsigned short h = f2bf(v);
        ph[j] = h;
        pl[j] = f2bf(v - bf2f(h));
    }
    *reinterpret_cast<bf16x8*>(&hi[i]) = *reinterpret_cast<bf16x8*>(ph);
    *reinterpret_cast<bf16x8*>(&lo[i]) = *reinterpret_cast<bf16x8*>(pl);
}

// ---------------------------------------------------------------------------
// Split-bf16 MFMA GEMM for q,k (exact-ish path, ~f32 accuracy). r15-validated.
// ---------------------------------------------------------------------------
__global__ __launch_bounds__(256)
void qk_split_kernel(const unsigned short* __restrict__ Ahi,
                     const unsigned short* __restrict__ Alo,
                     const unsigned short* __restrict__ Bhi,
                     const unsigned short* __restrict__ Blo,
                     float* __restrict__ outq,
                     float* __restrict__ outk,
                     int M, int O, int K)
{
    __shared__ unsigned short Ash[128][40];
    __shared__ unsigned short Asl[128][40];
    __shared__ unsigned short Bsh[64][40];
    __shared__ unsigned short Bsl[64][40];

    const int t  = threadIdx.x;
    const int w  = t >> 6;
    const int l  = t & 63;
    const int o0 = blockIdx.x * 64;
    const int m0 = blockIdx.y * 128;

    f32x4 acc[2][4];
    #pragma unroll
    for (int r = 0; r < 2; ++r)
        #pragma unroll
        for (int c = 0; c < 4; ++c) acc[r][c] = (f32x4){0.f, 0.f, 0.f, 0.f};

    const int ar = t >> 1, aseg = t & 1;
    const int br = t >> 2, bseg = t & 3;
    const int fr = l & 15, kg = l >> 4;

    for (int k0 = 0; k0 < K; k0 += 32) {
        const size_t abase = (size_t)(m0 + ar) * K + k0 + aseg * 16;
        const size_t bbase = (size_t)(o0 + br) * K + k0 + bseg * 8;
        const bf16x8 ah0 = *reinterpret_cast<const bf16x8*>(&Ahi[abase]);
        const bf16x8 ah1 = *reinterpret_cast<const bf16x8*>(&Ahi[abase + 8]);
        const bf16x8 al0 = *reinterpret_cast<const bf16x8*>(&Alo[abase]);
        const bf16x8 al1 = *reinterpret_cast<const bf16x8*>(&Alo[abase + 8]);
        const bf16x8 bh0 = *reinterpret_cast<const bf16x8*>(&Bhi[bbase]);
        const bf16x8 bl0 = *reinterpret_cast<const bf16x8*>(&Blo[bbase]);
        __syncthreads();
        *reinterpret_cast<bf16x8*>(&Ash[ar][aseg * 16])     = ah0;
        *reinterpret_cast<bf16x8*>(&Ash[ar][aseg * 16 + 8]) = ah1;
        *reinterpret_cast<bf16x8*>(&Asl[ar][aseg * 16])     = al0;
        *reinterpret_cast<bf16x8*>(&Asl[ar][aseg * 16 + 8]) = al1;
        *reinterpret_cast<bf16x8*>(&Bsh[br][bseg * 8])      = bh0;
        *reinterpret_cast<bf16x8*>(&Bsl[br][bseg * 8])      = bl0;
        __syncthreads();

        bf16x8 bfh[4], bfl[4];
        #pragma unroll
        for (int c = 0; c < 4; ++c) {
            bfh[c] = *reinterpret_cast<const bf16x8*>(&Bsh[c * 16 + fr][kg * 8]);
            bfl[c] = *reinterpret_cast<const bf16x8*>(&Bsl[c * 16 + fr][kg * 8]);
        }
        #pragma unroll
        for (int r = 0; r < 2; ++r) {
            const bf16x8 afh = *reinterpret_cast<const bf16x8*>(&Ash[w * 32 + r * 16 + fr][kg * 8]);
            const bf16x8 afl = *reinterpret_cast<const bf16x8*>(&Asl[w * 32 + r * 16 + fr][kg * 8]);
            #pragma unroll
            for (int c = 0; c < 4; ++c) {
                f32x4 a = acc[r][c];
                a = __builtin_amdgcn_mfma_f32_16x16x32_bf16(afh, bfh[c], a, 0, 0, 0);
                a = __builtin_amdgcn_mfma_f32_16x16x32_bf16(afh, bfl[c], a, 0, 0, 0);
                a = __builtin_amdgcn_mfma_f32_16x16x32_bf16(afl, bfh[c], a, 0, 0, 0);
                a = __builtin_amdgcn_mfma_f32_16x16x32_bf16(afl, bfl[c], a, 0, 0, 0);
                acc[r][c] = a;
            }
        }
    }

    #pragma unroll
    for (int c = 0; c < 4; ++c) {
        int oo = o0 + c * 16 + fr;
        float* dst = (oo < 1024) ? outq : outk;
        oo &= 1023;
        const int hh = oo >> 6, d0 = oo & 63;
        #pragma unroll
        for (int r = 0; r < 2; ++r) {
            #pragma unroll
            for (int j = 0; j < 4; ++j) {
                const int m = m0 + w * 32 + r * 16 + kg * 4 + j;
                const int bb_ = m >> 10, n = m & 1023;
                dst[((((size_t)bb_ * H_) + hh) * N_ + n) * HD_ + d0] = acc[r][c][j];
            }
        }
    }
}

// ---------------------------------------------------------------------------
// bf16 MFMA GEMM (damped paths). Validated r13.
// ---------------------------------------------------------------------------
template<int OUT_BF16>
__global__ __launch_bounds__(256)
void mfma_gemm_kernel(const unsigned short* __restrict__ A,
                      const unsigned short* __restrict__ Bw,
                      const float* __restrict__ bias,
                      float* __restrict__ outF,
                      unsigned short* __restrict__ outB,
                      int M, int O, int K)
{
    __shared__ unsigned short As[128][40];
    __shared__ unsigned short Bs[64][40];

    const int t  = threadIdx.x;
    const int w  = t >> 6;
    const int l  = t & 63;
    const int o0 = blockIdx.x * 64;
    const int m0 = blockIdx.y * 128;
    const size_t zoff = (size_t)blockIdx.z * 1048576;
    Bw += zoff;

    f32x4 acc[2][4];
    #pragma unroll
    for (int r = 0; r < 2; ++r)
        #pragma unroll
        for (int c = 0; c < 4; ++c) acc[r][c] = (f32x4){0.f, 0.f, 0.f, 0.f};

    const int ar = t >> 1, aseg = t & 1;
    const int br = t >> 2, bseg = t & 3;
    const int fr = l & 15, kg = l >> 4;

    for (int k0 = 0; k0 < K; k0 += 32) {
        const bf16x8 a0 = *reinterpret_cast<const bf16x8*>(&A[(size_t)(m0 + ar) * K + k0 + aseg * 16]);
        const bf16x8 a1 = *reinterpret_cast<const bf16x8*>(&A[(size_t)(m0 + ar) * K + k0 + aseg * 16 + 8]);
        const bf16x8 b0 = *reinterpret_cast<const bf16x8*>(&Bw[(size_t)(o0 + br) * K + k0 + bseg * 8]);
        __syncthreads();
        *reinterpret_cast<bf16x8*>(&As[ar][aseg * 16])     = a0;
        *reinterpret_cast<bf16x8*>(&As[ar][aseg * 16 + 8]) = a1;
        *reinterpret_cast<bf16x8*>(&Bs[br][bseg * 8])      = b0;
        __syncthreads();

        bf16x8 bfr[4];
        #pragma unroll
        for (int c = 0; c < 4; ++c)
            bfr[c] = *reinterpret_cast<const bf16x8*>(&Bs[c * 16 + fr][kg * 8]);
        #pragma unroll
        for (int r = 0; r < 2; ++r) {
            const bf16x8 af = *reinterpret_cast<const bf16x8*>(&As[w * 32 + r * 16 + fr][kg * 8]);
            #pragma unroll
            for (int c = 0; c < 4; ++c)
                acc[r][c] = __builtin_amdgcn_mfma_f32_16x16x32_bf16(af, bfr[c], acc[r][c], 0, 0, 0);
        }
    }

    #pragma unroll
    for (int c = 0; c < 4; ++c) {
        const int col = o0 + c * 16 + fr;
        const float bv = (OUT_BF16 == 0) ? bias[col] : 0.f;
        #pragma unroll
        for (int r = 0; r < 2; ++r) {
            #pragma unroll
            for (int j = 0; j < 4; ++j) {
                const int row = m0 + w * 32 + r * 16 + kg * 4 + j;
                const float v = acc[r][c][j] + bv;
                if (OUT_BF16)
                    outB[zoff + (size_t)row * O + col] = f2bf(v);
                else
                    outF[(size_t)row * O + col] = v;
            }
        }
    }
}

// ---------------------------------------------------------------------------
__global__ void wsum_kernel(const float* __restrict__ W_v, double* __restrict__ wsh)
{
    const int k = blockIdx.x * 256 + threadIdx.x;
    const int h = blockIdx.y;
    double s = 0.0;
    #pragma unroll 8
    for (int d = 0; d < 64; ++d) s += (double)W_v[(size_t)(h * 64 + d) * C_ + k];
    wsh[h * C_ + k] = s;
}

__global__ __launch_bounds__(256)
void vall_kernel(const float* __restrict__ x, const double* __restrict__ wsh,
                 double* __restrict__ Vall)
{
    __shared__ double ws_s[1024];
    const int h = blockIdx.y, b = blockIdx.z;
    const int m = blockIdx.x * 256 + threadIdx.x;
    for (int i = threadIdx.x; i < 1024; i += 256) ws_s[i] = wsh[h * C_ + i];
    __syncthreads();
    const float* xr = x + ((size_t)b * N_ + m) * C_;
    double acc = 0.0;
    #pragma unroll 8
    for (int kk = 0; kk < 1024; ++kk) acc += (double)xr[kk] * ws_s[kk];
    Vall[((size_t)b * H_ + h) * N_ + m] = acc;
}

// ---------------------------------------------------------------------------
// Fused attention r16 = r15 math BIT-IDENTICAL; LDS footprint surgery only:
//  - qc -> wave-uniform SGPRs (readfirstlane; rows w+4i are wave-uniform)
//  - epilogue w1/w2/S arrays alias into ptB (dead after final barrier)
//  - LDS = 4096(Qs4) + 16384(Kt4) + 2048(ptB) + 2048(qtB) + 16384(VtB)
//        = 40960 exactly -> 4 blocks/CU (was 41984 -> 3).
// ---------------------------------------------------------------------------
__device__ __forceinline__ f32x2 pk_fma(f32x2 a, f32x2 b, f32x2 c) {
#if __has_builtin(__builtin_elementwise_fma)
    return __builtin_elementwise_fma(a, b, c);
#else
    f32x2 r; r.x = fmaf(a.x, b.x, c.x); r.y = fmaf(a.y, b.y, c.y); return r;
#endif
}

__global__ __launch_bounds__(256)
void attn_kernel(const float* __restrict__ q,
                 const float* __restrict__ k,
                 const unsigned short* __restrict__ vtb,
                 const double* __restrict__ Vall,
                 const float* __restrict__ coord,
                 const float* __restrict__ W_pos,
                 const float* __restrict__ gating,
                 unsigned short* __restrict__ attnB)
{
    __shared__ float4 Qs4[16][16];                          // 4096B
    __shared__ float4 Kt4[64][16];                          // 16384B
    __shared__ __align__(16) unsigned short ptB[16 * 64];   // 2048B (epi alias)
    __shared__ __align__(16) unsigned short qtB[16 * 64];   // 2048B
    __shared__ __align__(16) unsigned short VtB[2][64 * 64];// 16384B

    const int t  = threadIdx.x;
    const int w  = t >> 6;
    const int l  = t & 63;
    const int n0 = blockIdx.x * 16;
    const int h  = blockIdx.y;
    const int b  = blockIdx.z;
    const size_t bhN = ((size_t)b * H_ + h) * N_;

    const int sr0 = t >> 4;
    const int sc  = t & 15;
    const int vd  = t >> 2;
    const int vkc = (t & 3) * 16;
    const unsigned short* vrow = vtb + (((size_t)b * H_ + h) * 64 + vd) * N_;
    const int vswz = (vd & 7) << 4;

    Qs4[t >> 4][t & 15] = reinterpret_cast<const float4*>(q + (bhN + n0) * HD_)[t];

    // query coords: wave-uniform (rows w+4i) -> SGPRs, replaces qc[] LDS
    float qcx[4], qcy[4], qcz[4];
    #pragma unroll
    for (int i = 0; i < 4; ++i) {
        const float* cp = coord + ((size_t)b * N_ + n0 + w + 4 * i) * 3;
        qcx[i] = rdfl(cp[0]);
        qcy[i] = rdfl(cp[1]);
        qcz[i] = rdfl(cp[2]);
    }
    const double w4hd = (double)W_pos[h * 4 + 3];
    const double ghd  = 1.0 / (1.0 + exp(-(double)gating[h]));

    double sp[4], sq[4], spv[4], sqv[4];
    f32x4 accP = {0.f, 0.f, 0.f, 0.f};
    f32x4 accQ = {0.f, 0.f, 0.f, 0.f};
    #pragma unroll
    for (int i = 0; i < 4; ++i) { sp[i] = 0.0; sq[i] = 0.0; spv[i] = 0.0; sqv[i] = 0.0; }

    {
        const float4* kb4 = reinterpret_cast<const float4*>(k + bhN * HD_);
        #pragma unroll
        for (int i = 0; i < 4; ++i)
            Kt4[sr0 + i * 16][sc ^ ((sr0 + i * 16) & 15)] = kb4[t + i * 256];
        const bf16x8 v0 = *reinterpret_cast<const bf16x8*>(vrow + vkc);
        const bf16x8 v1 = *reinterpret_cast<const bf16x8*>(vrow + vkc + 8);
        char* vb = reinterpret_cast<char*>(&VtB[0][0]);
        *reinterpret_cast<bf16x8*>(vb + ((vd * 128 + vkc * 2)      ^ vswz)) = v0;
        *reinterpret_cast<bf16x8*>(vb + ((vd * 128 + vkc * 2 + 16) ^ vswz)) = v1;
    }
    double Vm  = Vall[bhN + l];
    double cmx = (double)coord[((size_t)b * N_ + l) * 3 + 0];
    double cmy = (double)coord[((size_t)b * N_ + l) * 3 + 1];
    double cmz = (double)coord[((size_t)b * N_ + l) * 3 + 2];
    __syncthreads();

    for (int t16 = 0; t16 < 16; ++t16) {
        const int m0   = t16 * 64;
        const int vcur = t16 & 1;

        float4 st0, st1, st2, st3;
        bf16x8 sv0, sv1;
        double VmN = 0.0, cmxN = 0.0, cmyN = 0.0, cmzN = 0.0;
        if (t16 < 15) {
            const float4* kb4 = reinterpret_cast<const float4*>(k + (bhN + m0 + 64) * HD_);
            st0 = kb4[t];
            st1 = kb4[t + 256];
            st2 = kb4[t + 512];
            st3 = kb4[t + 768];
            sv0 = *reinterpret_cast<const bf16x8*>(vrow + m0 + 64 + vkc);
            sv1 = *reinterpret_cast<const bf16x8*>(vrow + m0 + 64 + vkc + 8);
            VmN  = Vall[bhN + m0 + 64 + l];
            cmxN = (double)coord[((size_t)b * N_ + m0 + 64 + l) * 3 + 0];
            cmyN = (double)coord[((size_t)b * N_ + m0 + 64 + l) * 3 + 1];
            cmzN = (double)coord[((size_t)b * N_ + m0 + 64 + l) * 3 + 2];
        }

        f32x2 dot2[4][2];
        #pragma unroll
        for (int i = 0; i < 4; ++i) {
            dot2[i][0] = (f32x2){0.f, 0.f};
            dot2[i][1] = (f32x2){0.f, 0.f};
        }
        #pragma unroll
        for (int d4 = 0; d4 < 16; ++d4) {
            const float4 kt = Kt4[l][d4 ^ (l & 15)];
            const int g = d4 >> 3;
            const f32x2 kxy = {kt.x, kt.y};
            const f32x2 kzw = {kt.z, kt.w};
            #pragma unroll
            for (int i = 0; i < 4; ++i) {
                const float4 q4 = Qs4[w + 4 * i][d4];
                dot2[i][g] = pk_fma(kxy, (f32x2){q4.x, q4.y}, dot2[i][g]);
                dot2[i][g] = pk_fma(kzw, (f32x2){q4.z, q4.w}, dot2[i][g]);
            }
        }

        #pragma unroll
        for (int i = 0; i < 4; ++i) {
            const int r = w + 4 * i;
            const double lgs = (((double)dot2[i][0].x + (double)dot2[i][0].y) +
                                ((double)dot2[i][1].x + (double)dot2[i][1].y));
            const float pf = fast_exp2f((float)(lgs * 0.18033688011112042));  // 0.125*log2(e)
            const double dx = (double)qcx[i] - cmx;
            const double dy = (double)qcy[i] - cmy;
            const double dz = (double)qcz[i] - cmz;
            const double r2 = __fma_rn(dx, dx, __fma_rn(dy, dy, dz * dz));
            const double y0 = (double)rsqrtf((float)r2);
            const double y1 = y0 * __fma_rn(-0.5 * r2, y0 * y0, 1.5);
            const double dist = (r2 > 0.0) ? r2 * y1 : 0.0;
            const double q64 = fast_exp64(dist * w4hd);
            const int off = (r * 128 + l * 2) ^ ((r & 7) << 4);
            *reinterpret_cast<unsigned short*>(reinterpret_cast<char*>(ptB) + off) = f2bf(pf);
            *reinterpret_cast<unsigned short*>(reinterpret_cast<char*>(qtB) + off) = f2bf((float)q64);
            sp[i]  += (double)pf;
            sq[i]  += q64;
            spv[i] += (double)pf * Vm;
            sqv[i] += q64 * Vm;
        }
        __syncthreads();   // barrier A

        {
            const int r_   = l & 15;
            const int kb_  = l >> 4;
            const int aoff = r_ * 128 + kb_ * 16;
            const int aswz = (r_ & 7) << 4;
            const int dimw = w * 16 + r_;
            const int boff = dimw * 128 + kb_ * 16;
            const int bswz = (dimw & 7) << 4;
            const char* pbase = reinterpret_cast<const char*>(ptB);
            const char* qbase = reinterpret_cast<const char*>(qtB);
            const char* vbase = reinterpret_cast<const char*>(&VtB[vcur][0]);
            #pragma unroll
            for (int kh = 0; kh < 2; ++kh) {
                const bf16x8 afp = *reinterpret_cast<const bf16x8*>(pbase + ((aoff + kh * 64) ^ aswz));
                const bf16x8 afq = *reinterpret_cast<const bf16x8*>(qbase + ((aoff + kh * 64) ^ aswz));
                const bf16x8 bf_ = *reinterpret_cast<const bf16x8*>(vbase + ((boff + kh * 64) ^ bswz));
                accP = __builtin_amdgcn_mfma_f32_16x16x32_bf16(afp, bf_, accP, 0, 0, 0);
                accQ = __builtin_amdgcn_mfma_f32_16x16x32_bf16(afq, bf_, accQ, 0, 0, 0);
            }
        }

        if (t16 < 15) {
            Kt4[sr0     ][sc ^ ( sr0       & 15)] = st0;
            Kt4[sr0 + 16][sc ^ ((sr0 + 16) & 15)] = st1;
            Kt4[sr0 + 32][sc ^ ((sr0 + 32) & 15)] = st2;
            Kt4[sr0 + 48][sc ^ ((sr0 + 48) & 15)] = st3;
            char* vb = reinterpret_cast<char*>(&VtB[vcur ^ 1][0]);
            *reinterpret_cast<bf16x8*>(vb + ((vd * 128 + vkc * 2)      ^ vswz)) = sv0;
            *reinterpret_cast<bf16x8*>(vb + ((vd * 128 + vkc * 2 + 16) ^ vswz)) = sv1;
            Vm = VmN; cmx = cmxN; cmy = cmyN; cmz = cmzN;
        }
        __syncthreads();   // barrier B  (also frees ptB for epilogue alias)
    }

    // ---- epilogue: per-row w1/w2/S shared via ptB alias (ptB dead now)
    double* epi = reinterpret_cast<double*>(ptB);   // 48 doubles <= 2048B
    #pragma unroll
    for (int i = 0; i < 4; ++i) {
        double vsp = sp[i], vsq = sq[i], vspv = spv[i], vsqv = sqv[i];
        #pragma unroll
        for (int mm = 32; mm >= 1; mm >>= 1) {
            vsp  += __shfl_xor(vsp,  mm);
            vsq  += __shfl_xor(vsq,  mm);
            vspv += __shfl_xor(vspv, mm);
            vsqv += __shfl_xor(vsqv, mm);
        }
        const double w1 = (1.0 - ghd) / vsp;
        const double w2 = ghd / vsq;
        if (l == 0) {
            epi[w + 4 * i]      = w1;
            epi[16 + w + 4 * i] = w2;
            epi[32 + w + 4 * i] = w1 * vspv + w2 * vsqv;   // S
        }
    }
    __syncthreads();
    const int col = h * HD_ + w * 16 + (l & 15);
    #pragma unroll
    for (int j = 0; j < 4; ++j) {
        const int m = 4 * (l >> 4) + j;
        const double a = epi[m] * (double)accP[j] + epi[16 + m] * (double)accQ[j];
        attnB[((size_t)b * N_ + n0 + m) * C_ + col] = f2bf((float)(a / epi[32 + m]));
    }
}

// ---------------------------------------------------------------------------
extern "C" void kernel_launch(void* const* d_in, const int* in_sizes, int n_in,
                              void* d_out, int out_size, void* d_ws, size_t ws_size,
                              hipStream_t stream)
{
    const float* x      = (const float*)d_in[0];
    const float* coord  = (const float*)d_in[1];
    const float* W_qk   = (const float*)d_in[2];
    const float* W_v    = (const float*)d_in[3];
    const float* W_proj = (const float*)d_in[4];
    const float* b_proj = (const float*)d_in[5];
    const float* W_pos  = (const float*)d_in[6];
    // d_in[7] = b_pos (cancels in softmax), d_in[9] = pos_emb (cancels) — unused
    const float* gating = (const float*)d_in[8];

    float* ws   = (float*)d_ws;
    const size_t per = (size_t)B_ * H_ * N_ * HD_;   // 4,194,304 elements
    float*          qb    = ws;                          // 16MB
    float*          kb    = qb + per;                    // 16MB
    unsigned short* attnB = (unsigned short*)(kb + per); // 8MB; hosts Wqk splits pre-attn
    unsigned short* WqkHi = attnB;                       // 4MB
    unsigned short* WqkLo = attnB + 2 * (size_t)C_ * C_; // 4MB
    unsigned short* vtb   = attnB + per;                 // 8MB
    unsigned short* xhi   = vtb + per;                   // 8MB (also v-GEMM's A)
    unsigned short* xlo   = xhi + per;                   // 8MB
    unsigned short* WvB   = xlo + per;                   // 2MB
    unsigned short* WpB   = WvB + (size_t)C_ * C_;       // 2MB
    double*         wsh   = (double*)(WpB + (size_t)C_ * C_);
    double*         Vall  = wsh + (size_t)H_ * C_;
    float*          out   = (float*)d_out;

    // splits + bf16 conversions
    cvt_split_kernel<<<2048, 256, 0, stream>>>(x, xhi, xlo, (int)per);
    cvt_split_kernel<<<1024, 256, 0, stream>>>(W_qk, WqkHi, WqkLo, 2 * C_ * C_);
    cvt_bf16_kernel<<<512, 256, 0, stream>>>(W_v, WvB, C_ * C_);
    cvt_bf16_kernel<<<512, 256, 0, stream>>>(W_proj, WpB, C_ * C_);

    // exact S-path precomputation (from raw f32 inputs)
    wsum_kernel<<<dim3(4, 16), 256, 0, stream>>>(W_v, wsh);
    vall_kernel<<<dim3(4, 16, 4), 256, 0, stream>>>(x, wsh, Vall);

    // q,k via split-bf16 MFMA (4 products, ~f32 accuracy)
    qk_split_kernel<<<dim3(32, 32), 256, 0, stream>>>(
        xhi, xlo, WqkHi, WqkLo, qb, kb, B_ * N_, 2 * C_, C_);

    // v^T bf16 via MFMA
    mfma_gemm_kernel<1><<<dim3(16, 8, 4), 256, 0, stream>>>(
        WvB, xhi, nullptr, nullptr, vtb, C_, N_, C_);

    // fused attention (overwrites the Wqk-split region with attnB — qk done)
    attn_kernel<<<dim3(N_ / 16, H_, B_), 256, 0, stream>>>(
        qb, kb, vtb, Vall, coord, W_pos, gating, attnB);

    // proj via MFMA
    mfma_gemm_kernel<0><<<dim3(16, 32, 1), 256, 0, stream>>>(
        attnB, WpB, b_proj, out, nullptr, B_ * N_, C_, C_);
}